// Round 3
// baseline (348.126 us; speedup 1.0000x reference)
//
#include <hip/hip_runtime.h>
#include <hip/hip_bf16.h>

// B=4, N=1024, E=256, H=8, D=32. Float tensors may be bf16 OR fp32 in d_in /
// d_out (detected at runtime on-device); adj is int32.
// Output: x_out [4,1024,256] then e_out [4,1024,1024] (element offsets).
//
// ws float offsets:
//   [0 .. 196608)   : 6 weight matrices, transposed, bf16, quad-interleaved
//                     matrix m at ushort offset m*65536; element (e,o) at
//                     ((e>>2)*256 + o)*4 + (e&3).  m: 0=Wcat 1=LIN 2=WQ 3=WK 4=WV 5=WO
#define BIAS_OFF 196608   // lin_b, bq, bk, bv, bo, a1, a2  (7*256 fp32)
#define S1_OFF   198400   // [h][4096]
#define S2_OFF   231168
#define CS_OFF   263936   // 32768: column partial sums+sumsq (reused twice)
#define ST1_OFF  296704   // mean[1024] + inv[1024]
#define ST2_OFF  298752
#define A_OFF    300800   // WhT bf16 [h][b][d][n] (2 MB) -> later Q,o fp32 head-major
#define MX_OFF   825088   // A_OFF+524288: softmax row max  [h][4096] (dead before Q)
#define RS_OFF   857856   // softmax row 1/sum              [h][4096]
#define PK_OFF   890624   // packed adj bitmask: [4096 rows][16 u64] = 512 KB (dead before Q)
#define B_OFF    1349376  // 4 MB: rownorm(xa)     -> later K bf16 head-major [b][h][n][32]
#define C_OFF    2397952  // 4 MB: raw xa, then rownorm(lin) -> later V^T bf16 hm [b][h][d][n]
#define FLAG_F   3446528  // int: 1 = bf16 tensors, 0 = fp32 tensors
// end 3446529 floats = 13.8 MB

#define NEGC (-9.0e15f)

typedef __attribute__((ext_vector_type(8))) short bf16x8s;
typedef __attribute__((ext_vector_type(4))) float f32x4;

static __device__ __forceinline__ float bf2f(unsigned short u) {
  union { unsigned int i; float f; } v; v.i = ((unsigned int)u) << 16; return v.f;
}
static __device__ __forceinline__ unsigned short f2bf(float f) {
  union { float f; unsigned int u; } v; v.f = f;
  unsigned int r = (v.u + 0x7FFFu + ((v.u >> 16) & 1u)) >> 16;   // RNE
  return (unsigned short)r;
}
static __device__ __forceinline__ float ldin(const void* p, long i, int bf) {
  return bf ? bf2f(((const unsigned short*)p)[i]) : ((const float*)p)[i];
}
static __device__ __forceinline__ unsigned short rdbf(const void* p, long i, int bf) {
  if (bf) return ((const unsigned short*)p)[i];
  return f2bf(((const float*)p)[i]);
}
static __device__ __forceinline__ void stout(void* p, long i, float v, int bf) {
  if (bf) ((unsigned short*)p)[i] = f2bf(v);
  else    ((float*)p)[i] = v;
}

// ---------------- dtype detector -------------------------------------------
__global__ __launch_bounds__(64) void detect_kernel(const unsigned short* x, int* flag) {
  int lane = threadIdx.x;
  unsigned short u = x[2 * lane];
  int e = (u >> 7) & 0xFF;
  bool good = (e >= 100 && e <= 140);
  unsigned long long m = __ballot(good);
  if (lane == 0) *flag = (__popcll(m) >= 48) ? 1 : 0;
}

// ---------------- adj -> bitmask: [row][16 u64], bit m%64 of word m/64 -----
__global__ __launch_bounds__(256) void packadj_kernel(const int* adj,
                                                      unsigned long long* pk) {
  int t = threadIdx.x, w = t >> 6, lane = t & 63;
  long row = blockIdx.x;            // 4096 rows
  #pragma unroll
  for (int j = 0; j < 4; ++j) {
    int m = t + 256*j;              // wave covers bits [w*64+256j .. +63]
    bool bit = adj[row*1024 + m] > 0;
    unsigned long long mask = __ballot(bit);
    if (lane == 0) pk[row*16 + w + 4*j] = mask;
  }
}

// ---------------- prep: weights -> transposed quad bf16; biases -> fp32 ----
__global__ __launch_bounds__(256) void prep_kernel(
    const void* wg, const void* lin_w, const void* inp_w, const void* out_w,
    const void* lin_b, const void* inp_b, const void* out_b,
    const void* a1, const void* a2, float* ws, const int* flagp) {
  const int bf = *flagp;
  unsigned short* wbf = (unsigned short*)ws;
  int t = threadIdx.x;
  int f = blockIdx.x;
  int m = blockIdx.y;
  int dst = m*65536 + ((f >> 2)*256 + t)*4 + (f & 3);
  if (m == 0) {
    int h = t >> 5, d = t & 31;
    wbf[dst] = rdbf(wg, h*8192 + f*32 + d, bf);
  } else if (m == 1) wbf[dst] = rdbf(lin_w, t*256 + f, bf);
  else if (m == 2)   wbf[dst] = rdbf(inp_w, t*256 + f, bf);
  else if (m == 3)   wbf[dst] = rdbf(inp_w, (256 + t)*256 + f, bf);
  else if (m == 4)   wbf[dst] = rdbf(inp_w, (512 + t)*256 + f, bf);
  else if (m == 5)   wbf[dst] = rdbf(out_w, t*256 + f, bf);
  else if (f == 0) {
    ws[BIAS_OFF + t]        = ldin(lin_b, t, bf);
    ws[BIAS_OFF + 256 + t]  = ldin(inp_b, t, bf);
    ws[BIAS_OFF + 512 + t]  = ldin(inp_b, 256 + t, bf);
    ws[BIAS_OFF + 768 + t]  = ldin(inp_b, 512 + t, bf);
    ws[BIAS_OFF + 1024 + t] = ldin(out_b, t, bf);
    ws[BIAS_OFF + 1280 + t] = ldin(a1, t, bf);
    ws[BIAS_OFF + 1536 + t] = ldin(a2, t, bf);
  }
}

// -------- Wh = x @ Wcat -> WhT bf16 [h][b][d][n]; s1/s2 head reductions ----
__global__ __launch_bounds__(256) void whs_kernel(const void* x, float* ws,
                                                  const int* flagp) {
  const int bf = *flagp;
  int t = threadIdx.x;
  int r0 = blockIdx.x * 8;
  __shared__ __align__(16) float U[8][256];
  #pragma unroll
  for (int r = 0; r < 8; ++r)
    U[r][t] = ldin(x, (long)(r0 + r)*256 + t, bf);
  __syncthreads();
  const ushort4* w4 = (const ushort4*)ws;
  float acc[8] = {0,0,0,0,0,0,0,0};
  for (int e4 = 0; e4 < 64; ++e4) {
    ushort4 u = w4[e4*256 + t];
    float w0 = bf2f(u.x), w1 = bf2f(u.y), w2 = bf2f(u.z), w3 = bf2f(u.w);
    #pragma unroll
    for (int r = 0; r < 8; ++r) {
      float4 uu = *(const float4*)&U[r][e4*4];
      acc[r] += uu.x*w0 + uu.y*w1 + uu.z*w2 + uu.w*w3;
    }
  }
  int h = t >> 5, d = t & 31;
  float a1v = ws[BIAS_OFF + 1280 + t];
  float a2v = ws[BIAS_OFF + 1536 + t];
  unsigned short wvals[8];
  #pragma unroll
  for (int r = 0; r < 8; ++r) {
    int row = r0 + r;
    wvals[r] = f2bf(acc[r]);
    float p1 = acc[r]*a1v, p2 = acc[r]*a2v;
    #pragma unroll
    for (int off = 16; off > 0; off >>= 1) {
      p1 += __shfl_xor(p1, off, 32);
      p2 += __shfl_xor(p2, off, 32);
    }
    if (d == 0) {
      ws[S1_OFF + h*4096 + row] = p1;
      ws[S2_OFF + h*4096 + row] = p2;
    }
  }
  // WhT[h][b][d][n], 8 contiguous n per thread (16B store)
  {
    unsigned short* wht = (unsigned short*)(ws + A_OFF);
    int bb = r0 >> 10, nn = r0 & 1023;
    *(bf16x8s*)(wht + ((long)((h*4 + bb)*32 + d))*1024 + nn) = *(bf16x8s*)wvals;
  }
}

// ------- graph attention, head-split, 8 rows/block -------------------------
// Grid 4096 = 4b x 128 groups x 8h; h in low 3 bits (XCD-L2 locality on WhT).
// adj from packed bitmask (scalar loads). Softmax register-resident: wave w
// owns rows w and w+4 (sequential). P bf16 in Pb (8 real rows, dup x2 in the
// 16-row MFMA A-tile). PV via mfma_f32_16x16x32_bf16 against WhT. Writes:
//   C region: raw xa slice  xa[b,n,h*32+d] = x + leaky(PV)
//   MX/RS: per-(h,row) softmax max and 1/sum (consumed by eout_kernel)
#define PB_S 1032    // Pb row stride (ushorts); 2064B = 129*16, rows +4 banks
__global__ __launch_bounds__(256) void attn1a_kernel(const void* x, float* ws,
                                                     const int* flagp) {
  const int bf = *flagp;
  int t = threadIdx.x;
  int gid = blockIdx.x;
  int h = gid & 7;
  int b = (gid >> 3) & 3;
  int n0 = (gid >> 5) * 8;
  __shared__ __align__(16) float s2s[1024];
  __shared__ __align__(16) unsigned short Pb[8][PB_S];
  __shared__ __align__(16) float opart[4][8][16];
  int w = t >> 6, lane = t & 63;
  int fm = lane & 15, quad = lane >> 4;
  const unsigned long long* pk = (const unsigned long long*)(ws + PK_OFF);
  const float* s2p = ws + S2_OFF + h*4096 + b*1024;
  #pragma unroll
  for (int j = 0; j < 4; ++j) s2s[t + 256*j] = s2p[t + 256*j];
  __syncthreads();
  // ---- softmax rows (n0+w) and (n0+w+4), head h: register resident --------
  #pragma unroll
  for (int rr = 0; rr < 2; ++rr) {
    int r = w + 4*rr;
    int rowi = __builtin_amdgcn_readfirstlane(b*1024 + n0 + r);
    const unsigned long long* prow = pk + (long)rowi * 16;   // wave-uniform
    float s1v = ws[S1_OFF + h*4096 + rowi];
    float p[16];
    float mx = -3.4e38f;
    #pragma unroll
    for (int j = 0; j < 16; ++j) {
      int m = lane + 64*j;
      float ev = s1v + s2s[m];
      ev = (ev >= 0.0f) ? ev : 0.1f*ev;
      ev = ((prow[j] >> lane) & 1ull) ? ev : NEGC;
      p[j] = ev;
      mx = fmaxf(mx, ev);
    }
    #pragma unroll
    for (int off = 32; off > 0; off >>= 1) mx = fmaxf(mx, __shfl_xor(mx, off));
    float s = 0.0f;
    #pragma unroll
    for (int j = 0; j < 16; ++j) { p[j] = __expf(p[j] - mx); s += p[j]; }
    #pragma unroll
    for (int off = 32; off > 0; off >>= 1) s += __shfl_xor(s, off);
    float rs = 1.0f / s;
    #pragma unroll
    for (int j = 0; j < 16; ++j)
      Pb[r][lane + 64*j] = f2bf(p[j] * rs);
    if (lane == 0) {
      ws[MX_OFF + h*4096 + rowi] = mx;
      ws[RS_OFF + h*4096 + rowi] = rs;
    }
  }
  __syncthreads();
  // ---- PV via MFMA: wave w -> ntile (w&1), k-tiles (w>>1)*16 .. +15 -------
  {
    const unsigned short* wht = (const unsigned short*)(ws + A_OFF);
    int ntile = w & 1;
    int ktbase = (w >> 1) * 16;
    int vd = ntile*16 + fm;
    const unsigned short* wrow = wht + ((long)((h*4 + b)*32 + vd))*1024;
    f32x4 acc0 = {0.0f, 0.0f, 0.0f, 0.0f};
    f32x4 acc1 = {0.0f, 0.0f, 0.0f, 0.0f};
    #pragma unroll
    for (int kt2 = 0; kt2 < 8; ++kt2) {
      int kt = ktbase + 2*kt2;
      bf16x8s ap0 = *(const bf16x8s*)&Pb[fm & 7][kt*32 + quad*8];
      bf16x8s bw0 = *(const bf16x8s*)(wrow + kt*32 + quad*8);
      acc0 = __builtin_amdgcn_mfma_f32_16x16x32_bf16(ap0, bw0, acc0, 0, 0, 0);
      bf16x8s ap1 = *(const bf16x8s*)&Pb[fm & 7][(kt+1)*32 + quad*8];
      bf16x8s bw1 = *(const bf16x8s*)(wrow + (kt+1)*32 + quad*8);
      acc1 = __builtin_amdgcn_mfma_f32_16x16x32_bf16(ap1, bw1, acc1, 0, 0, 0);
    }
    f32x4 acc = acc0 + acc1;
    if (quad < 2) {             // D rows 0..7 are the real query rows
      #pragma unroll
      for (int i = 0; i < 4; ++i) opart[w][quad*4 + i][fm] = acc[i];
    }
  }
  __syncthreads();
  {
    int r = t >> 5, dd = t & 31;
    int nt = dd >> 4, c = dd & 15;
    float sum = opart[nt][r][c] + opart[nt + 2][r][c];
    float hv = (sum >= 0.0f) ? sum : 0.01f*sum;
    long idx = (long)(b*1024 + n0 + r)*256 + h*32 + dd;
    ws[C_OFF + idx] = ldin(x, idx, bf) + hv;   // raw residual row slice
  }
}

// ------- e_out = mean_h attn (from stored mx/rs) + fused rownorm(xa) -------
// Grid 4096: one (b,n) row per block. Rownorm reads raw xa (C region), writes
// B region. e_out recomputed from s1/s2/packed-adj + per-head mx/rs (exact
// same arithmetic/order as before: sum over h of rs*exp(lrelu(s1+s2)-mx)).
__global__ __launch_bounds__(256) void eout_kernel(float* ws, void* dout,
                                                   const int* flagp) {
  const int bf = *flagp;
  int t = threadIdx.x;
  int gid = blockIdx.x;
  int b = gid & 3;
  int n = gid >> 2;
  int row = b*1024 + n;
  int w = t >> 6, lane = t & 63;
  __shared__ float part[8];
  const unsigned long long* pk = (const unsigned long long*)(ws + PK_OFF);
  const unsigned long long* prow = pk + (long)row * 16;
  // ---- rownorm (ddof=1, two-pass) of raw xa row ---------------------------
  float v = ws[C_OFF + (long)row*256 + t];
  float s = v;
  #pragma unroll
  for (int off = 32; off > 0; off >>= 1) s += __shfl_xor(s, off);
  if (lane == 0) part[w] = s;
  __syncthreads();
  float mean = (part[0] + part[1] + part[2] + part[3]) * (1.0f/256.0f);
  float d = v - mean;
  float ss = d*d;
  #pragma unroll
  for (int off = 32; off > 0; off >>= 1) ss += __shfl_xor(ss, off);
  if (lane == 0) part[4 + w] = ss;
  __syncthreads();
  float inv = 1.0f / (sqrtf((part[4]+part[5]+part[6]+part[7]) * (1.0f/255.0f)) + 1e-6f);
  ws[B_OFF + (long)row*256 + t] = d * inv;
  // ---- e_out --------------------------------------------------------------
  float s1v[8], mxv[8], rsv[8];
  #pragma unroll
  for (int h = 0; h < 8; ++h) {
    s1v[h] = ws[S1_OFF + h*4096 + row];
    mxv[h] = ws[MX_OFF + h*4096 + row];
    rsv[h] = ws[RS_OFF + h*4096 + row];
  }
  const float* s2b = ws + S2_OFF + b*1024;
  #pragma unroll
  for (int j = 0; j < 4; ++j) {
    int m = t + 256*j;
    bool a = (prow[w + 4*j] >> lane) & 1ull;   // bit m: word (m>>6)=w+4j, bit lane
    float acc = 0.0f;
    #pragma unroll
    for (int h = 0; h < 8; ++h) {
      float ev = s1v[h] + s2b[h*4096 + m];
      ev = (ev >= 0.0f) ? ev : 0.1f*ev;
      ev = a ? ev : NEGC;
      acc += rsv[h] * __expf(ev - mxv[h]);
    }
    stout(dout, 1048576L + (long)row*1024 + m, 0.125f*acc, bf);
  }
}

// ---------------- column (axis=1) stats, ddof=1 ----------------------------
__global__ __launch_bounds__(256) void colstatsA_kernel(const float* in, float* cs) {
  int t = threadIdx.x;
  int j = blockIdx.x & 15;
  int b = blockIdx.x >> 4;
  float s = 0, ss = 0;
  for (int n = j*64; n < j*64 + 64; ++n) {
    float v = in[(b*1024 + n)*256 + t];
    s += v; ss += v*v;
  }
  cs[(b*16 + j)*256 + t] = s;
  cs[16384 + (b*16 + j)*256 + t] = ss;
}

__global__ __launch_bounds__(256) void colstatsB_kernel(const float* cs, float* st) {
  int t = threadIdx.x;
  int b = blockIdx.x;
  float s = 0, ss = 0;
  for (int j = 0; j < 16; ++j) {
    s  += cs[(b*16 + j)*256 + t];
    ss += cs[16384 + (b*16 + j)*256 + t];
  }
  float mean = s * (1.0f/1024.0f);
  float var = fmaxf((ss - s*mean) * (1.0f/1023.0f), 0.0f);
  st[b*256 + t] = mean;
  st[1024 + b*256 + t] = 1.0f / (sqrtf(var) + 1e-6f);
}

// ---------------- row GEMM, bf16 quad weights ------------------------------
// IN_MODE 0: plain fp32 [row][256]; 1: fp32 + colnorm(st); 2: float-input src
//   permuted (n,b,e)->(b,n,e); 3: fp32 head-major [b][h][n][32]
// RN 1: fused rownorm on output
// OUTM 0: fp32 [row][256]; 1: d_out (dtype per flag); 2: fp32 head-major;
//      3: bf16 head-major; 4: bf16 TRANSPOSED head-major [b][h][d][n]
template<int IN_MODE, int RN, int OUTM>
__global__ __launch_bounds__(256) void gemm_kernel(const void* inp,
    const unsigned short* wmat, const float* bias, const float* st, void* outp,
    const int* flagp) {
  const int bf = *flagp;
  int t = threadIdx.x;
  int r0 = blockIdx.x * 8;
  __shared__ __align__(16) float U[8][256];
  #pragma unroll
  for (int r = 0; r < 8; ++r) {
    int row = r0 + r;
    float v;
    if (IN_MODE == 0) {
      v = ((const float*)inp)[row*256 + t];
    } else if (IN_MODE == 1) {
      int b = row >> 10;
      v = (((const float*)inp)[row*256 + t] - st[b*256 + t]) * st[1024 + b*256 + t];
    } else if (IN_MODE == 2) {
      int b = row >> 10, n = row & 1023;
      v = ldin(inp, (long)(n*4 + b)*256 + t, bf);
    } else {
      int b = row >> 10, n = row & 1023;
      v = ((const float*)inp)[((b*8 + (t >> 5))*1024 + n)*32 + (t & 31)];
    }
    U[r][t] = v;
  }
  __syncthreads();
  float bv = bias[t];
  float acc[8];
  #pragma unroll
  for (int r = 0; r < 8; ++r) acc[r] = bv;
  const ushort4* w4 = (const ushort4*)wmat;
  for (int e4 = 0; e4 < 64; ++e4) {
    ushort4 u = w4[e4*256 + t];
    float w0 = bf2f(u.x), w1 = bf2f(u.y), w2 = bf2f(u.z), w3 = bf2f(u.w);
    #pragma unroll
    for (int r = 0; r < 8; ++r) {
      float4 uu = *(const float4*)&U[r][e4*4];
      acc[r] += uu.x*w0 + uu.y*w1 + uu.z*w2 + uu.w*w3;
    }
  }
  if (RN == 0) {
    #pragma unroll
    for (int r = 0; r < 8; ++r) {
      int row = r0 + r;
      if (OUTM == 0) ((float*)outp)[row*256 + t] = acc[r];
      else if (OUTM == 1) stout(outp, (long)row*256 + t, acc[r], bf);
      else if (OUTM == 2) {
        int b = row >> 10, n = row & 1023;
        ((float*)outp)[((b*8 + (t >> 5))*1024 + n)*32 + (t & 31)] = acc[r];
      } else if (OUTM == 3) {
        int b = row >> 10, n = row & 1023;
        ((unsigned short*)outp)[((b*8 + (t >> 5))*1024 + n)*32 + (t & 31)] = f2bf(acc[r]);
      } else {
        int b = row >> 10, n = row & 1023;
        ((unsigned short*)outp)[((b*8 + (t >> 5))*32 + (t & 31))*1024 + n] = f2bf(acc[r]);
      }
    }
  } else {
    __syncthreads();
    #pragma unroll
    for (int r = 0; r < 8; ++r) U[r][t] = acc[r];
    __syncthreads();
    int w = t >> 6, lane = t & 63;
    for (int rr = w; rr < 8; rr += 4) {
      float vals[4]; float s = 0.0f;
      #pragma unroll
      for (int j = 0; j < 4; ++j) { vals[j] = U[rr][lane + 64*j]; s += vals[j]; }
      #pragma unroll
      for (int off = 32; off > 0; off >>= 1) s += __shfl_xor(s, off);
      float mean = s * (1.0f/256.0f);
      float ss = 0.0f;
      #pragma unroll
      for (int j = 0; j < 4; ++j) { float d = vals[j] - mean; ss += d*d; }
      #pragma unroll
      for (int off = 32; off > 0; off >>= 1) ss += __shfl_xor(ss, off);
      float inv = 1.0f / (sqrtf(ss * (1.0f/255.0f)) + 1e-6f);
      #pragma unroll
      for (int j = 0; j < 4; ++j)
        ((float*)outp)[(r0 + rr)*256 + lane + 64*j] = (vals[j] - mean) * inv;
    }
  }
}

// ---------------- MHA via MFMA, bf16 K/V, 8 q-rows per block ---------------
// GRID MUST BE 4096: 128 row-groups x 4 b x 8 h. h in low 3 bits (XCD-L2).
// Q fp32 head-major [b][h][n][32] at A_OFF (o overwrites q, exclusive slots);
// K bf16 [b][h][n][32] at B_OFF; V^T bf16 [b][h][d][n] at C_OFF.
// S in LDS fp32, stride 1032 (8-bank row shift): QK stores 2-way, softmax
// strided reads 2-way, PV b128 reads 2-way -- all conflict-free tiers.
// Softmax: single pass into regs, normalized P written back bf16 IN-PLACE
// (row r bf16 overlay occupies first 2 KB of row r's 4.1 KB fp32 footprint;
// write values data-depend on all reads, so no reorder hazard; cross-wave
// disjoint). PV reads P via ds_read_b128 (no cvt), dual accumulators.
// mfma_f32_16x16x32_bf16 layouts (m89-verified):
//   A[m=lane&15][k=(lane>>4)*8+j]; B[k=(lane>>4)*8+j][n=lane&15];
//   D col=lane&15, row=(lane>>4)*4+i.
#define SP_RS2 1032
__global__ __launch_bounds__(256) void attn2_kernel(float* ws) {
  int t = threadIdx.x;
  int gid = blockIdx.x;
  int h = gid & 7;
  int b = (gid >> 3) & 3;
  int n0 = (gid >> 5) << 3;   // 8 q-rows per block; gid>>5 in 0..127
  __shared__ __align__(16) float Sp[8*SP_RS2];
  __shared__ __align__(16) float opart[4][8][16];
  float* qq = ws + A_OFF;
  const unsigned short* kk = (const unsigned short*)(ws + B_OFF);
  const unsigned short* vt = (const unsigned short*)(ws + C_OFF);
  int base_bh = (b*8 + h)*1024;
  int w = t >> 6, lane = t & 63;
  int m = lane & 15, quad = lane >> 4;
  const float scl = 0.17677669529663687f; // 1/sqrt(32)
  // ---- QK via MFMA: wave w covers keys w*256 .. +255 ----------------------
  {
    const float* qp = qq + (base_bh + n0 + (lane & 7))*32 + quad*8;
    bf16x8s aq;
    #pragma unroll
    for (int j = 0; j < 8; ++j) ((unsigned short*)&aq)[j] = f2bf(qp[j]);
    f32x4 zero = {0.0f, 0.0f, 0.0f, 0.0f};
    #pragma unroll
    for (int kt = 0; kt < 16; ++kt) {
      int kbase = w*256 + kt*16;
      bf16x8s bk = *(const bf16x8s*)(kk + (base_bh + kbase + m)*32 + quad*8);
      f32x4 d = __builtin_amdgcn_mfma_f32_16x16x32_bf16(aq, bk, zero, 0, 0, 0);
      if (lane < 32) {
        int key = kbase + m;
        #pragma unroll
        for (int i = 0; i < 4; ++i)
          Sp[(quad*4 + i)*SP_RS2 + key] = d[i] * scl;
      }
    }
  }
  __syncthreads();
  // ---- softmax: wave w handles rows w and w+4; single pass, bf16 overlay --
  #pragma unroll
  for (int rr = 0; rr < 2; ++rr) {
    int r = w + 4*rr;
    float* Sr = Sp + r*SP_RS2;
    float p[16];
    #pragma unroll
    for (int j = 0; j < 16; ++j) p[j] = Sr[lane + 64*j];
    float mx = -3.4e38f;
    #pragma unroll
    for (int j = 0; j < 16; ++j) mx = fmaxf(mx, p[j]);
    #pragma unroll
    for (int off = 32; off > 0; off >>= 1) mx = fmaxf(mx, __shfl_xor(mx, off));
    float s = 0.0f;
    #pragma unroll
    for (int j = 0; j < 16; ++j) { p[j] = __expf(p[j] - mx); s += p[j]; }
    #pragma unroll
    for (int off = 32; off > 0; off >>= 1) s += __shfl_xor(s, off);
    float rs = 1.0f / s;
    unsigned short* Pr = (unsigned short*)Sr;     // bf16 overlay, same row
    #pragma unroll
    for (int j = 0; j < 16; ++j)
      Pr[lane + 64*j] = f2bf(p[j] * rs);
  }
  __syncthreads();
  // ---- PV via MFMA: wave w -> N-tile (w&1), k-tiles (w>>1)*16 .. +15 ------
  {
    int ntile = w & 1;
    int ktbase = (w >> 1) * 16;
    int vd = ntile*16 + m;
    const unsigned short* vrow = vt + base_bh*32 + vd*1024;
    const unsigned short* Pbase = (const unsigned short*)(Sp + (lane & 7)*SP_RS2);
    f32x4 acc0 = {0.0f, 0.0f, 0.0f, 0.0f};
    f32x4 acc1 = {0.0f, 0.0f, 0.0f, 0.0f};
    #pragma unroll
    for (int kt2 = 0; kt2 < 8; ++kt2) {
      int kt = ktbase + 2*kt2;
      bf16x8s ap0 = *(const bf16x8s*)(Pbase + kt*32 + quad*8);
      bf16x8s bv0 = *(const bf16x8s*)(vrow + kt*32 + quad*8);
      acc0 = __builtin_amdgcn_mfma_f32_16x16x32_bf16(ap0, bv0, acc0, 0, 0, 0);
      bf16x8s ap1 = *(const bf16x8s*)(Pbase + (kt+1)*32 + quad*8);
      bf16x8s bv1 = *(const bf16x8s*)(vrow + (kt+1)*32 + quad*8);
      acc1 = __builtin_amdgcn_mfma_f32_16x16x32_bf16(ap1, bv1, acc1, 0, 0, 0);
    }
    f32x4 acc = acc0 + acc1;
    if (lane < 32) {
      #pragma unroll
      for (int i = 0; i < 4; ++i)
        opart[w][quad*4 + i][m] = acc[i];
    }
  }
  __syncthreads();
  {
    int r = t >> 5, d = t & 31;
    int nt = d >> 4, c = d & 15;
    float sum = opart[nt][r][c] + opart[nt + 2][r][c];
    qq[(base_bh + n0 + r)*32 + d] = sum;   // o over q (own slots)
  }
}

extern "C" void kernel_launch(void* const* d_in, const int* in_sizes, int n_in,
                              void* d_out, int out_size, void* d_ws, size_t ws_size,
                              hipStream_t stream) {
  const void* x   = d_in[0];
  const void* src = d_in[1];
  const int* adj  = (const int*)d_in[2];
  const void* wg  = d_in[3];
  const void* a1  = d_in[4];
  const void* a2  = d_in[5];
  const void* lw  = d_in[6];
  const void* lb  = d_in[7];
  const void* ipw = d_in[8];
  const void* ipb = d_in[9];
  const void* opw = d_in[10];
  const void* opb = d_in[11];
  float* ws = (float*)d_ws;
  const unsigned short* wbf = (const unsigned short*)d_ws;
  int* flagp = (int*)(ws + FLAG_F);

  detect_kernel<<<1, 64, 0, stream>>>((const unsigned short*)x, flagp);
  prep_kernel<<<dim3(256, 7), 256, 0, stream>>>(wg, lw, ipw, opw, lb, ipb, opb,
                                                a1, a2, ws, flagp);
  packadj_kernel<<<4096, 256, 0, stream>>>(adj,
      (unsigned long long*)(ws + PK_OFF));
  whs_kernel<<<512, 256, 0, stream>>>(x, ws, flagp);
  attn1a_kernel<<<4096, 256, 0, stream>>>(x, ws, flagp);       // xa -> C, mx/rs
  eout_kernel<<<4096, 256, 0, stream>>>(ws, d_out, flagp);     // e_out; rownorm -> B
  colstatsA_kernel<<<64, 256, 0, stream>>>(ws + B_OFF, ws + CS_OFF);
  colstatsB_kernel<<<4, 256, 0, stream>>>(ws + CS_OFF, ws + ST1_OFF);
  gemm_kernel<1,1,0><<<512, 256, 0, stream>>>(ws + B_OFF, wbf + 1*65536,
      ws + BIAS_OFF, ws + ST1_OFF, ws + C_OFF, flagp);
  colstatsA_kernel<<<64, 256, 0, stream>>>(ws + C_OFF, ws + CS_OFF);
  colstatsB_kernel<<<4, 256, 0, stream>>>(ws + CS_OFF, ws + ST2_OFF);
  gemm_kernel<1,0,2><<<512, 256, 0, stream>>>(ws + C_OFF, wbf + 2*65536,
      ws + BIAS_OFF + 256, ws + ST2_OFF, ws + A_OFF, flagp);   // Q fp32 hm
  gemm_kernel<1,0,3><<<512, 256, 0, stream>>>(ws + C_OFF, wbf + 3*65536,
      ws + BIAS_OFF + 512, ws + ST2_OFF, ws + B_OFF, flagp);   // K bf16 hm
  gemm_kernel<2,0,4><<<512, 256, 0, stream>>>(src, wbf + 4*65536,
      ws + BIAS_OFF + 768, nullptr, ws + C_OFF, flagp);        // V^T bf16 hm
  attn2_kernel<<<4096, 256, 0, stream>>>(ws);                  // o -> A_OFF
  gemm_kernel<3,0,1><<<512, 256, 0, stream>>>(ws + A_OFF, wbf + 5*65536,
      ws + BIAS_OFF + 1024, nullptr, d_out, flagp);            // out-proj
}

// Round 4
// 346.086 us; speedup vs baseline: 1.0059x; 1.0059x over previous
//
#include <hip/hip_runtime.h>
#include <hip/hip_bf16.h>

// B=4, N=1024, E=256, H=8, D=32. Float tensors may be bf16 OR fp32 in d_in /
// d_out (detected at runtime on-device); adj is int32.
// Output: x_out [4,1024,256] then e_out [4,1024,1024] (element offsets).
//
// ws float offsets:
//   [0 .. 196608)   : 6 weight matrices, transposed, bf16, quad-interleaved
//                     matrix m at ushort offset m*65536; element (e,o) at
//                     ((e>>2)*256 + o)*4 + (e&3).  m: 0=Wcat 1=LIN 2=WQ 3=WK 4=WV 5=WO
#define BIAS_OFF 196608   // lin_b, bq, bk, bv, bo, a1, a2  (7*256 fp32)
#define S1_OFF   198400   // [h][4096]
#define S2_OFF   231168
#define CS_OFF   263936   // 32768: column partial sums+sumsq (reused twice)
#define ST1_OFF  296704   // mean[1024] + inv[1024]
#define ST2_OFF  298752
#define A_OFF    300800   // WhT bf16 [h][b][d][n] (2 MB) -> later Q,o fp32 head-major
#define MX_OFF   825088   // A_OFF+524288: softmax row max  [h][4096] (dead before Q)
#define RS_OFF   857856   // softmax row 1/sum              [h][4096]
#define PK_OFF   890624   // packed adj bitmask: [4096 rows][16 u64] = 512 KB (dead before Q)
#define B_OFF    1349376  // 4 MB: rownorm(xa)     -> later K bf16 head-major [b][h][n][32]
#define C_OFF    2397952  // 4 MB: raw xa, then rownorm(lin) -> later V^T bf16 hm [b][h][d][n]
#define FLAG_F   3446528  // int: 1 = bf16 tensors, 0 = fp32 tensors
// end 3446529 floats = 13.8 MB

#define NEGC (-9.0e15f)

typedef __attribute__((ext_vector_type(8))) short bf16x8s;
typedef __attribute__((ext_vector_type(4))) float f32x4;

static __device__ __forceinline__ float bf2f(unsigned short u) {
  union { unsigned int i; float f; } v; v.i = ((unsigned int)u) << 16; return v.f;
}
static __device__ __forceinline__ unsigned short f2bf(float f) {
  union { float f; unsigned int u; } v; v.f = f;
  unsigned int r = (v.u + 0x7FFFu + ((v.u >> 16) & 1u)) >> 16;   // RNE
  return (unsigned short)r;
}
static __device__ __forceinline__ float ldin(const void* p, long i, int bf) {
  return bf ? bf2f(((const unsigned short*)p)[i]) : ((const float*)p)[i];
}
static __device__ __forceinline__ unsigned short rdbf(const void* p, long i, int bf) {
  if (bf) return ((const unsigned short*)p)[i];
  return f2bf(((const float*)p)[i]);
}
static __device__ __forceinline__ void stout(void* p, long i, float v, int bf) {
  if (bf) ((unsigned short*)p)[i] = f2bf(v);
  else    ((float*)p)[i] = v;
}

// ---------------- dtype detector -------------------------------------------
__global__ __launch_bounds__(64) void detect_kernel(const unsigned short* x, int* flag) {
  int lane = threadIdx.x;
  unsigned short u = x[2 * lane];
  int e = (u >> 7) & 0xFF;
  bool good = (e >= 100 && e <= 140);
  unsigned long long m = __ballot(good);
  if (lane == 0) *flag = (__popcll(m) >= 48) ? 1 : 0;
}

// ---------------- adj -> bitmask: [row][16 u64], bit m%64 of word m/64 -----
__global__ __launch_bounds__(256) void packadj_kernel(const int* adj,
                                                      unsigned long long* pk) {
  int t = threadIdx.x, w = t >> 6, lane = t & 63;
  long row = blockIdx.x;            // 4096 rows
  #pragma unroll
  for (int j = 0; j < 4; ++j) {
    int m = t + 256*j;              // wave covers bits [w*64+256j .. +63]
    bool bit = adj[row*1024 + m] > 0;
    unsigned long long mask = __ballot(bit);
    if (lane == 0) pk[row*16 + w + 4*j] = mask;
  }
}

// ---------------- prep: weights -> transposed quad bf16; biases -> fp32 ----
__global__ __launch_bounds__(256) void prep_kernel(
    const void* wg, const void* lin_w, const void* inp_w, const void* out_w,
    const void* lin_b, const void* inp_b, const void* out_b,
    const void* a1, const void* a2, float* ws, const int* flagp) {
  const int bf = *flagp;
  unsigned short* wbf = (unsigned short*)ws;
  int t = threadIdx.x;
  int f = blockIdx.x;
  int m = blockIdx.y;
  int dst = m*65536 + ((f >> 2)*256 + t)*4 + (f & 3);
  if (m == 0) {
    int h = t >> 5, d = t & 31;
    wbf[dst] = rdbf(wg, h*8192 + f*32 + d, bf);
  } else if (m == 1) wbf[dst] = rdbf(lin_w, t*256 + f, bf);
  else if (m == 2)   wbf[dst] = rdbf(inp_w, t*256 + f, bf);
  else if (m == 3)   wbf[dst] = rdbf(inp_w, (256 + t)*256 + f, bf);
  else if (m == 4)   wbf[dst] = rdbf(inp_w, (512 + t)*256 + f, bf);
  else if (m == 5)   wbf[dst] = rdbf(out_w, t*256 + f, bf);
  else if (f == 0) {
    ws[BIAS_OFF + t]        = ldin(lin_b, t, bf);
    ws[BIAS_OFF + 256 + t]  = ldin(inp_b, t, bf);
    ws[BIAS_OFF + 512 + t]  = ldin(inp_b, 256 + t, bf);
    ws[BIAS_OFF + 768 + t]  = ldin(inp_b, 512 + t, bf);
    ws[BIAS_OFF + 1024 + t] = ldin(out_b, t, bf);
    ws[BIAS_OFF + 1280 + t] = ldin(a1, t, bf);
    ws[BIAS_OFF + 1536 + t] = ldin(a2, t, bf);
  }
}

// -------- Wh = x @ Wcat -> WhT bf16 [h][b][d][n]; s1/s2 head reductions ----
__global__ __launch_bounds__(256) void whs_kernel(const void* x, float* ws,
                                                  const int* flagp) {
  const int bf = *flagp;
  int t = threadIdx.x;
  int r0 = blockIdx.x * 8;
  __shared__ __align__(16) float U[8][256];
  #pragma unroll
  for (int r = 0; r < 8; ++r)
    U[r][t] = ldin(x, (long)(r0 + r)*256 + t, bf);
  __syncthreads();
  const ushort4* w4 = (const ushort4*)ws;
  float acc[8] = {0,0,0,0,0,0,0,0};
  for (int e4 = 0; e4 < 64; ++e4) {
    ushort4 u = w4[e4*256 + t];
    float w0 = bf2f(u.x), w1 = bf2f(u.y), w2 = bf2f(u.z), w3 = bf2f(u.w);
    #pragma unroll
    for (int r = 0; r < 8; ++r) {
      float4 uu = *(const float4*)&U[r][e4*4];
      acc[r] += uu.x*w0 + uu.y*w1 + uu.z*w2 + uu.w*w3;
    }
  }
  int h = t >> 5, d = t & 31;
  float a1v = ws[BIAS_OFF + 1280 + t];
  float a2v = ws[BIAS_OFF + 1536 + t];
  unsigned short wvals[8];
  #pragma unroll
  for (int r = 0; r < 8; ++r) {
    int row = r0 + r;
    wvals[r] = f2bf(acc[r]);
    float p1 = acc[r]*a1v, p2 = acc[r]*a2v;
    #pragma unroll
    for (int off = 16; off > 0; off >>= 1) {
      p1 += __shfl_xor(p1, off, 32);
      p2 += __shfl_xor(p2, off, 32);
    }
    if (d == 0) {
      ws[S1_OFF + h*4096 + row] = p1;
      ws[S2_OFF + h*4096 + row] = p2;
    }
  }
  // WhT[h][b][d][n], 8 contiguous n per thread (16B store)
  {
    unsigned short* wht = (unsigned short*)(ws + A_OFF);
    int bb = r0 >> 10, nn = r0 & 1023;
    *(bf16x8s*)(wht + ((long)((h*4 + bb)*32 + d))*1024 + nn) = *(bf16x8s*)wvals;
  }
}

// ------- graph attention, head-split, 8 rows/block -------------------------
// Grid 4096 = 4b x 128 groups x 8h; h in low 3 bits (XCD-L2 locality on WhT).
// adj from packed bitmask (scalar loads). Softmax register-resident: wave w
// owns rows w and w+4 (sequential). P bf16 in Pb (8 real rows, dup x2 in the
// 16-row MFMA A-tile). PV via mfma_f32_16x16x32_bf16 against WhT. Writes:
//   C region: raw xa slice  xa[b,n,h*32+d] = x + leaky(PV)
//   MX/RS: per-(h,row) softmax max and 1/sum (consumed by eout_kernel)
#define PB_S 1032    // Pb row stride (ushorts); 2064B = 129*16, rows +4 banks
__global__ __launch_bounds__(256) void attn1a_kernel(const void* x, float* ws,
                                                     const int* flagp) {
  const int bf = *flagp;
  int t = threadIdx.x;
  int gid = blockIdx.x;
  int h = gid & 7;
  int b = (gid >> 3) & 3;
  int n0 = (gid >> 5) * 8;
  __shared__ __align__(16) float s2s[1024];
  __shared__ __align__(16) unsigned short Pb[8][PB_S];
  __shared__ __align__(16) float opart[4][8][16];
  int w = t >> 6, lane = t & 63;
  int fm = lane & 15, quad = lane >> 4;
  const unsigned long long* pk = (const unsigned long long*)(ws + PK_OFF);
  const float* s2p = ws + S2_OFF + h*4096 + b*1024;
  #pragma unroll
  for (int j = 0; j < 4; ++j) s2s[t + 256*j] = s2p[t + 256*j];
  __syncthreads();
  // ---- softmax rows (n0+w) and (n0+w+4), head h: register resident --------
  #pragma unroll
  for (int rr = 0; rr < 2; ++rr) {
    int r = w + 4*rr;
    int rowi = __builtin_amdgcn_readfirstlane(b*1024 + n0 + r);
    const unsigned long long* prow = pk + (long)rowi * 16;   // wave-uniform
    float s1v = ws[S1_OFF + h*4096 + rowi];
    float p[16];
    float mx = -3.4e38f;
    #pragma unroll
    for (int j = 0; j < 16; ++j) {
      int m = lane + 64*j;
      float ev = s1v + s2s[m];
      ev = (ev >= 0.0f) ? ev : 0.1f*ev;
      ev = ((prow[j] >> lane) & 1ull) ? ev : NEGC;
      p[j] = ev;
      mx = fmaxf(mx, ev);
    }
    #pragma unroll
    for (int off = 32; off > 0; off >>= 1) mx = fmaxf(mx, __shfl_xor(mx, off));
    float s = 0.0f;
    #pragma unroll
    for (int j = 0; j < 16; ++j) { p[j] = __expf(p[j] - mx); s += p[j]; }
    #pragma unroll
    for (int off = 32; off > 0; off >>= 1) s += __shfl_xor(s, off);
    float rs = 1.0f / s;
    #pragma unroll
    for (int j = 0; j < 16; ++j)
      Pb[r][lane + 64*j] = f2bf(p[j] * rs);
    if (lane == 0) {
      ws[MX_OFF + h*4096 + rowi] = mx;
      ws[RS_OFF + h*4096 + rowi] = rs;
    }
  }
  __syncthreads();
  // ---- PV via MFMA: wave w -> ntile (w&1), k-tiles (w>>1)*16 .. +15 -------
  {
    const unsigned short* wht = (const unsigned short*)(ws + A_OFF);
    int ntile = w & 1;
    int ktbase = (w >> 1) * 16;
    int vd = ntile*16 + fm;
    const unsigned short* wrow = wht + ((long)((h*4 + b)*32 + vd))*1024;
    f32x4 acc0 = {0.0f, 0.0f, 0.0f, 0.0f};
    f32x4 acc1 = {0.0f, 0.0f, 0.0f, 0.0f};
    #pragma unroll
    for (int kt2 = 0; kt2 < 8; ++kt2) {
      int kt = ktbase + 2*kt2;
      bf16x8s ap0 = *(const bf16x8s*)&Pb[fm & 7][kt*32 + quad*8];
      bf16x8s bw0 = *(const bf16x8s*)(wrow + kt*32 + quad*8);
      acc0 = __builtin_amdgcn_mfma_f32_16x16x32_bf16(ap0, bw0, acc0, 0, 0, 0);
      bf16x8s ap1 = *(const bf16x8s*)&Pb[fm & 7][(kt+1)*32 + quad*8];
      bf16x8s bw1 = *(const bf16x8s*)(wrow + (kt+1)*32 + quad*8);
      acc1 = __builtin_amdgcn_mfma_f32_16x16x32_bf16(ap1, bw1, acc1, 0, 0, 0);
    }
    f32x4 acc = acc0 + acc1;
    if (quad < 2) {             // D rows 0..7 are the real query rows
      #pragma unroll
      for (int i = 0; i < 4; ++i) opart[w][quad*4 + i][fm] = acc[i];
    }
  }
  __syncthreads();
  {
    int r = t >> 5, dd = t & 31;
    int nt = dd >> 4, c = dd & 15;
    float sum = opart[nt][r][c] + opart[nt + 2][r][c];
    float hv = (sum >= 0.0f) ? sum : 0.01f*sum;
    long idx = (long)(b*1024 + n0 + r)*256 + h*32 + dd;
    ws[C_OFF + idx] = ldin(x, idx, bf) + hv;   // raw residual row slice
  }
}

// ------- e_out = mean_h attn (from stored mx/rs) + fused rownorm(xa) -------
// Grid 4096: one (b,n) row per block. Rownorm reads raw xa (C region), writes
// B region. e_out recomputed from s1/s2/packed-adj + per-head mx/rs (exact
// same arithmetic/order as before: sum over h of rs*exp(lrelu(s1+s2)-mx)).
__global__ __launch_bounds__(256) void eout_kernel(float* ws, void* dout,
                                                   const int* flagp) {
  const int bf = *flagp;
  int t = threadIdx.x;
  int gid = blockIdx.x;
  int b = gid & 3;
  int n = gid >> 2;
  int row = b*1024 + n;
  int w = t >> 6, lane = t & 63;
  __shared__ float part[8];
  const unsigned long long* pk = (const unsigned long long*)(ws + PK_OFF);
  const unsigned long long* prow = pk + (long)row * 16;
  // ---- rownorm (ddof=1, two-pass) of raw xa row ---------------------------
  float v = ws[C_OFF + (long)row*256 + t];
  float s = v;
  #pragma unroll
  for (int off = 32; off > 0; off >>= 1) s += __shfl_xor(s, off);
  if (lane == 0) part[w] = s;
  __syncthreads();
  float mean = (part[0] + part[1] + part[2] + part[3]) * (1.0f/256.0f);
  float d = v - mean;
  float ss = d*d;
  #pragma unroll
  for (int off = 32; off > 0; off >>= 1) ss += __shfl_xor(ss, off);
  if (lane == 0) part[4 + w] = ss;
  __syncthreads();
  float inv = 1.0f / (sqrtf((part[4]+part[5]+part[6]+part[7]) * (1.0f/255.0f)) + 1e-6f);
  ws[B_OFF + (long)row*256 + t] = d * inv;
  // ---- e_out --------------------------------------------------------------
  float s1v[8], mxv[8], rsv[8];
  #pragma unroll
  for (int h = 0; h < 8; ++h) {
    s1v[h] = ws[S1_OFF + h*4096 + row];
    mxv[h] = ws[MX_OFF + h*4096 + row];
    rsv[h] = ws[RS_OFF + h*4096 + row];
  }
  const float* s2b = ws + S2_OFF + b*1024;
  #pragma unroll
  for (int j = 0; j < 4; ++j) {
    int m = t + 256*j;
    bool a = (prow[w + 4*j] >> lane) & 1ull;   // bit m: word (m>>6)=w+4j, bit lane
    float acc = 0.0f;
    #pragma unroll
    for (int h = 0; h < 8; ++h) {
      float ev = s1v[h] + s2b[h*4096 + m];
      ev = (ev >= 0.0f) ? ev : 0.1f*ev;
      ev = a ? ev : NEGC;
      acc += rsv[h] * __expf(ev - mxv[h]);
    }
    stout(dout, 1048576L + (long)row*1024 + m, 0.125f*acc, bf);
  }
}

// ---------------- column (axis=1) stats, ddof=1 ----------------------------
__global__ __launch_bounds__(256) void colstatsA_kernel(const float* in, float* cs) {
  int t = threadIdx.x;
  int j = blockIdx.x & 15;
  int b = blockIdx.x >> 4;
  float s = 0, ss = 0;
  for (int n = j*64; n < j*64 + 64; ++n) {
    float v = in[(b*1024 + n)*256 + t];
    s += v; ss += v*v;
  }
  cs[(b*16 + j)*256 + t] = s;
  cs[16384 + (b*16 + j)*256 + t] = ss;
}

__global__ __launch_bounds__(256) void colstatsB_kernel(const float* cs, float* st) {
  int t = threadIdx.x;
  int b = blockIdx.x;
  float s = 0, ss = 0;
  for (int j = 0; j < 16; ++j) {
    s  += cs[(b*16 + j)*256 + t];
    ss += cs[16384 + (b*16 + j)*256 + t];
  }
  float mean = s * (1.0f/1024.0f);
  float var = fmaxf((ss - s*mean) * (1.0f/1023.0f), 0.0f);
  st[b*256 + t] = mean;
  st[1024 + b*256 + t] = 1.0f / (sqrtf(var) + 1e-6f);
}

// ---------------- row GEMM, bf16 quad weights ------------------------------
// IN_MODE 0: plain fp32 [row][256]; 1: fp32 + colnorm(st); 2: float-input src
//   permuted (n,b,e)->(b,n,e); 3: fp32 head-major [b][h][n][32]
// RN 1: fused rownorm on output
// OUTM 0: fp32 [row][256]; 1: d_out (dtype per flag); 2: fp32 head-major;
//      3: bf16 head-major; 4: bf16 TRANSPOSED head-major [b][h][d][n]
template<int IN_MODE, int RN, int OUTM>
__global__ __launch_bounds__(256) void gemm_kernel(const void* inp,
    const unsigned short* wmat, const float* bias, const float* st, void* outp,
    const int* flagp) {
  const int bf = *flagp;
  int t = threadIdx.x;
  int r0 = blockIdx.x * 8;
  __shared__ __align__(16) float U[8][256];
  #pragma unroll
  for (int r = 0; r < 8; ++r) {
    int row = r0 + r;
    float v;
    if (IN_MODE == 0) {
      v = ((const float*)inp)[row*256 + t];
    } else if (IN_MODE == 1) {
      int b = row >> 10;
      v = (((const float*)inp)[row*256 + t] - st[b*256 + t]) * st[1024 + b*256 + t];
    } else if (IN_MODE == 2) {
      int b = row >> 10, n = row & 1023;
      v = ldin(inp, (long)(n*4 + b)*256 + t, bf);
    } else {
      int b = row >> 10, n = row & 1023;
      v = ((const float*)inp)[((b*8 + (t >> 5))*1024 + n)*32 + (t & 31)];
    }
    U[r][t] = v;
  }
  __syncthreads();
  float bv = bias[t];
  float acc[8];
  #pragma unroll
  for (int r = 0; r < 8; ++r) acc[r] = bv;
  const ushort4* w4 = (const ushort4*)wmat;
  for (int e4 = 0; e4 < 64; ++e4) {
    ushort4 u = w4[e4*256 + t];
    float w0 = bf2f(u.x), w1 = bf2f(u.y), w2 = bf2f(u.z), w3 = bf2f(u.w);
    #pragma unroll
    for (int r = 0; r < 8; ++r) {
      float4 uu = *(const float4*)&U[r][e4*4];
      acc[r] += uu.x*w0 + uu.y*w1 + uu.z*w2 + uu.w*w3;
    }
  }
  if (RN == 0) {
    #pragma unroll
    for (int r = 0; r < 8; ++r) {
      int row = r0 + r;
      if (OUTM == 0) ((float*)outp)[row*256 + t] = acc[r];
      else if (OUTM == 1) stout(outp, (long)row*256 + t, acc[r], bf);
      else if (OUTM == 2) {
        int b = row >> 10, n = row & 1023;
        ((float*)outp)[((b*8 + (t >> 5))*1024 + n)*32 + (t & 31)] = acc[r];
      } else if (OUTM == 3) {
        int b = row >> 10, n = row & 1023;
        ((unsigned short*)outp)[((b*8 + (t >> 5))*1024 + n)*32 + (t & 31)] = f2bf(acc[r]);
      } else {
        int b = row >> 10, n = row & 1023;
        ((unsigned short*)outp)[((b*8 + (t >> 5))*32 + (t & 31))*1024 + n] = f2bf(acc[r]);
      }
    }
  } else {
    __syncthreads();
    #pragma unroll
    for (int r = 0; r < 8; ++r) U[r][t] = acc[r];
    __syncthreads();
    int w = t >> 6, lane = t & 63;
    for (int rr = w; rr < 8; rr += 4) {
      float vals[4]; float s = 0.0f;
      #pragma unroll
      for (int j = 0; j < 4; ++j) { vals[j] = U[rr][lane + 64*j]; s += vals[j]; }
      #pragma unroll
      for (int off = 32; off > 0; off >>= 1) s += __shfl_xor(s, off);
      float mean = s * (1.0f/256.0f);
      float ss = 0.0f;
      #pragma unroll
      for (int j = 0; j < 4; ++j) { float d = vals[j] - mean; ss += d*d; }
      #pragma unroll
      for (int off = 32; off > 0; off >>= 1) ss += __shfl_xor(ss, off);
      float inv = 1.0f / (sqrtf(ss * (1.0f/255.0f)) + 1e-6f);
      #pragma unroll
      for (int j = 0; j < 4; ++j)
        ((float*)outp)[(r0 + rr)*256 + lane + 64*j] = (vals[j] - mean) * inv;
    }
  }
}

// ---------------- MHA via MFMA, bf16 K/V, 8 q-rows per block ---------------
// GRID MUST BE 4096, BLOCK 512 (8 waves): 128 row-groups x 4 b x 8 h.
// h in low 3 bits (XCD-L2). Q fp32 head-major [b][h][n][32] at A_OFF
// (o overwrites q, exclusive slots); K bf16 [b][h][n][32] at B_OFF;
// V^T bf16 [b][h][d][n] at C_OFF.
// 8-wave split: QK wave w covers keys w*128..+127 (8 MFMAs); softmax wave w
// owns row w exactly; PV wave w = (ktq=w>>1)*2 + (ntile=w&1): 8 key-chunks
// of 32, d-tile ntile; opart reduced over the 4 ktq partials.
// LDS 37 KB -> 4 blocks/CU x 8 waves = 32 waves/CU (100% cap); VGPR ~52.
// S in LDS fp32, stride 1032 (8-bank row shift; all accesses <=2-way).
// Softmax single pass in regs, normalized P written back bf16 IN-PLACE
// (bf16 row overlay = first 2 KB of the row's 4.1 KB footprint; write vals
// depend on all reads; rows are wave-private). PV reads P via ds_read_b128.
// mfma_f32_16x16x32_bf16 layouts (m89-verified):
//   A[m=lane&15][k=(lane>>4)*8+j]; B[k=(lane>>4)*8+j][n=lane&15];
//   D col=lane&15, row=(lane>>4)*4+i.
#define SP_RS2 1032
__global__ __launch_bounds__(512) void attn2_kernel(float* ws) {
  int t = threadIdx.x;
  int gid = blockIdx.x;
  int h = gid & 7;
  int b = (gid >> 3) & 3;
  int n0 = (gid >> 5) << 3;   // 8 q-rows per block; gid>>5 in 0..127
  __shared__ __align__(16) float Sp[8*SP_RS2];     // 33 KB
  __shared__ __align__(16) float opart[8][8][16];  // 4 KB
  float* qq = ws + A_OFF;
  const unsigned short* kk = (const unsigned short*)(ws + B_OFF);
  const unsigned short* vt = (const unsigned short*)(ws + C_OFF);
  int base_bh = (b*8 + h)*1024;
  int w = t >> 6, lane = t & 63;   // w 0..7
  int m = lane & 15, quad = lane >> 4;
  const float scl = 0.17677669529663687f; // 1/sqrt(32)
  // ---- QK via MFMA: wave w covers keys w*128 .. +127 ----------------------
  {
    const float* qp = qq + (base_bh + n0 + (lane & 7))*32 + quad*8;
    bf16x8s aq;
    #pragma unroll
    for (int j = 0; j < 8; ++j) ((unsigned short*)&aq)[j] = f2bf(qp[j]);
    f32x4 zero = {0.0f, 0.0f, 0.0f, 0.0f};
    #pragma unroll
    for (int kt = 0; kt < 8; ++kt) {
      int kbase = w*128 + kt*16;
      bf16x8s bk = *(const bf16x8s*)(kk + (base_bh + kbase + m)*32 + quad*8);
      f32x4 d = __builtin_amdgcn_mfma_f32_16x16x32_bf16(aq, bk, zero, 0, 0, 0);
      if (lane < 32) {
        int key = kbase + m;
        #pragma unroll
        for (int i = 0; i < 4; ++i)
          Sp[(quad*4 + i)*SP_RS2 + key] = d[i] * scl;
      }
    }
  }
  __syncthreads();
  // ---- softmax: wave w owns row w; single pass, bf16 overlay --------------
  {
    float* Sr = Sp + w*SP_RS2;
    float p[16];
    #pragma unroll
    for (int j = 0; j < 16; ++j) p[j] = Sr[lane + 64*j];
    float mx = -3.4e38f;
    #pragma unroll
    for (int j = 0; j < 16; ++j) mx = fmaxf(mx, p[j]);
    #pragma unroll
    for (int off = 32; off > 0; off >>= 1) mx = fmaxf(mx, __shfl_xor(mx, off));
    float s = 0.0f;
    #pragma unroll
    for (int j = 0; j < 16; ++j) { p[j] = __expf(p[j] - mx); s += p[j]; }
    #pragma unroll
    for (int off = 32; off > 0; off >>= 1) s += __shfl_xor(s, off);
    float rs = 1.0f / s;
    unsigned short* Pr = (unsigned short*)Sr;     // bf16 overlay, same row
    #pragma unroll
    for (int j = 0; j < 16; ++j)
      Pr[lane + 64*j] = f2bf(p[j] * rs);
  }
  __syncthreads();
  // ---- PV via MFMA: wave w -> d-tile (w&1), key-chunks (w>>1)*8 .. +7 -----
  {
    int ntile = w & 1;
    int ktbase = (w >> 1) * 8;
    int vd = ntile*16 + m;
    const unsigned short* vrow = vt + base_bh*32 + vd*1024;
    const unsigned short* Pbase = (const unsigned short*)(Sp + (lane & 7)*SP_RS2);
    f32x4 acc0 = {0.0f, 0.0f, 0.0f, 0.0f};
    f32x4 acc1 = {0.0f, 0.0f, 0.0f, 0.0f};
    #pragma unroll
    for (int kt2 = 0; kt2 < 4; ++kt2) {
      int kt = ktbase + 2*kt2;
      bf16x8s ap0 = *(const bf16x8s*)(Pbase + kt*32 + quad*8);
      bf16x8s bv0 = *(const bf16x8s*)(vrow + kt*32 + quad*8);
      acc0 = __builtin_amdgcn_mfma_f32_16x16x32_bf16(ap0, bv0, acc0, 0, 0, 0);
      bf16x8s ap1 = *(const bf16x8s*)(Pbase + (kt+1)*32 + quad*8);
      bf16x8s bv1 = *(const bf16x8s*)(vrow + (kt+1)*32 + quad*8);
      acc1 = __builtin_amdgcn_mfma_f32_16x16x32_bf16(ap1, bv1, acc1, 0, 0, 0);
    }
    f32x4 acc = acc0 + acc1;
    if (lane < 32) {
      #pragma unroll
      for (int i = 0; i < 4; ++i)
        opart[w][quad*4 + i][m] = acc[i];
    }
  }
  __syncthreads();
  if (t < 256) {
    int r = t >> 5, d = t & 31;
    int nt = d >> 4, c = d & 15;
    float sum = opart[nt][r][c] + opart[nt + 2][r][c]
              + opart[nt + 4][r][c] + opart[nt + 6][r][c];
    qq[(base_bh + n0 + r)*32 + d] = sum;   // o over q (own slots)
  }
}

extern "C" void kernel_launch(void* const* d_in, const int* in_sizes, int n_in,
                              void* d_out, int out_size, void* d_ws, size_t ws_size,
                              hipStream_t stream) {
  const void* x   = d_in[0];
  const void* src = d_in[1];
  const int* adj  = (const int*)d_in[2];
  const void* wg  = d_in[3];
  const void* a1  = d_in[4];
  const void* a2  = d_in[5];
  const void* lw  = d_in[6];
  const void* lb  = d_in[7];
  const void* ipw = d_in[8];
  const void* ipb = d_in[9];
  const void* opw = d_in[10];
  const void* opb = d_in[11];
  float* ws = (float*)d_ws;
  const unsigned short* wbf = (const unsigned short*)d_ws;
  int* flagp = (int*)(ws + FLAG_F);

  detect_kernel<<<1, 64, 0, stream>>>((const unsigned short*)x, flagp);
  prep_kernel<<<dim3(256, 7), 256, 0, stream>>>(wg, lw, ipw, opw, lb, ipb, opb,
                                                a1, a2, ws, flagp);
  packadj_kernel<<<4096, 256, 0, stream>>>(adj,
      (unsigned long long*)(ws + PK_OFF));
  whs_kernel<<<512, 256, 0, stream>>>(x, ws, flagp);
  attn1a_kernel<<<4096, 256, 0, stream>>>(x, ws, flagp);       // xa -> C, mx/rs
  eout_kernel<<<4096, 256, 0, stream>>>(ws, d_out, flagp);     // e_out; rownorm -> B
  colstatsA_kernel<<<64, 256, 0, stream>>>(ws + B_OFF, ws + CS_OFF);
  colstatsB_kernel<<<4, 256, 0, stream>>>(ws + CS_OFF, ws + ST1_OFF);
  gemm_kernel<1,1,0><<<512, 256, 0, stream>>>(ws + B_OFF, wbf + 1*65536,
      ws + BIAS_OFF, ws + ST1_OFF, ws + C_OFF, flagp);
  colstatsA_kernel<<<64, 256, 0, stream>>>(ws + C_OFF, ws + CS_OFF);
  colstatsB_kernel<<<4, 256, 0, stream>>>(ws + CS_OFF, ws + ST2_OFF);
  gemm_kernel<1,0,2><<<512, 256, 0, stream>>>(ws + C_OFF, wbf + 2*65536,
      ws + BIAS_OFF + 256, ws + ST2_OFF, ws + A_OFF, flagp);   // Q fp32 hm
  gemm_kernel<1,0,3><<<512, 256, 0, stream>>>(ws + C_OFF, wbf + 3*65536,
      ws + BIAS_OFF + 512, ws + ST2_OFF, ws + B_OFF, flagp);   // K bf16 hm
  gemm_kernel<2,0,4><<<512, 256, 0, stream>>>(src, wbf + 4*65536,
      ws + BIAS_OFF + 768, nullptr, ws + C_OFF, flagp);        // V^T bf16 hm
  attn2_kernel<<<4096, 512, 0, stream>>>(ws);                  // o -> A_OFF
  gemm_kernel<3,0,1><<<512, 256, 0, stream>>>(ws + A_OFF, wbf + 5*65536,
      ws + BIAS_OFF + 1024, nullptr, d_out, flagp);            // out-proj
}

// Round 5
// 309.879 us; speedup vs baseline: 1.1234x; 1.1168x over previous
//
#include <hip/hip_runtime.h>
#include <hip/hip_bf16.h>

// B=4, N=1024, E=256, H=8, D=32. Float tensors may be bf16 OR fp32 in d_in /
// d_out (detected at runtime on-device); adj is int32.
// Output: x_out [4,1024,256] then e_out [4,1024,1024] (element offsets).
//
// ws float offsets:
//   [0 .. 196608)   : 6 weight matrices, transposed, bf16, quad-interleaved
//                     matrix m at ushort offset m*65536; element (e,o) at
//                     ((e>>2)*256 + o)*4 + (e&3).  m: 0=Wcat 1=LIN 2=WQ 3=WK 4=WV 5=WO
#define BIAS_OFF 196608   // lin_b, bq, bk, bv, bo, a1, a2  (7*256 fp32)
#define S1_OFF   198400   // [h][4096]
#define S2_OFF   231168
#define CS_OFF   263936   // 32768: column partial sums+sumsq (reused twice)
#define ST1_OFF  296704   // mean[1024] + inv[1024]
#define ST2_OFF  298752
#define A_OFF    300800   // WhT bf16 [h][b][d][n] (2 MB) -> later Q,o fp32 head-major
#define MX_OFF   825088   // A_OFF+524288: softmax row max  [h][4096] (dead before Q)
#define RS_OFF   857856   // softmax row 1/sum              [h][4096]
#define PK_OFF   890624   // packed adj bitmask: [4096 rows][16 u64] = 512 KB (dead before Q)
#define B_OFF    1349376  // 4 MB: rownorm(xa)     -> later K bf16 head-major [b][h][n][32]
#define C_OFF    2397952  // 4 MB: raw xa, then rownorm(lin) -> later V^T bf16 hm [b][h][d][n]
#define FLAG_F   3446528  // int: 1 = bf16 tensors, 0 = fp32 tensors
// end 3446529 floats = 13.8 MB

#define NEGC (-9.0e15f)

typedef __attribute__((ext_vector_type(8))) short bf16x8s;
typedef __attribute__((ext_vector_type(4))) float f32x4;

static __device__ __forceinline__ float bf2f(unsigned short u) {
  union { unsigned int i; float f; } v; v.i = ((unsigned int)u) << 16; return v.f;
}
static __device__ __forceinline__ unsigned short f2bf(float f) {
  union { float f; unsigned int u; } v; v.f = f;
  unsigned int r = (v.u + 0x7FFFu + ((v.u >> 16) & 1u)) >> 16;   // RNE
  return (unsigned short)r;
}
static __device__ __forceinline__ float ldin(const void* p, long i, int bf) {
  return bf ? bf2f(((const unsigned short*)p)[i]) : ((const float*)p)[i];
}
static __device__ __forceinline__ unsigned short rdbf(const void* p, long i, int bf) {
  if (bf) return ((const unsigned short*)p)[i];
  return f2bf(((const float*)p)[i]);
}
static __device__ __forceinline__ void stout(void* p, long i, float v, int bf) {
  if (bf) ((unsigned short*)p)[i] = f2bf(v);
  else    ((float*)p)[i] = v;
}

// ---------------- dtype detector -------------------------------------------
__global__ __launch_bounds__(64) void detect_kernel(const unsigned short* x, int* flag) {
  int lane = threadIdx.x;
  unsigned short u = x[2 * lane];
  int e = (u >> 7) & 0xFF;
  bool good = (e >= 100 && e <= 140);
  unsigned long long m = __ballot(good);
  if (lane == 0) *flag = (__popcll(m) >= 48) ? 1 : 0;
}

// ---------------- adj -> bitmask: [row][16 u64], bit m%64 of word m/64 -----
__global__ __launch_bounds__(256) void packadj_kernel(const int* adj,
                                                      unsigned long long* pk) {
  int t = threadIdx.x, w = t >> 6, lane = t & 63;
  long row = blockIdx.x;            // 4096 rows
  #pragma unroll
  for (int j = 0; j < 4; ++j) {
    int m = t + 256*j;              // wave covers bits [w*64+256j .. +63]
    bool bit = adj[row*1024 + m] > 0;
    unsigned long long mask = __ballot(bit);
    if (lane == 0) pk[row*16 + w + 4*j] = mask;
  }
}

// ---------------- prep: weights -> transposed quad bf16; biases -> fp32 ----
__global__ __launch_bounds__(256) void prep_kernel(
    const void* wg, const void* lin_w, const void* inp_w, const void* out_w,
    const void* lin_b, const void* inp_b, const void* out_b,
    const void* a1, const void* a2, float* ws, const int* flagp) {
  const int bf = *flagp;
  unsigned short* wbf = (unsigned short*)ws;
  int t = threadIdx.x;
  int f = blockIdx.x;
  int m = blockIdx.y;
  int dst = m*65536 + ((f >> 2)*256 + t)*4 + (f & 3);
  if (m == 0) {
    int h = t >> 5, d = t & 31;
    wbf[dst] = rdbf(wg, h*8192 + f*32 + d, bf);
  } else if (m == 1) wbf[dst] = rdbf(lin_w, t*256 + f, bf);
  else if (m == 2)   wbf[dst] = rdbf(inp_w, t*256 + f, bf);
  else if (m == 3)   wbf[dst] = rdbf(inp_w, (256 + t)*256 + f, bf);
  else if (m == 4)   wbf[dst] = rdbf(inp_w, (512 + t)*256 + f, bf);
  else if (m == 5)   wbf[dst] = rdbf(out_w, t*256 + f, bf);
  else if (f == 0) {
    ws[BIAS_OFF + t]        = ldin(lin_b, t, bf);
    ws[BIAS_OFF + 256 + t]  = ldin(inp_b, t, bf);
    ws[BIAS_OFF + 512 + t]  = ldin(inp_b, 256 + t, bf);
    ws[BIAS_OFF + 768 + t]  = ldin(inp_b, 512 + t, bf);
    ws[BIAS_OFF + 1024 + t] = ldin(out_b, t, bf);
    ws[BIAS_OFF + 1280 + t] = ldin(a1, t, bf);
    ws[BIAS_OFF + 1536 + t] = ldin(a2, t, bf);
  }
}

// -------- Wh = x @ Wcat -> WhT bf16 [h][b][d][n]; s1/s2 head reductions ----
__global__ __launch_bounds__(256) void whs_kernel(const void* x, float* ws,
                                                  const int* flagp) {
  const int bf = *flagp;
  int t = threadIdx.x;
  int r0 = blockIdx.x * 8;
  __shared__ __align__(16) float U[8][256];
  #pragma unroll
  for (int r = 0; r < 8; ++r)
    U[r][t] = ldin(x, (long)(r0 + r)*256 + t, bf);
  __syncthreads();
  const ushort4* w4 = (const ushort4*)ws;
  float acc[8] = {0,0,0,0,0,0,0,0};
  for (int e4 = 0; e4 < 64; ++e4) {
    ushort4 u = w4[e4*256 + t];
    float w0 = bf2f(u.x), w1 = bf2f(u.y), w2 = bf2f(u.z), w3 = bf2f(u.w);
    #pragma unroll
    for (int r = 0; r < 8; ++r) {
      float4 uu = *(const float4*)&U[r][e4*4];
      acc[r] += uu.x*w0 + uu.y*w1 + uu.z*w2 + uu.w*w3;
    }
  }
  int h = t >> 5, d = t & 31;
  float a1v = ws[BIAS_OFF + 1280 + t];
  float a2v = ws[BIAS_OFF + 1536 + t];
  unsigned short wvals[8];
  #pragma unroll
  for (int r = 0; r < 8; ++r) {
    int row = r0 + r;
    wvals[r] = f2bf(acc[r]);
    float p1 = acc[r]*a1v, p2 = acc[r]*a2v;
    #pragma unroll
    for (int off = 16; off > 0; off >>= 1) {
      p1 += __shfl_xor(p1, off, 32);
      p2 += __shfl_xor(p2, off, 32);
    }
    if (d == 0) {
      ws[S1_OFF + h*4096 + row] = p1;
      ws[S2_OFF + h*4096 + row] = p2;
    }
  }
  // WhT[h][b][d][n], 8 contiguous n per thread (16B store)
  {
    unsigned short* wht = (unsigned short*)(ws + A_OFF);
    int bb = r0 >> 10, nn = r0 & 1023;
    *(bf16x8s*)(wht + ((long)((h*4 + bb)*32 + d))*1024 + nn) = *(bf16x8s*)wvals;
  }
}

// ------- graph attention, head-split, 8 rows/block -------------------------
// Grid 4096 = 4b x 128 groups x 8h; h in low 3 bits (XCD-L2 locality on WhT).
// adj from packed bitmask (scalar loads). Softmax register-resident: wave w
// owns rows w and w+4 (sequential). P bf16 in Pb (8 real rows, dup x2 in the
// 16-row MFMA A-tile). PV via mfma_f32_16x16x32_bf16 against WhT. Writes:
//   C region: raw xa slice  xa[b,n,h*32+d] = x + leaky(PV)
//   MX/RS: per-(h,row) softmax max and 1/sum (consumed by eout_kernel)
#define PB_S 1032    // Pb row stride (ushorts); 2064B = 129*16, rows +4 banks
__global__ __launch_bounds__(256) void attn1a_kernel(const void* x, float* ws,
                                                     const int* flagp) {
  const int bf = *flagp;
  int t = threadIdx.x;
  int gid = blockIdx.x;
  int h = gid & 7;
  int b = (gid >> 3) & 3;
  int n0 = (gid >> 5) * 8;
  __shared__ __align__(16) float s2s[1024];
  __shared__ __align__(16) unsigned short Pb[8][PB_S];
  __shared__ __align__(16) float opart[4][8][16];
  int w = t >> 6, lane = t & 63;
  int fm = lane & 15, quad = lane >> 4;
  const unsigned long long* pk = (const unsigned long long*)(ws + PK_OFF);
  const float* s2p = ws + S2_OFF + h*4096 + b*1024;
  #pragma unroll
  for (int j = 0; j < 4; ++j) s2s[t + 256*j] = s2p[t + 256*j];
  __syncthreads();
  // ---- softmax rows (n0+w) and (n0+w+4), head h: register resident --------
  #pragma unroll
  for (int rr = 0; rr < 2; ++rr) {
    int r = w + 4*rr;
    int rowi = __builtin_amdgcn_readfirstlane(b*1024 + n0 + r);
    const unsigned long long* prow = pk + (long)rowi * 16;   // wave-uniform
    float s1v = ws[S1_OFF + h*4096 + rowi];
    float p[16];
    float mx = -3.4e38f;
    #pragma unroll
    for (int j = 0; j < 16; ++j) {
      int m = lane + 64*j;
      float ev = s1v + s2s[m];
      ev = (ev >= 0.0f) ? ev : 0.1f*ev;
      ev = ((prow[j] >> lane) & 1ull) ? ev : NEGC;
      p[j] = ev;
      mx = fmaxf(mx, ev);
    }
    #pragma unroll
    for (int off = 32; off > 0; off >>= 1) mx = fmaxf(mx, __shfl_xor(mx, off));
    float s = 0.0f;
    #pragma unroll
    for (int j = 0; j < 16; ++j) { p[j] = __expf(p[j] - mx); s += p[j]; }
    #pragma unroll
    for (int off = 32; off > 0; off >>= 1) s += __shfl_xor(s, off);
    float rs = 1.0f / s;
    #pragma unroll
    for (int j = 0; j < 16; ++j)
      Pb[r][lane + 64*j] = f2bf(p[j] * rs);
    if (lane == 0) {
      ws[MX_OFF + h*4096 + rowi] = mx;
      ws[RS_OFF + h*4096 + rowi] = rs;
    }
  }
  __syncthreads();
  // ---- PV via MFMA: wave w -> ntile (w&1), k-tiles (w>>1)*16 .. +15 -------
  {
    const unsigned short* wht = (const unsigned short*)(ws + A_OFF);
    int ntile = w & 1;
    int ktbase = (w >> 1) * 16;
    int vd = ntile*16 + fm;
    const unsigned short* wrow = wht + ((long)((h*4 + b)*32 + vd))*1024;
    f32x4 acc0 = {0.0f, 0.0f, 0.0f, 0.0f};
    f32x4 acc1 = {0.0f, 0.0f, 0.0f, 0.0f};
    #pragma unroll
    for (int kt2 = 0; kt2 < 8; ++kt2) {
      int kt = ktbase + 2*kt2;
      bf16x8s ap0 = *(const bf16x8s*)&Pb[fm & 7][kt*32 + quad*8];
      bf16x8s bw0 = *(const bf16x8s*)(wrow + kt*32 + quad*8);
      acc0 = __builtin_amdgcn_mfma_f32_16x16x32_bf16(ap0, bw0, acc0, 0, 0, 0);
      bf16x8s ap1 = *(const bf16x8s*)&Pb[fm & 7][(kt+1)*32 + quad*8];
      bf16x8s bw1 = *(const bf16x8s*)(wrow + (kt+1)*32 + quad*8);
      acc1 = __builtin_amdgcn_mfma_f32_16x16x32_bf16(ap1, bw1, acc1, 0, 0, 0);
    }
    f32x4 acc = acc0 + acc1;
    if (quad < 2) {             // D rows 0..7 are the real query rows
      #pragma unroll
      for (int i = 0; i < 4; ++i) opart[w][quad*4 + i][fm] = acc[i];
    }
  }
  __syncthreads();
  {
    int r = t >> 5, dd = t & 31;
    int nt = dd >> 4, c = dd & 15;
    float sum = opart[nt][r][c] + opart[nt + 2][r][c];
    float hv = (sum >= 0.0f) ? sum : 0.01f*sum;
    long idx = (long)(b*1024 + n0 + r)*256 + h*32 + dd;
    ws[C_OFF + idx] = ldin(x, idx, bf) + hv;   // raw residual row slice
  }
}

// ------- e_out = mean_h attn (from stored mx/rs) + fused rownorm(xa) -------
// Grid 4096: one (b,n) row per block. Rownorm reads raw xa (C region), writes
// B region. e_out recomputed from s1/s2/packed-adj + per-head mx/rs (exact
// same arithmetic/order as before: sum over h of rs*exp(lrelu(s1+s2)-mx)).
__global__ __launch_bounds__(256) void eout_kernel(float* ws, void* dout,
                                                   const int* flagp) {
  const int bf = *flagp;
  int t = threadIdx.x;
  int gid = blockIdx.x;
  int b = gid & 3;
  int n = gid >> 2;
  int row = b*1024 + n;
  int w = t >> 6, lane = t & 63;
  __shared__ float part[8];
  const unsigned long long* pk = (const unsigned long long*)(ws + PK_OFF);
  const unsigned long long* prow = pk + (long)row * 16;
  // ---- rownorm (ddof=1, two-pass) of raw xa row ---------------------------
  float v = ws[C_OFF + (long)row*256 + t];
  float s = v;
  #pragma unroll
  for (int off = 32; off > 0; off >>= 1) s += __shfl_xor(s, off);
  if (lane == 0) part[w] = s;
  __syncthreads();
  float mean = (part[0] + part[1] + part[2] + part[3]) * (1.0f/256.0f);
  float d = v - mean;
  float ss = d*d;
  #pragma unroll
  for (int off = 32; off > 0; off >>= 1) ss += __shfl_xor(ss, off);
  if (lane == 0) part[4 + w] = ss;
  __syncthreads();
  float inv = 1.0f / (sqrtf((part[4]+part[5]+part[6]+part[7]) * (1.0f/255.0f)) + 1e-6f);
  ws[B_OFF + (long)row*256 + t] = d * inv;
  // ---- e_out --------------------------------------------------------------
  float s1v[8], mxv[8], rsv[8];
  #pragma unroll
  for (int h = 0; h < 8; ++h) {
    s1v[h] = ws[S1_OFF + h*4096 + row];
    mxv[h] = ws[MX_OFF + h*4096 + row];
    rsv[h] = ws[RS_OFF + h*4096 + row];
  }
  const float* s2b = ws + S2_OFF + b*1024;
  #pragma unroll
  for (int j = 0; j < 4; ++j) {
    int m = t + 256*j;
    bool a = (prow[w + 4*j] >> lane) & 1ull;   // bit m: word (m>>6)=w+4j, bit lane
    float acc = 0.0f;
    #pragma unroll
    for (int h = 0; h < 8; ++h) {
      float ev = s1v[h] + s2b[h*4096 + m];
      ev = (ev >= 0.0f) ? ev : 0.1f*ev;
      ev = a ? ev : NEGC;
      acc += rsv[h] * __expf(ev - mxv[h]);
    }
    stout(dout, 1048576L + (long)row*1024 + m, 0.125f*acc, bf);
  }
}

// ---------------- column (axis=1) stats, ddof=1 ----------------------------
__global__ __launch_bounds__(256) void colstatsA_kernel(const float* in, float* cs) {
  int t = threadIdx.x;
  int j = blockIdx.x & 15;
  int b = blockIdx.x >> 4;
  float s = 0, ss = 0;
  for (int n = j*64; n < j*64 + 64; ++n) {
    float v = in[(b*1024 + n)*256 + t];
    s += v; ss += v*v;
  }
  cs[(b*16 + j)*256 + t] = s;
  cs[16384 + (b*16 + j)*256 + t] = ss;
}

__global__ __launch_bounds__(256) void colstatsB_kernel(const float* cs, float* st) {
  int t = threadIdx.x;
  int b = blockIdx.x;
  float s = 0, ss = 0;
  for (int j = 0; j < 16; ++j) {
    s  += cs[(b*16 + j)*256 + t];
    ss += cs[16384 + (b*16 + j)*256 + t];
  }
  float mean = s * (1.0f/1024.0f);
  float var = fmaxf((ss - s*mean) * (1.0f/1023.0f), 0.0f);
  st[b*256 + t] = mean;
  st[1024 + b*256 + t] = 1.0f / (sqrtf(var) + 1e-6f);
}

// ---------------- row GEMM, bf16 quad weights ------------------------------
// IN_MODE 0: plain fp32 [row][256]; 1: fp32 + colnorm(st); 2: float-input src
//   permuted (n,b,e)->(b,n,e); 3: fp32 head-major [b][h][n][32]
// RN 1: fused rownorm on output
// OUTM 0: fp32 [row][256]; 1: d_out (dtype per flag); 2: fp32 head-major;
//      3: bf16 head-major; 4: bf16 TRANSPOSED head-major [b][h][d][n]
// ROWS: rows per block (grid = 4096/ROWS). 4 -> 4 waves/SIMD latency hiding.
template<int IN_MODE, int RN, int OUTM, int ROWS>
__global__ __launch_bounds__(256) void gemm_kernel(const void* inp,
    const unsigned short* wmat, const float* bias, const float* st, void* outp,
    const int* flagp) {
  const int bf = *flagp;
  int t = threadIdx.x;
  int r0 = blockIdx.x * ROWS;
  __shared__ __align__(16) float U[ROWS][256];
  #pragma unroll
  for (int r = 0; r < ROWS; ++r) {
    int row = r0 + r;
    float v;
    if (IN_MODE == 0) {
      v = ((const float*)inp)[row*256 + t];
    } else if (IN_MODE == 1) {
      int b = row >> 10;
      v = (((const float*)inp)[row*256 + t] - st[b*256 + t]) * st[1024 + b*256 + t];
    } else if (IN_MODE == 2) {
      int b = row >> 10, n = row & 1023;
      v = ldin(inp, (long)(n*4 + b)*256 + t, bf);
    } else {
      int b = row >> 10, n = row & 1023;
      v = ((const float*)inp)[((b*8 + (t >> 5))*1024 + n)*32 + (t & 31)];
    }
    U[r][t] = v;
  }
  __syncthreads();
  float bv = bias[t];
  float acc[ROWS];
  #pragma unroll
  for (int r = 0; r < ROWS; ++r) acc[r] = bv;
  const ushort4* w4 = (const ushort4*)wmat;
  for (int e4 = 0; e4 < 64; ++e4) {
    ushort4 u = w4[e4*256 + t];
    float w0 = bf2f(u.x), w1 = bf2f(u.y), w2 = bf2f(u.z), w3 = bf2f(u.w);
    #pragma unroll
    for (int r = 0; r < ROWS; ++r) {
      float4 uu = *(const float4*)&U[r][e4*4];
      acc[r] += uu.x*w0 + uu.y*w1 + uu.z*w2 + uu.w*w3;
    }
  }
  if (RN == 0) {
    #pragma unroll
    for (int r = 0; r < ROWS; ++r) {
      int row = r0 + r;
      if (OUTM == 0) ((float*)outp)[row*256 + t] = acc[r];
      else if (OUTM == 1) stout(outp, (long)row*256 + t, acc[r], bf);
      else if (OUTM == 2) {
        int b = row >> 10, n = row & 1023;
        ((float*)outp)[((b*8 + (t >> 5))*1024 + n)*32 + (t & 31)] = acc[r];
      } else if (OUTM == 3) {
        int b = row >> 10, n = row & 1023;
        ((unsigned short*)outp)[((b*8 + (t >> 5))*1024 + n)*32 + (t & 31)] = f2bf(acc[r]);
      } else {
        int b = row >> 10, n = row & 1023;
        ((unsigned short*)outp)[((b*8 + (t >> 5))*32 + (t & 31))*1024 + n] = f2bf(acc[r]);
      }
    }
  } else {
    __syncthreads();
    #pragma unroll
    for (int r = 0; r < ROWS; ++r) U[r][t] = acc[r];
    __syncthreads();
    int w = t >> 6, lane = t & 63;
    for (int rr = w; rr < ROWS; rr += 4) {
      float vals[4]; float s = 0.0f;
      #pragma unroll
      for (int j = 0; j < 4; ++j) { vals[j] = U[rr][lane + 64*j]; s += vals[j]; }
      #pragma unroll
      for (int off = 32; off > 0; off >>= 1) s += __shfl_xor(s, off);
      float mean = s * (1.0f/256.0f);
      float ss = 0.0f;
      #pragma unroll
      for (int j = 0; j < 4; ++j) { float d = vals[j] - mean; ss += d*d; }
      #pragma unroll
      for (int off = 32; off > 0; off >>= 1) ss += __shfl_xor(ss, off);
      float inv = 1.0f / (sqrtf(ss * (1.0f/255.0f)) + 1e-6f);
      #pragma unroll
      for (int j = 0; j < 4; ++j)
        ((float*)outp)[(r0 + rr)*256 + lane + 64*j] = (vals[j] - mean) * inv;
    }
  }
}

// ---------------- MHA via MFMA, bf16 K/V, 16 q-rows per block --------------
// GRID MUST BE 2048, BLOCK 512 (8 waves): 64 row-groups x 4 b x 8 h.
// h in low 3 bits (XCD-L2). Q fp32 head-major [b][h][n][32] at A_OFF
// (o overwrites q, exclusive slots); K bf16 [b][h][n][32] at B_OFF;
// V^T bf16 [b][h][d][n] at C_OFF.
// 16 REAL rows per MFMA A-frag (m=lane&15, no duplication): QK wave w covers
// keys w*128..+127 (8 MFMAs, each 16rows x 16keys); softmax wave w owns rows
// 2w,2w+1; PV wave w -> d-tile (w&1), key-chunks (w>>1)*8..+7 (8 MFMAs);
// opart[8][16][17] reduced over 4 partials. Per-block K/V L2 read (128 KB)
// now amortized over 16 rows (2x R4) and MFMA count halved (no dup).
// LDS 75 KB -> 2 blocks/CU x 8 waves = 16 waves/CU; VGPR low.
// S stride 1036 fp32 (4144 B, 16B-aligned; 12-bank/row shift -> <=2-way on
// QK stores and PV b128 reads). Softmax single pass in regs, normalized P
// written back bf16 IN-PLACE (first 2072 ushorts of the row footprint).
// mfma_f32_16x16x32_bf16 layouts (m89-verified):
//   A[m=lane&15][k=(lane>>4)*8+j]; B[k=(lane>>4)*8+j][n=lane&15];
//   D col=lane&15, row=(lane>>4)*4+i.
#define SPS 1036
__global__ __launch_bounds__(512) void attn2_kernel(float* ws) {
  int t = threadIdx.x;
  int gid = blockIdx.x;
  int h = gid & 7;
  int b = (gid >> 3) & 3;
  int n0 = (gid >> 5) << 4;   // 16 q-rows per block; gid>>5 in 0..63
  __shared__ __align__(16) float Sp[16*SPS];        // 66.3 KB
  __shared__ __align__(16) float opart[8][16][17];  // 8.7 KB
  float* qq = ws + A_OFF;
  const unsigned short* kk = (const unsigned short*)(ws + B_OFF);
  const unsigned short* vt = (const unsigned short*)(ws + C_OFF);
  int base_bh = (b*8 + h)*1024;
  int w = t >> 6, lane = t & 63;   // w 0..7
  int m = lane & 15, quad = lane >> 4;
  const float scl = 0.17677669529663687f; // 1/sqrt(32)
  // ---- QK via MFMA: wave w covers keys w*128 .. +127 ----------------------
  {
    const float* qp = qq + (base_bh + n0 + m)*32 + quad*8;   // 16 real rows
    bf16x8s aq;
    #pragma unroll
    for (int j = 0; j < 8; ++j) ((unsigned short*)&aq)[j] = f2bf(qp[j]);
    f32x4 zero = {0.0f, 0.0f, 0.0f, 0.0f};
    #pragma unroll
    for (int kt = 0; kt < 8; ++kt) {
      int kbase = w*128 + kt*16;
      bf16x8s bk = *(const bf16x8s*)(kk + (base_bh + kbase + m)*32 + quad*8);
      f32x4 d = __builtin_amdgcn_mfma_f32_16x16x32_bf16(aq, bk, zero, 0, 0, 0);
      int key = kbase + m;          // D: col=lane&15 -> key; row=quad*4+i
      #pragma unroll
      for (int i = 0; i < 4; ++i)
        Sp[(quad*4 + i)*SPS + key] = d[i] * scl;
    }
  }
  __syncthreads();
  // ---- softmax: wave w owns rows 2w, 2w+1; single pass, bf16 overlay ------
  #pragma unroll
  for (int rr = 0; rr < 2; ++rr) {
    int r = 2*w + rr;
    float* Sr = Sp + r*SPS;
    float p[16];
    #pragma unroll
    for (int j = 0; j < 16; ++j) p[j] = Sr[lane + 64*j];
    float mx = -3.4e38f;
    #pragma unroll
    for (int j = 0; j < 16; ++j) mx = fmaxf(mx, p[j]);
    #pragma unroll
    for (int off = 32; off > 0; off >>= 1) mx = fmaxf(mx, __shfl_xor(mx, off));
    float s = 0.0f;
    #pragma unroll
    for (int j = 0; j < 16; ++j) { p[j] = __expf(p[j] - mx); s += p[j]; }
    #pragma unroll
    for (int off = 32; off > 0; off >>= 1) s += __shfl_xor(s, off);
    float rs = 1.0f / s;
    unsigned short* Pr = (unsigned short*)Sr;     // bf16 overlay, same row
    #pragma unroll
    for (int j = 0; j < 16; ++j)
      Pr[lane + 64*j] = f2bf(p[j] * rs);
  }
  __syncthreads();
  // ---- PV via MFMA: wave w -> d-tile (w&1), key-chunks (w>>1)*8 .. +7 -----
  {
    int ntile = w & 1;
    int ktbase = (w >> 1) * 8;
    int vd = ntile*16 + m;
    const unsigned short* vrow = vt + base_bh*32 + vd*1024;
    const unsigned short* P0 = (const unsigned short*)Sp + m*(SPS*2);  // row m
    f32x4 acc0 = {0.0f, 0.0f, 0.0f, 0.0f};
    f32x4 acc1 = {0.0f, 0.0f, 0.0f, 0.0f};
    #pragma unroll
    for (int kt2 = 0; kt2 < 4; ++kt2) {
      int kt = ktbase + 2*kt2;
      bf16x8s ap0 = *(const bf16x8s*)(P0 + kt*32 + quad*8);
      bf16x8s bv0 = *(const bf16x8s*)(vrow + kt*32 + quad*8);
      acc0 = __builtin_amdgcn_mfma_f32_16x16x32_bf16(ap0, bv0, acc0, 0, 0, 0);
      bf16x8s ap1 = *(const bf16x8s*)(P0 + (kt+1)*32 + quad*8);
      bf16x8s bv1 = *(const bf16x8s*)(vrow + (kt+1)*32 + quad*8);
      acc1 = __builtin_amdgcn_mfma_f32_16x16x32_bf16(ap1, bv1, acc1, 0, 0, 0);
    }
    f32x4 acc = acc0 + acc1;
    // D: row=(quad*4+i) = P-row (16 real), col=m = d-in-tile; all lanes live
    #pragma unroll
    for (int i = 0; i < 4; ++i)
      opart[w][quad*4 + i][m] = acc[i];
  }
  __syncthreads();
  {
    int r = t >> 5, d = t & 31;         // 512 threads: 16 rows x 32 d
    int nt = d >> 4, c = d & 15;
    float sum = opart[nt][r][c] + opart[nt + 2][r][c]
              + opart[nt + 4][r][c] + opart[nt + 6][r][c];
    qq[(base_bh + n0 + r)*32 + d] = sum;   // o over q (own slots)
  }
}

extern "C" void kernel_launch(void* const* d_in, const int* in_sizes, int n_in,
                              void* d_out, int out_size, void* d_ws, size_t ws_size,
                              hipStream_t stream) {
  const void* x   = d_in[0];
  const void* src = d_in[1];
  const int* adj  = (const int*)d_in[2];
  const void* wg  = d_in[3];
  const void* a1  = d_in[4];
  const void* a2  = d_in[5];
  const void* lw  = d_in[6];
  const void* lb  = d_in[7];
  const void* ipw = d_in[8];
  const void* ipb = d_in[9];
  const void* opw = d_in[10];
  const void* opb = d_in[11];
  float* ws = (float*)d_ws;
  const unsigned short* wbf = (const unsigned short*)d_ws;
  int* flagp = (int*)(ws + FLAG_F);

  detect_kernel<<<1, 64, 0, stream>>>((const unsigned short*)x, flagp);
  prep_kernel<<<dim3(256, 7), 256, 0, stream>>>(wg, lw, ipw, opw, lb, ipb, opb,
                                                a1, a2, ws, flagp);
  packadj_kernel<<<4096, 256, 0, stream>>>(adj,
      (unsigned long long*)(ws + PK_OFF));
  whs_kernel<<<512, 256, 0, stream>>>(x, ws, flagp);
  attn1a_kernel<<<4096, 256, 0, stream>>>(x, ws, flagp);       // xa -> C, mx/rs
  eout_kernel<<<4096, 256, 0, stream>>>(ws, d_out, flagp);     // e_out; rownorm -> B
  colstatsA_kernel<<<64, 256, 0, stream>>>(ws + B_OFF, ws + CS_OFF);
  colstatsB_kernel<<<4, 256, 0, stream>>>(ws + CS_OFF, ws + ST1_OFF);
  gemm_kernel<1,1,0,4><<<1024, 256, 0, stream>>>(ws + B_OFF, wbf + 1*65536,
      ws + BIAS_OFF, ws + ST1_OFF, ws + C_OFF, flagp);
  colstatsA_kernel<<<64, 256, 0, stream>>>(ws + C_OFF, ws + CS_OFF);
  colstatsB_kernel<<<4, 256, 0, stream>>>(ws + CS_OFF, ws + ST2_OFF);
  gemm_kernel<1,0,2,4><<<1024, 256, 0, stream>>>(ws + C_OFF, wbf + 2*65536,
      ws + BIAS_OFF + 256, ws + ST2_OFF, ws + A_OFF, flagp);   // Q fp32 hm
  gemm_kernel<1,0,3,4><<<1024, 256, 0, stream>>>(ws + C_OFF, wbf + 3*65536,
      ws + BIAS_OFF + 512, ws + ST2_OFF, ws + B_OFF, flagp);   // K bf16 hm
  gemm_kernel<2,0,4,4><<<1024, 256, 0, stream>>>(src, wbf + 4*65536,
      ws + BIAS_OFF + 768, nullptr, ws + C_OFF, flagp);        // V^T bf16 hm
  attn2_kernel<<<2048, 512, 0, stream>>>(ws);                  // o -> A_OFF
  gemm_kernel<3,0,1,4><<<1024, 256, 0, stream>>>(ws + A_OFF, wbf + 5*65536,
      ws + BIAS_OFF + 1024, nullptr, d_out, flagp);            // out-proj
}

// Round 6
// 299.643 us; speedup vs baseline: 1.1618x; 1.0342x over previous
//
#include <hip/hip_runtime.h>
#include <hip/hip_bf16.h>

// B=4, N=1024, E=256, H=8, D=32. Float tensors may be bf16 OR fp32 in d_in /
// d_out (detected at runtime on-device); adj is int32.
// Output: x_out [4,1024,256] then e_out [4,1024,1024] (element offsets).
//
// ws float offsets:
//   [0 .. 196608)   : 6 weight matrices, transposed, bf16, quad-interleaved
//                     matrix m at ushort offset m*65536; element (e,o) at
//                     ((e>>2)*256 + o)*4 + (e&3).  m: 0=Wcat 1=LIN 2=WQ 3=WK 4=WV 5=WO
#define BIAS_OFF 196608   // lin_b, bq, bk, bv, bo, a1, a2  (7*256 fp32)
#define S1_OFF   198400   // [h][4096]
#define S2_OFF   231168
#define CS_OFF   263936   // 32768: column partial sums+sumsq (reused twice)
#define ST1_OFF  296704   // mean[1024] + inv[1024]
#define ST2_OFF  298752
#define A_OFF    300800   // WhT bf16 [h][b][d][n] (2 MB) -> later Q,o fp32 head-major
#define MX_OFF   825088   // A_OFF+524288: softmax row max  [h][4096] (dead before Q)
#define RS_OFF   857856   // softmax row 1/sum              [h][4096]
#define PK_OFF   890624   // packed adj bitmask: [4096 rows][16 u64] = 512 KB (dead before Q)
#define B_OFF    1349376  // 4 MB: rownorm(xa)     -> later K bf16 head-major [b][h][n][32]
#define C_OFF    2397952  // 4 MB: raw xa, then rownorm(lin) -> later V^T bf16 hm [b][h][d][n]
#define FLAG_F   3446528  // int: 1 = bf16 tensors, 0 = fp32 tensors
// end 3446529 floats = 13.8 MB

#define NEGC (-9.0e15f)

typedef __attribute__((ext_vector_type(8))) short bf16x8s;
typedef __attribute__((ext_vector_type(4))) float f32x4;

static __device__ __forceinline__ float bf2f(unsigned short u) {
  union { unsigned int i; float f; } v; v.i = ((unsigned int)u) << 16; return v.f;
}
static __device__ __forceinline__ unsigned short f2bf(float f) {
  union { float f; unsigned int u; } v; v.f = f;
  unsigned int r = (v.u + 0x7FFFu + ((v.u >> 16) & 1u)) >> 16;   // RNE
  return (unsigned short)r;
}
static __device__ __forceinline__ float ldin(const void* p, long i, int bf) {
  return bf ? bf2f(((const unsigned short*)p)[i]) : ((const float*)p)[i];
}
static __device__ __forceinline__ unsigned short rdbf(const void* p, long i, int bf) {
  if (bf) return ((const unsigned short*)p)[i];
  return f2bf(((const float*)p)[i]);
}
static __device__ __forceinline__ void stout(void* p, long i, float v, int bf) {
  if (bf) ((unsigned short*)p)[i] = f2bf(v);
  else    ((float*)p)[i] = v;
}

// ---------------- dtype detector -------------------------------------------
__global__ __launch_bounds__(64) void detect_kernel(const unsigned short* x, int* flag) {
  int lane = threadIdx.x;
  unsigned short u = x[2 * lane];
  int e = (u >> 7) & 0xFF;
  bool good = (e >= 100 && e <= 140);
  unsigned long long m = __ballot(good);
  if (lane == 0) *flag = (__popcll(m) >= 48) ? 1 : 0;
}

// ---------------- adj -> bitmask: [row][16 u64], bit m%64 of word m/64 -----
__global__ __launch_bounds__(256) void packadj_kernel(const int* adj,
                                                      unsigned long long* pk) {
  int t = threadIdx.x, w = t >> 6, lane = t & 63;
  long row = blockIdx.x;            // 4096 rows
  #pragma unroll
  for (int j = 0; j < 4; ++j) {
    int m = t + 256*j;              // wave covers bits [w*64+256j .. +63]
    bool bit = adj[row*1024 + m] > 0;
    unsigned long long mask = __ballot(bit);
    if (lane == 0) pk[row*16 + w + 4*j] = mask;
  }
}

// ---------------- prep: weights -> transposed quad bf16; biases -> fp32 ----
__global__ __launch_bounds__(256) void prep_kernel(
    const void* wg, const void* lin_w, const void* inp_w, const void* out_w,
    const void* lin_b, const void* inp_b, const void* out_b,
    const void* a1, const void* a2, float* ws, const int* flagp) {
  const int bf = *flagp;
  unsigned short* wbf = (unsigned short*)ws;
  int t = threadIdx.x;
  int f = blockIdx.x;
  int m = blockIdx.y;
  int dst = m*65536 + ((f >> 2)*256 + t)*4 + (f & 3);
  if (m == 0) {
    int h = t >> 5, d = t & 31;
    wbf[dst] = rdbf(wg, h*8192 + f*32 + d, bf);
  } else if (m == 1) wbf[dst] = rdbf(lin_w, t*256 + f, bf);
  else if (m == 2)   wbf[dst] = rdbf(inp_w, t*256 + f, bf);
  else if (m == 3)   wbf[dst] = rdbf(inp_w, (256 + t)*256 + f, bf);
  else if (m == 4)   wbf[dst] = rdbf(inp_w, (512 + t)*256 + f, bf);
  else if (m == 5)   wbf[dst] = rdbf(out_w, t*256 + f, bf);
  else if (f == 0) {
    ws[BIAS_OFF + t]        = ldin(lin_b, t, bf);
    ws[BIAS_OFF + 256 + t]  = ldin(inp_b, t, bf);
    ws[BIAS_OFF + 512 + t]  = ldin(inp_b, 256 + t, bf);
    ws[BIAS_OFF + 768 + t]  = ldin(inp_b, 512 + t, bf);
    ws[BIAS_OFF + 1024 + t] = ldin(out_b, t, bf);
    ws[BIAS_OFF + 1280 + t] = ldin(a1, t, bf);
    ws[BIAS_OFF + 1536 + t] = ldin(a2, t, bf);
  }
}

// -------- Wh = x @ Wcat -> WhT bf16 [h][b][d][n]; s1/s2 head reductions ----
__global__ __launch_bounds__(256) void whs_kernel(const void* x, float* ws,
                                                  const int* flagp) {
  const int bf = *flagp;
  int t = threadIdx.x;
  int r0 = blockIdx.x * 8;
  __shared__ __align__(16) float U[8][256];
  #pragma unroll
  for (int r = 0; r < 8; ++r)
    U[r][t] = ldin(x, (long)(r0 + r)*256 + t, bf);
  __syncthreads();
  const ushort4* w4 = (const ushort4*)ws;
  float acc[8] = {0,0,0,0,0,0,0,0};
  for (int e4 = 0; e4 < 64; ++e4) {
    ushort4 u = w4[e4*256 + t];
    float w0 = bf2f(u.x), w1 = bf2f(u.y), w2 = bf2f(u.z), w3 = bf2f(u.w);
    #pragma unroll
    for (int r = 0; r < 8; ++r) {
      float4 uu = *(const float4*)&U[r][e4*4];
      acc[r] += uu.x*w0 + uu.y*w1 + uu.z*w2 + uu.w*w3;
    }
  }
  int h = t >> 5, d = t & 31;
  float a1v = ws[BIAS_OFF + 1280 + t];
  float a2v = ws[BIAS_OFF + 1536 + t];
  unsigned short wvals[8];
  #pragma unroll
  for (int r = 0; r < 8; ++r) {
    int row = r0 + r;
    wvals[r] = f2bf(acc[r]);
    float p1 = acc[r]*a1v, p2 = acc[r]*a2v;
    #pragma unroll
    for (int off = 16; off > 0; off >>= 1) {
      p1 += __shfl_xor(p1, off, 32);
      p2 += __shfl_xor(p2, off, 32);
    }
    if (d == 0) {
      ws[S1_OFF + h*4096 + row] = p1;
      ws[S2_OFF + h*4096 + row] = p2;
    }
  }
  // WhT[h][b][d][n], 8 contiguous n per thread (16B store)
  {
    unsigned short* wht = (unsigned short*)(ws + A_OFF);
    int bb = r0 >> 10, nn = r0 & 1023;
    *(bf16x8s*)(wht + ((long)((h*4 + bb)*32 + d))*1024 + nn) = *(bf16x8s*)wvals;
  }
}

// ------- graph attention, head-split, 16 REAL rows/block -------------------
// GRID 2048, BLOCK 512 (8 waves): 4b x 64 groups x 8h; h in low 3 bits
// (XCD-L2 locality on WhT). adj from packed bitmask (scalar loads).
// Softmax register-resident: wave w owns rows 2w, 2w+1. P bf16 in Pb[16]
// (16 real rows -> A-frag m=lane&15, NO duplication). PV: wave w -> d-tile
// (w&1), key-chunks (w>>1)*8..+7 (8 MFMAs); opart[8][16][17] reduced over 4
// partials. Per-block WhT L2 sweep (64 KB) amortized over 16 rows; PV MFMA
// per row halved vs 8-row version. LDS ~46 KB -> 3 blocks/CU = 24 waves/CU.
// Writes:
//   C region: raw xa slice  xa[b,n,h*32+d] = x + leaky(PV)
//   MX/RS: per-(h,row) softmax max and 1/sum (consumed by eout_kernel)
#define PB_S 1032    // Pb row stride (ushorts); 2064B = 129*16, rows +1 slot
__global__ __launch_bounds__(512) void attn1a_kernel(const void* x, float* ws,
                                                     const int* flagp) {
  const int bf = *flagp;
  int t = threadIdx.x;
  int gid = blockIdx.x;
  int h = gid & 7;
  int b = (gid >> 3) & 3;
  int n0 = (gid >> 5) * 16;               // gid>>5 in 0..63
  __shared__ __align__(16) float s2s[1024];
  __shared__ __align__(16) unsigned short Pb[16][PB_S];   // 33 KB
  __shared__ __align__(16) float opart[8][16][17];        // 8.7 KB
  int w = t >> 6, lane = t & 63;          // w 0..7
  int m = lane & 15, quad = lane >> 4;
  const unsigned long long* pk = (const unsigned long long*)(ws + PK_OFF);
  const float* s2p = ws + S2_OFF + h*4096 + b*1024;
  #pragma unroll
  for (int j = 0; j < 2; ++j) s2s[t + 512*j] = s2p[t + 512*j];
  __syncthreads();
  // ---- softmax rows (n0+2w) and (n0+2w+1), head h: register resident ------
  #pragma unroll
  for (int rr = 0; rr < 2; ++rr) {
    int r = 2*w + rr;
    int rowi = __builtin_amdgcn_readfirstlane(b*1024 + n0 + r);
    const unsigned long long* prow = pk + (long)rowi * 16;   // wave-uniform
    float s1v = ws[S1_OFF + h*4096 + rowi];
    float p[16];
    float mx = -3.4e38f;
    #pragma unroll
    for (int j = 0; j < 16; ++j) {
      int mm = lane + 64*j;
      float ev = s1v + s2s[mm];
      ev = (ev >= 0.0f) ? ev : 0.1f*ev;
      ev = ((prow[j] >> lane) & 1ull) ? ev : NEGC;
      p[j] = ev;
      mx = fmaxf(mx, ev);
    }
    #pragma unroll
    for (int off = 32; off > 0; off >>= 1) mx = fmaxf(mx, __shfl_xor(mx, off));
    float s = 0.0f;
    #pragma unroll
    for (int j = 0; j < 16; ++j) { p[j] = __expf(p[j] - mx); s += p[j]; }
    #pragma unroll
    for (int off = 32; off > 0; off >>= 1) s += __shfl_xor(s, off);
    float rs = 1.0f / s;
    #pragma unroll
    for (int j = 0; j < 16; ++j)
      Pb[r][lane + 64*j] = f2bf(p[j] * rs);
    if (lane == 0) {
      ws[MX_OFF + h*4096 + rowi] = mx;
      ws[RS_OFF + h*4096 + rowi] = rs;
    }
  }
  __syncthreads();
  // ---- PV via MFMA: wave w -> d-tile (w&1), key-chunks (w>>1)*8 .. +7 -----
  {
    const unsigned short* wht = (const unsigned short*)(ws + A_OFF);
    int ntile = w & 1;
    int ktbase = (w >> 1) * 8;
    int vd = ntile*16 + m;
    const unsigned short* wrow = wht + ((long)((h*4 + b)*32 + vd))*1024;
    f32x4 acc0 = {0.0f, 0.0f, 0.0f, 0.0f};
    f32x4 acc1 = {0.0f, 0.0f, 0.0f, 0.0f};
    #pragma unroll
    for (int kt2 = 0; kt2 < 4; ++kt2) {
      int kt = ktbase + 2*kt2;
      bf16x8s ap0 = *(const bf16x8s*)&Pb[m][kt*32 + quad*8];
      bf16x8s bw0 = *(const bf16x8s*)(wrow + kt*32 + quad*8);
      acc0 = __builtin_amdgcn_mfma_f32_16x16x32_bf16(ap0, bw0, acc0, 0, 0, 0);
      bf16x8s ap1 = *(const bf16x8s*)&Pb[m][(kt+1)*32 + quad*8];
      bf16x8s bw1 = *(const bf16x8s*)(wrow + (kt+1)*32 + quad*8);
      acc1 = __builtin_amdgcn_mfma_f32_16x16x32_bf16(ap1, bw1, acc1, 0, 0, 0);
    }
    f32x4 acc = acc0 + acc1;
    // D: row=(quad*4+i) = P-row (16 real), col=m = d-in-tile; all lanes live
    #pragma unroll
    for (int i = 0; i < 4; ++i)
      opart[w][quad*4 + i][m] = acc[i];
  }
  __syncthreads();
  {
    int r = t >> 5, dd = t & 31;        // 512 threads: 16 rows x 32 d
    int nt = dd >> 4, c = dd & 15;
    float sum = opart[nt][r][c] + opart[nt + 2][r][c]
              + opart[nt + 4][r][c] + opart[nt + 6][r][c];
    float hv = (sum >= 0.0f) ? sum : 0.01f*sum;
    long idx = (long)(b*1024 + n0 + r)*256 + h*32 + dd;
    ws[C_OFF + idx] = ldin(x, idx, bf) + hv;   // raw residual row slice
  }
}

// ------- e_out = mean_h attn (from stored mx/rs) + fused rownorm(xa) -------
// Grid 4096: one (b,n) row per block. Rownorm reads raw xa (C region), writes
// B region. e_out recomputed from s1/s2/packed-adj + per-head mx/rs (exact
// same arithmetic/order as before: sum over h of rs*exp(lrelu(s1+s2)-mx)).
__global__ __launch_bounds__(256) void eout_kernel(float* ws, void* dout,
                                                   const int* flagp) {
  const int bf = *flagp;
  int t = threadIdx.x;
  int gid = blockIdx.x;
  int b = gid & 3;
  int n = gid >> 2;
  int row = b*1024 + n;
  int w = t >> 6, lane = t & 63;
  __shared__ float part[8];
  const unsigned long long* pk = (const unsigned long long*)(ws + PK_OFF);
  const unsigned long long* prow = pk + (long)row * 16;
  // ---- rownorm (ddof=1, two-pass) of raw xa row ---------------------------
  float v = ws[C_OFF + (long)row*256 + t];
  float s = v;
  #pragma unroll
  for (int off = 32; off > 0; off >>= 1) s += __shfl_xor(s, off);
  if (lane == 0) part[w] = s;
  __syncthreads();
  float mean = (part[0] + part[1] + part[2] + part[3]) * (1.0f/256.0f);
  float d = v - mean;
  float ss = d*d;
  #pragma unroll
  for (int off = 32; off > 0; off >>= 1) ss += __shfl_xor(ss, off);
  if (lane == 0) part[4 + w] = ss;
  __syncthreads();
  float inv = 1.0f / (sqrtf((part[4]+part[5]+part[6]+part[7]) * (1.0f/255.0f)) + 1e-6f);
  ws[B_OFF + (long)row*256 + t] = d * inv;
  // ---- e_out --------------------------------------------------------------
  float s1v[8], mxv[8], rsv[8];
  #pragma unroll
  for (int h = 0; h < 8; ++h) {
    s1v[h] = ws[S1_OFF + h*4096 + row];
    mxv[h] = ws[MX_OFF + h*4096 + row];
    rsv[h] = ws[RS_OFF + h*4096 + row];
  }
  const float* s2b = ws + S2_OFF + b*1024;
  #pragma unroll
  for (int j = 0; j < 4; ++j) {
    int m = t + 256*j;
    bool a = (prow[w + 4*j] >> lane) & 1ull;   // bit m: word (m>>6)=w+4j, bit lane
    float acc = 0.0f;
    #pragma unroll
    for (int h = 0; h < 8; ++h) {
      float ev = s1v[h] + s2b[h*4096 + m];
      ev = (ev >= 0.0f) ? ev : 0.1f*ev;
      ev = a ? ev : NEGC;
      acc += rsv[h] * __expf(ev - mxv[h]);
    }
    stout(dout, 1048576L + (long)row*1024 + m, 0.125f*acc, bf);
  }
}

// ---------------- column (axis=1) stats, ddof=1 ----------------------------
__global__ __launch_bounds__(256) void colstatsA_kernel(const float* in, float* cs) {
  int t = threadIdx.x;
  int j = blockIdx.x & 15;
  int b = blockIdx.x >> 4;
  float s = 0, ss = 0;
  for (int n = j*64; n < j*64 + 64; ++n) {
    float v = in[(b*1024 + n)*256 + t];
    s += v; ss += v*v;
  }
  cs[(b*16 + j)*256 + t] = s;
  cs[16384 + (b*16 + j)*256 + t] = ss;
}

__global__ __launch_bounds__(256) void colstatsB_kernel(const float* cs, float* st) {
  int t = threadIdx.x;
  int b = blockIdx.x;
  float s = 0, ss = 0;
  for (int j = 0; j < 16; ++j) {
    s  += cs[(b*16 + j)*256 + t];
    ss += cs[16384 + (b*16 + j)*256 + t];
  }
  float mean = s * (1.0f/1024.0f);
  float var = fmaxf((ss - s*mean) * (1.0f/1023.0f), 0.0f);
  st[b*256 + t] = mean;
  st[1024 + b*256 + t] = 1.0f / (sqrtf(var) + 1e-6f);
}

// ---------------- row GEMM, bf16 quad weights ------------------------------
// IN_MODE 0: plain fp32 [row][256]; 1: fp32 + colnorm(st); 2: float-input src
//   permuted (n,b,e)->(b,n,e); 3: fp32 head-major [b][h][n][32]
// RN 1: fused rownorm on output
// OUTM 0: fp32 [row][256]; 1: d_out (dtype per flag); 2: fp32 head-major;
//      3: bf16 head-major; 4: bf16 TRANSPOSED head-major [b][h][d][n]
// ROWS: rows per block (grid = 4096/ROWS). 4 -> 4 waves/SIMD latency hiding.
template<int IN_MODE, int RN, int OUTM, int ROWS>
__global__ __launch_bounds__(256) void gemm_kernel(const void* inp,
    const unsigned short* wmat, const float* bias, const float* st, void* outp,
    const int* flagp) {
  const int bf = *flagp;
  int t = threadIdx.x;
  int r0 = blockIdx.x * ROWS;
  __shared__ __align__(16) float U[ROWS][256];
  #pragma unroll
  for (int r = 0; r < ROWS; ++r) {
    int row = r0 + r;
    float v;
    if (IN_MODE == 0) {
      v = ((const float*)inp)[row*256 + t];
    } else if (IN_MODE == 1) {
      int b = row >> 10;
      v = (((const float*)inp)[row*256 + t] - st[b*256 + t]) * st[1024 + b*256 + t];
    } else if (IN_MODE == 2) {
      int b = row >> 10, n = row & 1023;
      v = ldin(inp, (long)(n*4 + b)*256 + t, bf);
    } else {
      int b = row >> 10, n = row & 1023;
      v = ((const float*)inp)[((b*8 + (t >> 5))*1024 + n)*32 + (t & 31)];
    }
    U[r][t] = v;
  }
  __syncthreads();
  float bv = bias[t];
  float acc[ROWS];
  #pragma unroll
  for (int r = 0; r < ROWS; ++r) acc[r] = bv;
  const ushort4* w4 = (const ushort4*)wmat;
  for (int e4 = 0; e4 < 64; ++e4) {
    ushort4 u = w4[e4*256 + t];
    float w0 = bf2f(u.x), w1 = bf2f(u.y), w2 = bf2f(u.z), w3 = bf2f(u.w);
    #pragma unroll
    for (int r = 0; r < ROWS; ++r) {
      float4 uu = *(const float4*)&U[r][e4*4];
      acc[r] += uu.x*w0 + uu.y*w1 + uu.z*w2 + uu.w*w3;
    }
  }
  if (RN == 0) {
    #pragma unroll
    for (int r = 0; r < ROWS; ++r) {
      int row = r0 + r;
      if (OUTM == 0) ((float*)outp)[row*256 + t] = acc[r];
      else if (OUTM == 1) stout(outp, (long)row*256 + t, acc[r], bf);
      else if (OUTM == 2) {
        int b = row >> 10, n = row & 1023;
        ((float*)outp)[((b*8 + (t >> 5))*1024 + n)*32 + (t & 31)] = acc[r];
      } else if (OUTM == 3) {
        int b = row >> 10, n = row & 1023;
        ((unsigned short*)outp)[((b*8 + (t >> 5))*1024 + n)*32 + (t & 31)] = f2bf(acc[r]);
      } else {
        int b = row >> 10, n = row & 1023;
        ((unsigned short*)outp)[((b*8 + (t >> 5))*32 + (t & 31))*1024 + n] = f2bf(acc[r]);
      }
    }
  } else {
    __syncthreads();
    #pragma unroll
    for (int r = 0; r < ROWS; ++r) U[r][t] = acc[r];
    __syncthreads();
    int w = t >> 6, lane = t & 63;
    for (int rr = w; rr < ROWS; rr += 4) {
      float vals[4]; float s = 0.0f;
      #pragma unroll
      for (int j = 0; j < 4; ++j) { vals[j] = U[rr][lane + 64*j]; s += vals[j]; }
      #pragma unroll
      for (int off = 32; off > 0; off >>= 1) s += __shfl_xor(s, off);
      float mean = s * (1.0f/256.0f);
      float ss = 0.0f;
      #pragma unroll
      for (int j = 0; j < 4; ++j) { float d = vals[j] - mean; ss += d*d; }
      #pragma unroll
      for (int off = 32; off > 0; off >>= 1) ss += __shfl_xor(ss, off);
      float inv = 1.0f / (sqrtf(ss * (1.0f/255.0f)) + 1e-6f);
      #pragma unroll
      for (int j = 0; j < 4; ++j)
        ((float*)outp)[(r0 + rr)*256 + lane + 64*j] = (vals[j] - mean) * inv;
    }
  }
}

// ---------------- MHA via MFMA, bf16 K/V, 16 q-rows per block --------------
// GRID MUST BE 2048, BLOCK 512 (8 waves): 64 row-groups x 4 b x 8 h.
// h in low 3 bits (XCD-L2). Q fp32 head-major [b][h][n][32] at A_OFF
// (o overwrites q, exclusive slots); K bf16 [b][h][n][32] at B_OFF;
// V^T bf16 [b][h][d][n] at C_OFF.
// 16 REAL rows per MFMA A-frag (m=lane&15, no duplication): QK wave w covers
// keys w*128..+127 (8 MFMAs, each 16rows x 16keys); softmax wave w owns rows
// 2w,2w+1; PV wave w -> d-tile (w&1), key-chunks (w>>1)*8..+7 (8 MFMAs);
// opart[8][16][17] reduced over 4 partials.
// LDS 75 KB -> 2 blocks/CU x 8 waves = 16 waves/CU; VGPR low.
// S stride 1036 fp32; softmax single pass in regs, normalized P written back
// bf16 IN-PLACE. mfma_f32_16x16x32_bf16 layouts (m89-verified):
//   A[m=lane&15][k=(lane>>4)*8+j]; B[k=(lane>>4)*8+j][n=lane&15];
//   D col=lane&15, row=(lane>>4)*4+i.
#define SPS 1036
__global__ __launch_bounds__(512) void attn2_kernel(float* ws) {
  int t = threadIdx.x;
  int gid = blockIdx.x;
  int h = gid & 7;
  int b = (gid >> 3) & 3;
  int n0 = (gid >> 5) << 4;   // 16 q-rows per block; gid>>5 in 0..63
  __shared__ __align__(16) float Sp[16*SPS];        // 66.3 KB
  __shared__ __align__(16) float opart[8][16][17];  // 8.7 KB
  float* qq = ws + A_OFF;
  const unsigned short* kk = (const unsigned short*)(ws + B_OFF);
  const unsigned short* vt = (const unsigned short*)(ws + C_OFF);
  int base_bh = (b*8 + h)*1024;
  int w = t >> 6, lane = t & 63;   // w 0..7
  int m = lane & 15, quad = lane >> 4;
  const float scl = 0.17677669529663687f; // 1/sqrt(32)
  // ---- QK via MFMA: wave w covers keys w*128 .. +127 ----------------------
  {
    const float* qp = qq + (base_bh + n0 + m)*32 + quad*8;   // 16 real rows
    bf16x8s aq;
    #pragma unroll
    for (int j = 0; j < 8; ++j) ((unsigned short*)&aq)[j] = f2bf(qp[j]);
    f32x4 zero = {0.0f, 0.0f, 0.0f, 0.0f};
    #pragma unroll
    for (int kt = 0; kt < 8; ++kt) {
      int kbase = w*128 + kt*16;
      bf16x8s bk = *(const bf16x8s*)(kk + (base_bh + kbase + m)*32 + quad*8);
      f32x4 d = __builtin_amdgcn_mfma_f32_16x16x32_bf16(aq, bk, zero, 0, 0, 0);
      int key = kbase + m;          // D: col=lane&15 -> key; row=quad*4+i
      #pragma unroll
      for (int i = 0; i < 4; ++i)
        Sp[(quad*4 + i)*SPS + key] = d[i] * scl;
    }
  }
  __syncthreads();
  // ---- softmax: wave w owns rows 2w, 2w+1; single pass, bf16 overlay ------
  #pragma unroll
  for (int rr = 0; rr < 2; ++rr) {
    int r = 2*w + rr;
    float* Sr = Sp + r*SPS;
    float p[16];
    #pragma unroll
    for (int j = 0; j < 16; ++j) p[j] = Sr[lane + 64*j];
    float mx = -3.4e38f;
    #pragma unroll
    for (int j = 0; j < 16; ++j) mx = fmaxf(mx, p[j]);
    #pragma unroll
    for (int off = 32; off > 0; off >>= 1) mx = fmaxf(mx, __shfl_xor(mx, off));
    float s = 0.0f;
    #pragma unroll
    for (int j = 0; j < 16; ++j) { p[j] = __expf(p[j] - mx); s += p[j]; }
    #pragma unroll
    for (int off = 32; off > 0; off >>= 1) s += __shfl_xor(s, off);
    float rs = 1.0f / s;
    unsigned short* Pr = (unsigned short*)Sr;     // bf16 overlay, same row
    #pragma unroll
    for (int j = 0; j < 16; ++j)
      Pr[lane + 64*j] = f2bf(p[j] * rs);
  }
  __syncthreads();
  // ---- PV via MFMA: wave w -> d-tile (w&1), key-chunks (w>>1)*8 .. +7 -----
  {
    int ntile = w & 1;
    int ktbase = (w >> 1) * 8;
    int vd = ntile*16 + m;
    const unsigned short* vrow = vt + base_bh*32 + vd*1024;
    const unsigned short* P0 = (const unsigned short*)Sp + m*(SPS*2);  // row m
    f32x4 acc0 = {0.0f, 0.0f, 0.0f, 0.0f};
    f32x4 acc1 = {0.0f, 0.0f, 0.0f, 0.0f};
    #pragma unroll
    for (int kt2 = 0; kt2 < 4; ++kt2) {
      int kt = ktbase + 2*kt2;
      bf16x8s ap0 = *(const bf16x8s*)(P0 + kt*32 + quad*8);
      bf16x8s bv0 = *(const bf16x8s*)(vrow + kt*32 + quad*8);
      acc0 = __builtin_amdgcn_mfma_f32_16x16x32_bf16(ap0, bv0, acc0, 0, 0, 0);
      bf16x8s ap1 = *(const bf16x8s*)(P0 + (kt+1)*32 + quad*8);
      bf16x8s bv1 = *(const bf16x8s*)(vrow + (kt+1)*32 + quad*8);
      acc1 = __builtin_amdgcn_mfma_f32_16x16x32_bf16(ap1, bv1, acc1, 0, 0, 0);
    }
    f32x4 acc = acc0 + acc1;
    // D: row=(quad*4+i) = P-row (16 real), col=m = d-in-tile; all lanes live
    #pragma unroll
    for (int i = 0; i < 4; ++i)
      opart[w][quad*4 + i][m] = acc[i];
  }
  __syncthreads();
  {
    int r = t >> 5, d = t & 31;         // 512 threads: 16 rows x 32 d
    int nt = d >> 4, c = d & 15;
    float sum = opart[nt][r][c] + opart[nt + 2][r][c]
              + opart[nt + 4][r][c] + opart[nt + 6][r][c];
    qq[(base_bh + n0 + r)*32 + d] = sum;   // o over q (own slots)
  }
}

extern "C" void kernel_launch(void* const* d_in, const int* in_sizes, int n_in,
                              void* d_out, int out_size, void* d_ws, size_t ws_size,
                              hipStream_t stream) {
  const void* x   = d_in[0];
  const void* src = d_in[1];
  const int* adj  = (const int*)d_in[2];
  const void* wg  = d_in[3];
  const void* a1  = d_in[4];
  const void* a2  = d_in[5];
  const void* lw  = d_in[6];
  const void* lb  = d_in[7];
  const void* ipw = d_in[8];
  const void* ipb = d_in[9];
  const void* opw = d_in[10];
  const void* opb = d_in[11];
  float* ws = (float*)d_ws;
  const unsigned short* wbf = (const unsigned short*)d_ws;
  int* flagp = (int*)(ws + FLAG_F);

  detect_kernel<<<1, 64, 0, stream>>>((const unsigned short*)x, flagp);
  prep_kernel<<<dim3(256, 7), 256, 0, stream>>>(wg, lw, ipw, opw, lb, ipb, opb,
                                                a1, a2, ws, flagp);
  packadj_kernel<<<4096, 256, 0, stream>>>(adj,
      (unsigned long long*)(ws + PK_OFF));
  whs_kernel<<<512, 256, 0, stream>>>(x, ws, flagp);
  attn1a_kernel<<<2048, 512, 0, stream>>>(x, ws, flagp);       // xa -> C, mx/rs
  eout_kernel<<<4096, 256, 0, stream>>>(ws, d_out, flagp);     // e_out; rownorm -> B
  colstatsA_kernel<<<64, 256, 0, stream>>>(ws + B_OFF, ws + CS_OFF);
  colstatsB_kernel<<<4, 256, 0, stream>>>(ws + CS_OFF, ws + ST1_OFF);
  gemm_kernel<1,1,0,4><<<1024, 256, 0, stream>>>(ws + B_OFF, wbf + 1*65536,
      ws + BIAS_OFF, ws + ST1_OFF, ws + C_OFF, flagp);
  colstatsA_kernel<<<64, 256, 0, stream>>>(ws + C_OFF, ws + CS_OFF);
  colstatsB_kernel<<<4, 256, 0, stream>>>(ws + CS_OFF, ws + ST2_OFF);
  gemm_kernel<1,0,2,4><<<1024, 256, 0, stream>>>(ws + C_OFF, wbf + 2*65536,
      ws + BIAS_OFF + 256, ws + ST2_OFF, ws + A_OFF, flagp);   // Q fp32 hm
  gemm_kernel<1,0,3,4><<<1024, 256, 0, stream>>>(ws + C_OFF, wbf + 3*65536,
      ws + BIAS_OFF + 512, ws + ST2_OFF, ws + B_OFF, flagp);   // K bf16 hm
  gemm_kernel<2,0,4,4><<<1024, 256, 0, stream>>>(src, wbf + 4*65536,
      ws + BIAS_OFF + 768, nullptr, ws + C_OFF, flagp);        // V^T bf16 hm
  attn2_kernel<<<2048, 512, 0, stream>>>(ws);                  // o -> A_OFF
  gemm_kernel<3,0,1,4><<<1024, 256, 0, stream>>>(ws + A_OFF, wbf + 5*65536,
      ws + BIAS_OFF + 1024, nullptr, d_out, flagp);            // out-proj
}

// Round 7
// 255.162 us; speedup vs baseline: 1.3643x; 1.1743x over previous
//
#include <hip/hip_runtime.h>
#include <hip/hip_bf16.h>

// B=4, N=1024, E=256, H=8, D=32. Float tensors may be bf16 OR fp32 in d_in /
// d_out (detected at runtime on-device); adj is int32.
// Output: x_out [4,1024,256] then e_out [4,1024,1024] (element offsets).
//
// ws float offsets:
//   [0 .. 196608)   : weight matrices, bf16, ushort offset m*65536.
//       m=0 (Wcat, used by whs): quad-interleaved ((e>>2)*256+o)*4+(e&3)
//       m=1..5 (LIN WQ WK WV WO, used by gemm2): o-major  o*256+e
#define BIAS_OFF 196608   // lin_b, bq, bk, bv, bo, a1, a2  (7*256 fp32)
#define S1_OFF   198400   // [h][4096]
#define S2_OFF   231168
#define CS_OFF   263936   // (legacy, unused)
#define ST1_OFF  296704   // mean[1024] + inv[1024]
#define ST2_OFF  298752
#define A_OFF    300800   // WhT bf16 [h][b][d][n] (2 MB) -> later Q,o fp32 head-major
#define MX_OFF   825088   // softmax row max [h][4096]; later colstats scratch (131072 f)
#define RS_OFF   857856   // softmax row 1/sum [h][4096]
#define PK_OFF   890624   // packed adj bitmask: [4096 rows][16 u64] = 512 KB (dead after eout)
#define B_OFF    1349376  // 4 MB: rownorm(xa)     -> later K bf16 head-major [b][h][n][32]
#define C_OFF    2397952  // 4 MB: raw xa, then rownorm(lin) -> later V^T bf16 hm [b][h][d][n]
#define FLAG_F   3446528  // int: 1 = bf16 tensors, 0 = fp32 tensors
// end 3446529 floats = 13.8 MB

#define NEGC (-9.0e15f)

typedef __attribute__((ext_vector_type(8))) short bf16x8s;
typedef __attribute__((ext_vector_type(4))) float f32x4;

static __device__ __forceinline__ float bf2f(unsigned short u) {
  union { unsigned int i; float f; } v; v.i = ((unsigned int)u) << 16; return v.f;
}
static __device__ __forceinline__ unsigned short f2bf(float f) {
  union { float f; unsigned int u; } v; v.f = f;
  unsigned int r = (v.u + 0x7FFFu + ((v.u >> 16) & 1u)) >> 16;   // RNE
  return (unsigned short)r;
}
static __device__ __forceinline__ float ldin(const void* p, long i, int bf) {
  return bf ? bf2f(((const unsigned short*)p)[i]) : ((const float*)p)[i];
}
static __device__ __forceinline__ unsigned short rdbf(const void* p, long i, int bf) {
  if (bf) return ((const unsigned short*)p)[i];
  return f2bf(((const float*)p)[i]);
}
static __device__ __forceinline__ void stout(void* p, long i, float v, int bf) {
  if (bf) ((unsigned short*)p)[i] = f2bf(v);
  else    ((float*)p)[i] = v;
}

// ---------------- dtype detector -------------------------------------------
__global__ __launch_bounds__(64) void detect_kernel(const unsigned short* x, int* flag) {
  int lane = threadIdx.x;
  unsigned short u = x[2 * lane];
  int e = (u >> 7) & 0xFF;
  bool good = (e >= 100 && e <= 140);
  unsigned long long m = __ballot(good);
  if (lane == 0) *flag = (__popcll(m) >= 48) ? 1 : 0;
}

// ---------------- adj -> bitmask: [row][16 u64], bit m%64 of word m/64 -----
__global__ __launch_bounds__(256) void packadj_kernel(const int* adj,
                                                      unsigned long long* pk) {
  int t = threadIdx.x, w = t >> 6, lane = t & 63;
  long row = blockIdx.x;            // 4096 rows
  #pragma unroll
  for (int j = 0; j < 4; ++j) {
    int m = t + 256*j;              // wave covers bits [w*64+256j .. +63]
    bool bit = adj[row*1024 + m] > 0;
    unsigned long long mask = __ballot(bit);
    if (lane == 0) pk[row*16 + w + 4*j] = mask;
  }
}

// ------- prep: Wcat -> quad bf16; LIN/WQ/WK/WV/WO -> o-major bf16; biases --
__global__ __launch_bounds__(256) void prep_kernel(
    const void* wg, const void* lin_w, const void* inp_w, const void* out_w,
    const void* lin_b, const void* inp_b, const void* out_b,
    const void* a1, const void* a2, float* ws, const int* flagp) {
  const int bf = *flagp;
  unsigned short* wbf = (unsigned short*)ws;
  int t = threadIdx.x;
  int f = blockIdx.x;         // e (input feature)
  int m = blockIdx.y;
  if (m == 0) {
    int h = t >> 5, d = t & 31;
    int dst = ((f >> 2)*256 + t)*4 + (f & 3);
    wbf[dst] = rdbf(wg, h*8192 + f*32 + d, bf);
  } else if (m <= 5) {
    int dst = m*65536 + t*256 + f;          // W[o=t][e=f]
    if (m == 1)      wbf[dst] = rdbf(lin_w, t*256 + f, bf);
    else if (m == 2) wbf[dst] = rdbf(inp_w, t*256 + f, bf);
    else if (m == 3) wbf[dst] = rdbf(inp_w, (256 + t)*256 + f, bf);
    else if (m == 4) wbf[dst] = rdbf(inp_w, (512 + t)*256 + f, bf);
    else             wbf[dst] = rdbf(out_w, t*256 + f, bf);
  } else if (f == 0) {
    ws[BIAS_OFF + t]        = ldin(lin_b, t, bf);
    ws[BIAS_OFF + 256 + t]  = ldin(inp_b, t, bf);
    ws[BIAS_OFF + 512 + t]  = ldin(inp_b, 256 + t, bf);
    ws[BIAS_OFF + 768 + t]  = ldin(inp_b, 512 + t, bf);
    ws[BIAS_OFF + 1024 + t] = ldin(out_b, t, bf);
    ws[BIAS_OFF + 1280 + t] = ldin(a1, t, bf);
    ws[BIAS_OFF + 1536 + t] = ldin(a2, t, bf);
  }
}

// -------- Wh = x @ Wcat -> WhT bf16 [h][b][d][n]; s1/s2 head reductions ----
__global__ __launch_bounds__(256) void whs_kernel(const void* x, float* ws,
                                                  const int* flagp) {
  const int bf = *flagp;
  int t = threadIdx.x;
  int r0 = blockIdx.x * 8;
  __shared__ __align__(16) float U[8][256];
  #pragma unroll
  for (int r = 0; r < 8; ++r)
    U[r][t] = ldin(x, (long)(r0 + r)*256 + t, bf);
  __syncthreads();
  const ushort4* w4 = (const ushort4*)ws;
  float acc[8] = {0,0,0,0,0,0,0,0};
  for (int e4 = 0; e4 < 64; ++e4) {
    ushort4 u = w4[e4*256 + t];
    float w0 = bf2f(u.x), w1 = bf2f(u.y), w2 = bf2f(u.z), w3 = bf2f(u.w);
    #pragma unroll
    for (int r = 0; r < 8; ++r) {
      float4 uu = *(const float4*)&U[r][e4*4];
      acc[r] += uu.x*w0 + uu.y*w1 + uu.z*w2 + uu.w*w3;
    }
  }
  int h = t >> 5, d = t & 31;
  float a1v = ws[BIAS_OFF + 1280 + t];
  float a2v = ws[BIAS_OFF + 1536 + t];
  unsigned short wvals[8];
  #pragma unroll
  for (int r = 0; r < 8; ++r) {
    int row = r0 + r;
    wvals[r] = f2bf(acc[r]);
    float p1 = acc[r]*a1v, p2 = acc[r]*a2v;
    #pragma unroll
    for (int off = 16; off > 0; off >>= 1) {
      p1 += __shfl_xor(p1, off, 32);
      p2 += __shfl_xor(p2, off, 32);
    }
    if (d == 0) {
      ws[S1_OFF + h*4096 + row] = p1;
      ws[S2_OFF + h*4096 + row] = p2;
    }
  }
  // WhT[h][b][d][n], 8 contiguous n per thread (16B store)
  {
    unsigned short* wht = (unsigned short*)(ws + A_OFF);
    int bb = r0 >> 10, nn = r0 & 1023;
    *(bf16x8s*)(wht + ((long)((h*4 + bb)*32 + d))*1024 + nn) = *(bf16x8s*)wvals;
  }
}

// ------- graph attention, head-split, 16 REAL rows/block -------------------
// GRID 2048, BLOCK 512 (8 waves): 4b x 64 groups x 8h; h in low 3 bits.
#define PB_S 1032    // Pb row stride (ushorts)
__global__ __launch_bounds__(512) void attn1a_kernel(const void* x, float* ws,
                                                     const int* flagp) {
  const int bf = *flagp;
  int t = threadIdx.x;
  int gid = blockIdx.x;
  int h = gid & 7;
  int b = (gid >> 3) & 3;
  int n0 = (gid >> 5) * 16;               // gid>>5 in 0..63
  __shared__ __align__(16) float s2s[1024];
  __shared__ __align__(16) unsigned short Pb[16][PB_S];   // 33 KB
  __shared__ __align__(16) float opart[8][16][17];        // 8.7 KB
  int w = t >> 6, lane = t & 63;          // w 0..7
  int m = lane & 15, quad = lane >> 4;
  const unsigned long long* pk = (const unsigned long long*)(ws + PK_OFF);
  const float* s2p = ws + S2_OFF + h*4096 + b*1024;
  #pragma unroll
  for (int j = 0; j < 2; ++j) s2s[t + 512*j] = s2p[t + 512*j];
  __syncthreads();
  // ---- softmax rows (n0+2w) and (n0+2w+1), head h: register resident ------
  #pragma unroll
  for (int rr = 0; rr < 2; ++rr) {
    int r = 2*w + rr;
    int rowi = __builtin_amdgcn_readfirstlane(b*1024 + n0 + r);
    const unsigned long long* prow = pk + (long)rowi * 16;   // wave-uniform
    float s1v = ws[S1_OFF + h*4096 + rowi];
    float p[16];
    float mx = -3.4e38f;
    #pragma unroll
    for (int j = 0; j < 16; ++j) {
      int mm = lane + 64*j;
      float ev = s1v + s2s[mm];
      ev = (ev >= 0.0f) ? ev : 0.1f*ev;
      ev = ((prow[j] >> lane) & 1ull) ? ev : NEGC;
      p[j] = ev;
      mx = fmaxf(mx, ev);
    }
    #pragma unroll
    for (int off = 32; off > 0; off >>= 1) mx = fmaxf(mx, __shfl_xor(mx, off));
    float s = 0.0f;
    #pragma unroll
    for (int j = 0; j < 16; ++j) { p[j] = __expf(p[j] - mx); s += p[j]; }
    #pragma unroll
    for (int off = 32; off > 0; off >>= 1) s += __shfl_xor(s, off);
    float rs = 1.0f / s;
    #pragma unroll
    for (int j = 0; j < 16; ++j)
      Pb[r][lane + 64*j] = f2bf(p[j] * rs);
    if (lane == 0) {
      ws[MX_OFF + h*4096 + rowi] = mx;
      ws[RS_OFF + h*4096 + rowi] = rs;
    }
  }
  __syncthreads();
  // ---- PV via MFMA: wave w -> d-tile (w&1), key-chunks (w>>1)*8 .. +7 -----
  {
    const unsigned short* wht = (const unsigned short*)(ws + A_OFF);
    int ntile = w & 1;
    int ktbase = (w >> 1) * 8;
    int vd = ntile*16 + m;
    const unsigned short* wrow = wht + ((long)((h*4 + b)*32 + vd))*1024;
    f32x4 acc0 = {0.0f, 0.0f, 0.0f, 0.0f};
    f32x4 acc1 = {0.0f, 0.0f, 0.0f, 0.0f};
    #pragma unroll
    for (int kt2 = 0; kt2 < 4; ++kt2) {
      int kt = ktbase + 2*kt2;
      bf16x8s ap0 = *(const bf16x8s*)&Pb[m][kt*32 + quad*8];
      bf16x8s bw0 = *(const bf16x8s*)(wrow + kt*32 + quad*8);
      acc0 = __builtin_amdgcn_mfma_f32_16x16x32_bf16(ap0, bw0, acc0, 0, 0, 0);
      bf16x8s ap1 = *(const bf16x8s*)&Pb[m][(kt+1)*32 + quad*8];
      bf16x8s bw1 = *(const bf16x8s*)(wrow + (kt+1)*32 + quad*8);
      acc1 = __builtin_amdgcn_mfma_f32_16x16x32_bf16(ap1, bw1, acc1, 0, 0, 0);
    }
    f32x4 acc = acc0 + acc1;
    #pragma unroll
    for (int i = 0; i < 4; ++i)
      opart[w][quad*4 + i][m] = acc[i];
  }
  __syncthreads();
  {
    int r = t >> 5, dd = t & 31;        // 512 threads: 16 rows x 32 d
    int nt = dd >> 4, c = dd & 15;
    float sum = opart[nt][r][c] + opart[nt + 2][r][c]
              + opart[nt + 4][r][c] + opart[nt + 6][r][c];
    float hv = (sum >= 0.0f) ? sum : 0.01f*sum;
    long idx = (long)(b*1024 + n0 + r)*256 + h*32 + dd;
    ws[C_OFF + idx] = ldin(x, idx, bf) + hv;   // raw residual row slice
  }
}

// ------- e_out = mean_h attn (from stored mx/rs) + fused rownorm(xa) -------
__global__ __launch_bounds__(256) void eout_kernel(float* ws, void* dout,
                                                   const int* flagp) {
  const int bf = *flagp;
  int t = threadIdx.x;
  int gid = blockIdx.x;
  int b = gid & 3;
  int n = gid >> 2;
  int row = b*1024 + n;
  int w = t >> 6, lane = t & 63;
  __shared__ float part[8];
  const unsigned long long* pk = (const unsigned long long*)(ws + PK_OFF);
  const unsigned long long* prow = pk + (long)row * 16;
  // ---- rownorm (ddof=1, two-pass) of raw xa row ---------------------------
  float v = ws[C_OFF + (long)row*256 + t];
  float s = v;
  #pragma unroll
  for (int off = 32; off > 0; off >>= 1) s += __shfl_xor(s, off);
  if (lane == 0) part[w] = s;
  __syncthreads();
  float mean = (part[0] + part[1] + part[2] + part[3]) * (1.0f/256.0f);
  float d = v - mean;
  float ss = d*d;
  #pragma unroll
  for (int off = 32; off > 0; off >>= 1) ss += __shfl_xor(ss, off);
  if (lane == 0) part[4 + w] = ss;
  __syncthreads();
  float inv = 1.0f / (sqrtf((part[4]+part[5]+part[6]+part[7]) * (1.0f/255.0f)) + 1e-6f);
  ws[B_OFF + (long)row*256 + t] = d * inv;
  // ---- e_out --------------------------------------------------------------
  float s1v[8], mxv[8], rsv[8];
  #pragma unroll
  for (int h = 0; h < 8; ++h) {
    s1v[h] = ws[S1_OFF + h*4096 + row];
    mxv[h] = ws[MX_OFF + h*4096 + row];
    rsv[h] = ws[RS_OFF + h*4096 + row];
  }
  const float* s2b = ws + S2_OFF + b*1024;
  #pragma unroll
  for (int j = 0; j < 4; ++j) {
    int m = t + 256*j;
    bool a = (prow[w + 4*j] >> lane) & 1ull;
    float acc = 0.0f;
    #pragma unroll
    for (int h = 0; h < 8; ++h) {
      float ev = s1v[h] + s2b[h*4096 + m];
      ev = (ev >= 0.0f) ? ev : 0.1f*ev;
      ev = a ? ev : NEGC;
      acc += rsv[h] * __expf(ev - mxv[h]);
    }
    stout(dout, 1048576L + (long)row*1024 + m, 0.125f*acc, bf);
  }
}

// -------- column (axis=1) stats, ddof=1; scratch = MX region (dead) --------
__global__ __launch_bounds__(256) void colstatsA_kernel(const float* in, float* cs) {
  int t = threadIdx.x;
  int j = blockIdx.x & 63;
  int b = blockIdx.x >> 6;
  float s = 0, ss = 0;
  for (int n = j*16; n < j*16 + 16; ++n) {
    float v = in[(b*1024 + n)*256 + t];
    s += v; ss += v*v;
  }
  cs[(b*64 + j)*256 + t] = s;
  cs[65536 + (b*64 + j)*256 + t] = ss;
}

__global__ __launch_bounds__(256) void colstatsB_kernel(const float* cs, float* st) {
  int t = threadIdx.x;
  int b = blockIdx.x;
  float s = 0, ss = 0;
  for (int j = 0; j < 64; ++j) {
    s  += cs[(b*64 + j)*256 + t];
    ss += cs[65536 + (b*64 + j)*256 + t];
  }
  float mean = s * (1.0f/1024.0f);
  float var = fmaxf((ss - s*mean) * (1.0f/1023.0f), 0.0f);
  st[b*256 + t] = mean;
  st[1024 + b*256 + t] = 1.0f / (sqrtf(var) + 1e-6f);
}

// ---------------- MFMA row-GEMM, fp32-accurate via bf16 hi/lo split --------
// out[row][o] = sum_e in[row][e] * W[o][e] + bias[o];  in = hi + lo (bf16),
// two MFMAs per tile accumulate into one fp32 acc (~2^-16 rel err).
// Block 512 thr (8 waves), 16 rows staged in LDS (bf16 hi/lo, pad 264).
// CS=2: grid 512 = 256 rowgroups x 2 colhalves; wave w -> n-tile colhalf*128+w*16.
// CS=1: grid 256; wave w -> n-tiles w*16 and w*16+128 (full 256 cols; RN-able).
// IN_MODE 1: fp32 + colnorm(st); 2: src permuted (n,b,e)->(b,n,e); 3: fp32 hm.
// OUTM 0: fp32 flat (with RN=1: fused rownorm); 1: d_out; 4: bf16 T hm;
//      5: DUAL Q/K (outp = ws base; Q fp32 hm -> A_OFF, K bf16 hm -> B_OFF).
// mfma_f32_16x16x32_bf16 layouts (m89-verified): A[m=lane&15][k=quad*8+j];
//   B[k=quad*8+j][n=lane&15]; D col=lane&15, row=quad*4+i.
template<int IN_MODE, int RN, int OUTM, int CS>
__global__ __launch_bounds__(512) void gemm2_kernel(const void* inp,
    const unsigned short* wmat, const unsigned short* wmat2,
    const float* bias, const float* bias2, const float* st,
    void* outp, const int* flagp) {
  const int bf = *flagp;
  int t = threadIdx.x;
  int gid = blockIdx.x;
  int rowg = (CS == 2) ? (gid >> 1) : gid;
  int colbase = (CS == 2) ? ((gid & 1) * 128) : 0;
  int r0 = rowg * 16;
  __shared__ __align__(16) unsigned short Usm[2*16*264];    // 16.9 KB
  unsigned short (*Uh)[264] = (unsigned short (*)[264])Usm;
  unsigned short (*Ul)[264] = (unsigned short (*)[264])(Usm + 16*264);
  // ---- stage 16 rows as bf16 hi/lo ----------------------------------------
  {
    int srow = t >> 5;
    int e0 = (t & 31) * 8;
    long grow = r0 + srow;
    float v[8];
    if (IN_MODE == 1) {
      int b = (int)(grow >> 10);
      const float* ip = (const float*)inp + grow*256 + e0;
      const float* mp = st + b*256 + e0;
      const float* vp = st + 1024 + b*256 + e0;
      #pragma unroll
      for (int j = 0; j < 8; ++j) v[j] = (ip[j] - mp[j]) * vp[j];
    } else if (IN_MODE == 2) {
      int b = (int)(grow >> 10), n = (int)(grow & 1023);
      #pragma unroll
      for (int j = 0; j < 8; ++j)
        v[j] = ldin(inp, (long)(n*4 + b)*256 + e0 + j, bf);
    } else {
      int b = (int)(grow >> 10), n = (int)(grow & 1023);
      const float* ip = (const float*)inp
          + ((long)(b*8 + (e0 >> 5))*1024 + n)*32 + (e0 & 31);
      #pragma unroll
      for (int j = 0; j < 8; ++j) v[j] = ip[j];
    }
    unsigned short hv[8], lv[8];
    #pragma unroll
    for (int j = 0; j < 8; ++j) {
      hv[j] = f2bf(v[j]);
      lv[j] = f2bf(v[j] - bf2f(hv[j]));
    }
    *(bf16x8s*)&Uh[srow][e0] = *(bf16x8s*)hv;
    *(bf16x8s*)&Ul[srow][e0] = *(bf16x8s*)lv;
  }
  __syncthreads();
  int w = t >> 6, lane = t & 63, m = lane & 15, quad = lane >> 4;
  const int NT = (CS == 1) ? 2 : 1;
  f32x4 accs[2];
  f32x4 acck;
  #pragma unroll
  for (int nt = 0; nt < NT; ++nt) {
    int o = colbase + w*16 + nt*128 + m;
    const unsigned short* wp = wmat + o*256 + quad*8;
    f32x4 ah_acc = {0,0,0,0}, al_acc = {0,0,0,0};
    f32x4 kh_acc = {0,0,0,0}, kl_acc = {0,0,0,0};
    const unsigned short* wp2 = (OUTM == 5) ? (wmat2 + o*256 + quad*8) : wp;
    #pragma unroll
    for (int kt = 0; kt < 8; ++kt) {
      bf16x8s ah = *(const bf16x8s*)&Uh[m][kt*32 + quad*8];
      bf16x8s al = *(const bf16x8s*)&Ul[m][kt*32 + quad*8];
      bf16x8s bw = *(const bf16x8s*)(wp + kt*32);
      ah_acc = __builtin_amdgcn_mfma_f32_16x16x32_bf16(ah, bw, ah_acc, 0, 0, 0);
      al_acc = __builtin_amdgcn_mfma_f32_16x16x32_bf16(al, bw, al_acc, 0, 0, 0);
      if (OUTM == 5) {
        bf16x8s bw2 = *(const bf16x8s*)(wp2 + kt*32);
        kh_acc = __builtin_amdgcn_mfma_f32_16x16x32_bf16(ah, bw2, kh_acc, 0, 0, 0);
        kl_acc = __builtin_amdgcn_mfma_f32_16x16x32_bf16(al, bw2, kl_acc, 0, 0, 0);
      }
    }
    accs[nt] = ah_acc + al_acc;
    if (OUTM == 5) acck = kh_acc + kl_acc;
    if (RN == 0) {
      float bv = bias[o];
      if constexpr (OUTM == 0) {
        #pragma unroll
        for (int i = 0; i < 4; ++i) {
          long row = r0 + quad*4 + i;
          ((float*)outp)[row*256 + o] = accs[nt][i] + bv;
        }
      } else if constexpr (OUTM == 1) {
        #pragma unroll
        for (int i = 0; i < 4; ++i) {
          long row = r0 + quad*4 + i;
          stout(outp, row*256 + o, accs[nt][i] + bv, bf);
        }
      } else if constexpr (OUTM == 4) {
        int h = o >> 5, d = o & 31;
        #pragma unroll
        for (int i = 0; i < 4; ++i) {
          long row = r0 + quad*4 + i;
          int b = (int)(row >> 10), n = (int)(row & 1023);
          ((unsigned short*)outp)[((long)((b*8 + h)*32 + d))*1024 + n]
              = f2bf(accs[nt][i] + bv);
        }
      } else if constexpr (OUTM == 5) {
        float* wsf = (float*)outp;                 // outp = ws base
        float* qhm = wsf + A_OFF;
        unsigned short* khm = (unsigned short*)(wsf + B_OFF);
        float bq = bias[o], bk = bias2[o];
        int h = o >> 5, d = o & 31;
        #pragma unroll
        for (int i = 0; i < 4; ++i) {
          long row = r0 + quad*4 + i;
          int b = (int)(row >> 10), n = (int)(row & 1023);
          long idx = ((long)((b*8 + h)*1024 + n))*32 + d;
          qhm[idx] = accs[nt][i] + bq;
          khm[idx] = f2bf(acck[i] + bk);
        }
      }
    }
  }
  if constexpr (RN == 1) {
    // overlay O (fp32 16x264) on Usm; all U reads are done
    __syncthreads();
    float (*O)[264] = (float (*)[264])Usm;
    #pragma unroll
    for (int nt = 0; nt < NT; ++nt) {
      int oc = colbase + w*16 + nt*128 + m;
      float bv = bias[oc];
      #pragma unroll
      for (int i = 0; i < 4; ++i)
        O[quad*4 + i][oc] = accs[nt][i] + bv;
    }
    __syncthreads();
    #pragma unroll
    for (int rr = 0; rr < 2; ++rr) {
      int r = 2*w + rr;
      float vals[4]; float s = 0.0f;
      #pragma unroll
      for (int j = 0; j < 4; ++j) { vals[j] = O[r][lane + 64*j]; s += vals[j]; }
      #pragma unroll
      for (int off = 32; off > 0; off >>= 1) s += __shfl_xor(s, off);
      float mean = s * (1.0f/256.0f);
      float ss = 0.0f;
      #pragma unroll
      for (int j = 0; j < 4; ++j) { float d = vals[j] - mean; ss += d*d; }
      #pragma unroll
      for (int off = 32; off > 0; off >>= 1) ss += __shfl_xor(ss, off);
      float inv = 1.0f / (sqrtf(ss * (1.0f/255.0f)) + 1e-6f);
      #pragma unroll
      for (int j = 0; j < 4; ++j)
        ((float*)outp)[(long)(r0 + r)*256 + lane + 64*j] = (vals[j] - mean) * inv;
    }
  }
}

// ---------------- MHA via MFMA, bf16 K/V, 16 q-rows per block --------------
#define SPS 1036
__global__ __launch_bounds__(512) void attn2_kernel(float* ws) {
  int t = threadIdx.x;
  int gid = blockIdx.x;
  int h = gid & 7;
  int b = (gid >> 3) & 3;
  int n0 = (gid >> 5) << 4;   // 16 q-rows per block; gid>>5 in 0..63
  __shared__ __align__(16) float Sp[16*SPS];        // 66.3 KB
  __shared__ __align__(16) float opart[8][16][17];  // 8.7 KB
  float* qq = ws + A_OFF;
  const unsigned short* kk = (const unsigned short*)(ws + B_OFF);
  const unsigned short* vt = (const unsigned short*)(ws + C_OFF);
  int base_bh = (b*8 + h)*1024;
  int w = t >> 6, lane = t & 63;   // w 0..7
  int m = lane & 15, quad = lane >> 4;
  const float scl = 0.17677669529663687f; // 1/sqrt(32)
  // ---- QK via MFMA: wave w covers keys w*128 .. +127 ----------------------
  {
    const float* qp = qq + (base_bh + n0 + m)*32 + quad*8;   // 16 real rows
    bf16x8s aq;
    #pragma unroll
    for (int j = 0; j < 8; ++j) ((unsigned short*)&aq)[j] = f2bf(qp[j]);
    f32x4 zero = {0.0f, 0.0f, 0.0f, 0.0f};
    #pragma unroll
    for (int kt = 0; kt < 8; ++kt) {
      int kbase = w*128 + kt*16;
      bf16x8s bk = *(const bf16x8s*)(kk + (base_bh + kbase + m)*32 + quad*8);
      f32x4 d = __builtin_amdgcn_mfma_f32_16x16x32_bf16(aq, bk, zero, 0, 0, 0);
      int key = kbase + m;
      #pragma unroll
      for (int i = 0; i < 4; ++i)
        Sp[(quad*4 + i)*SPS + key] = d[i] * scl;
    }
  }
  __syncthreads();
  // ---- softmax: wave w owns rows 2w, 2w+1; single pass, bf16 overlay ------
  #pragma unroll
  for (int rr = 0; rr < 2; ++rr) {
    int r = 2*w + rr;
    float* Sr = Sp + r*SPS;
    float p[16];
    #pragma unroll
    for (int j = 0; j < 16; ++j) p[j] = Sr[lane + 64*j];
    float mx = -3.4e38f;
    #pragma unroll
    for (int j = 0; j < 16; ++j) mx = fmaxf(mx, p[j]);
    #pragma unroll
    for (int off = 32; off > 0; off >>= 1) mx = fmaxf(mx, __shfl_xor(mx, off));
    float s = 0.0f;
    #pragma unroll
    for (int j = 0; j < 16; ++j) { p[j] = __expf(p[j] - mx); s += p[j]; }
    #pragma unroll
    for (int off = 32; off > 0; off >>= 1) s += __shfl_xor(s, off);
    float rs = 1.0f / s;
    unsigned short* Pr = (unsigned short*)Sr;     // bf16 overlay, same row
    #pragma unroll
    for (int j = 0; j < 16; ++j)
      Pr[lane + 64*j] = f2bf(p[j] * rs);
  }
  __syncthreads();
  // ---- PV via MFMA: wave w -> d-tile (w&1), key-chunks (w>>1)*8 .. +7 -----
  {
    int ntile = w & 1;
    int ktbase = (w >> 1) * 8;
    int vd = ntile*16 + m;
    const unsigned short* vrow = vt + base_bh*32 + vd*1024;
    const unsigned short* P0 = (const unsigned short*)Sp + m*(SPS*2);  // row m
    f32x4 acc0 = {0.0f, 0.0f, 0.0f, 0.0f};
    f32x4 acc1 = {0.0f, 0.0f, 0.0f, 0.0f};
    #pragma unroll
    for (int kt2 = 0; kt2 < 4; ++kt2) {
      int kt = ktbase + 2*kt2;
      bf16x8s ap0 = *(const bf16x8s*)(P0 + kt*32 + quad*8);
      bf16x8s bv0 = *(const bf16x8s*)(vrow + kt*32 + quad*8);
      acc0 = __builtin_amdgcn_mfma_f32_16x16x32_bf16(ap0, bv0, acc0, 0, 0, 0);
      bf16x8s ap1 = *(const bf16x8s*)(P0 + (kt+1)*32 + quad*8);
      bf16x8s bv1 = *(const bf16x8s*)(vrow + (kt+1)*32 + quad*8);
      acc1 = __builtin_amdgcn_mfma_f32_16x16x32_bf16(ap1, bv1, acc1, 0, 0, 0);
    }
    f32x4 acc = acc0 + acc1;
    #pragma unroll
    for (int i = 0; i < 4; ++i)
      opart[w][quad*4 + i][m] = acc[i];
  }
  __syncthreads();
  {
    int r = t >> 5, d = t & 31;         // 512 threads: 16 rows x 32 d
    int nt = d >> 4, c = d & 15;
    float sum = opart[nt][r][c] + opart[nt + 2][r][c]
              + opart[nt + 4][r][c] + opart[nt + 6][r][c];
    qq[(base_bh + n0 + r)*32 + d] = sum;   // o over q (own slots)
  }
}

extern "C" void kernel_launch(void* const* d_in, const int* in_sizes, int n_in,
                              void* d_out, int out_size, void* d_ws, size_t ws_size,
                              hipStream_t stream) {
  const void* x   = d_in[0];
  const void* src = d_in[1];
  const int* adj  = (const int*)d_in[2];
  const void* wg  = d_in[3];
  const void* a1  = d_in[4];
  const void* a2  = d_in[5];
  const void* lw  = d_in[6];
  const void* lb  = d_in[7];
  const void* ipw = d_in[8];
  const void* ipb = d_in[9];
  const void* opw = d_in[10];
  const void* opb = d_in[11];
  float* ws = (float*)d_ws;
  const unsigned short* wbf = (const unsigned short*)d_ws;
  int* flagp = (int*)(ws + FLAG_F);

  detect_kernel<<<1, 64, 0, stream>>>((const unsigned short*)x, flagp);
  prep_kernel<<<dim3(256, 7), 256, 0, stream>>>(wg, lw, ipw, opw, lb, ipb, opb,
                                                a1, a2, ws, flagp);
  packadj_kernel<<<4096, 256, 0, stream>>>(adj,
      (unsigned long long*)(ws + PK_OFF));
  whs_kernel<<<512, 256, 0, stream>>>(x, ws, flagp);
  attn1a_kernel<<<2048, 512, 0, stream>>>(x, ws, flagp);       // xa -> C, mx/rs
  eout_kernel<<<4096, 256, 0, stream>>>(ws, d_out, flagp);     // e_out; rownorm -> B
  colstatsA_kernel<<<256, 256, 0, stream>>>(ws + B_OFF, ws + MX_OFF);
  colstatsB_kernel<<<4, 256, 0, stream>>>(ws + MX_OFF, ws + ST1_OFF);
  gemm2_kernel<1,1,0,1><<<256, 512, 0, stream>>>(ws + B_OFF, wbf + 1*65536,
      nullptr, ws + BIAS_OFF, nullptr, ws + ST1_OFF, ws + C_OFF, flagp); // lin+RN -> C
  colstatsA_kernel<<<256, 256, 0, stream>>>(ws + C_OFF, ws + MX_OFF);
  colstatsB_kernel<<<4, 256, 0, stream>>>(ws + MX_OFF, ws + ST2_OFF);
  gemm2_kernel<1,0,5,2><<<512, 512, 0, stream>>>(ws + C_OFF, wbf + 2*65536,
      wbf + 3*65536, ws + BIAS_OFF + 256, ws + BIAS_OFF + 512, ws + ST2_OFF,
      ws, flagp);                                              // Q -> A, K -> B
  gemm2_kernel<2,0,4,2><<<512, 512, 0, stream>>>(src, wbf + 4*65536,
      nullptr, ws + BIAS_OFF + 768, nullptr, nullptr, ws + C_OFF, flagp); // V^T -> C
  attn2_kernel<<<2048, 512, 0, stream>>>(ws);                  // o -> A_OFF
  gemm2_kernel<3,0,1,2><<<512, 512, 0, stream>>>(ws + A_OFF, wbf + 5*65536,
      nullptr, ws + BIAS_OFF + 1024, nullptr, nullptr, d_out, flagp);    // out-proj
}

// Round 8
// 245.649 us; speedup vs baseline: 1.4172x; 1.0387x over previous
//
#include <hip/hip_runtime.h>
#include <hip/hip_bf16.h>

// B=4, N=1024, E=256, H=8, D=32. Float tensors may be bf16 OR fp32 in d_in /
// d_out (detected at runtime on-device); adj is int32.
// Output: x_out [4,1024,256] then e_out [4,1024,1024] (element offsets).
//
// ws float offsets:
//   [0 .. 196608)   : weight matrices, bf16, ushort offset m*65536, ALL o-major
//       W[o][e] at m*65536 + o*256 + e.  m: 0=Wcat 1=LIN 2=WQ 3=WK 4=WV 5=WO
#define BIAS_OFF 196608   // lin_b, bq, bk, bv, bo, a1, a2  (7*256 fp32)
#define S1_OFF   198400   // [h][4096]
#define S2_OFF   231168
#define CS_OFF   263936   // ca1[8][256], ca2[8][256], zero-bias[256] (prep-filled)
#define ST1_OFF  296704   // mean[1024] + inv[1024]
#define ST2_OFF  298752
#define A_OFF    300800   // WhT bf16 [b][h][d][n] (2 MB) -> later Q,o fp32 head-major
#define MX_OFF   825088   // softmax row max [h][4096]; later colstats scratch (131072 f)
#define RS_OFF   857856   // softmax row 1/sum [h][4096]
#define PK_OFF   890624   // packed adj bitmask: [4096 rows][16 u64] = 512 KB (dead after eout)
#define B_OFF    1349376  // 4 MB: rownorm(xa)     -> later K bf16 head-major [b][h][n][32]
#define C_OFF    2397952  // 4 MB: raw xa, then rownorm(lin) -> later V^T bf16 hm [b][h][d][n]
#define FLAG_F   3446528  // int: 1 = bf16 tensors, 0 = fp32 tensors
// end 3446529 floats = 13.8 MB

#define NEGC (-9.0e15f)

typedef __attribute__((ext_vector_type(8))) short bf16x8s;
typedef __attribute__((ext_vector_type(4))) float f32x4;

static __device__ __forceinline__ float bf2f(unsigned short u) {
  union { unsigned int i; float f; } v; v.i = ((unsigned int)u) << 16; return v.f;
}
static __device__ __forceinline__ unsigned short f2bf(float f) {
  union { float f; unsigned int u; } v; v.f = f;
  unsigned int r = (v.u + 0x7FFFu + ((v.u >> 16) & 1u)) >> 16;   // RNE
  return (unsigned short)r;
}
static __device__ __forceinline__ float ldin(const void* p, long i, int bf) {
  return bf ? bf2f(((const unsigned short*)p)[i]) : ((const float*)p)[i];
}
static __device__ __forceinline__ unsigned short rdbf(const void* p, long i, int bf) {
  if (bf) return ((const unsigned short*)p)[i];
  return f2bf(((const float*)p)[i]);
}
static __device__ __forceinline__ void stout(void* p, long i, float v, int bf) {
  if (bf) ((unsigned short*)p)[i] = f2bf(v);
  else    ((float*)p)[i] = v;
}

// ---------------- dtype detector -------------------------------------------
__global__ __launch_bounds__(64) void detect_kernel(const unsigned short* x, int* flag) {
  int lane = threadIdx.x;
  unsigned short u = x[2 * lane];
  int e = (u >> 7) & 0xFF;
  bool good = (e >= 100 && e <= 140);
  unsigned long long m = __ballot(good);
  if (lane == 0) *flag = (__popcll(m) >= 48) ? 1 : 0;
}

// ---------------- adj -> bitmask: [row][16 u64], bit m%64 of word m/64 -----
__global__ __launch_bounds__(256) void packadj_kernel(const int* adj,
                                                      unsigned long long* pk) {
  int t = threadIdx.x, w = t >> 6, lane = t & 63;
  long row = blockIdx.x;            // 4096 rows
  #pragma unroll
  for (int j = 0; j < 4; ++j) {
    int m = t + 256*j;              // wave covers bits [w*64+256j .. +63]
    bool bit = adj[row*1024 + m] > 0;
    unsigned long long mask = __ballot(bit);
    if (lane == 0) pk[row*16 + w + 4*j] = mask;
  }
}

// ------- prep: all weights -> o-major bf16; ca1/ca2 = Wg·a1/a2; biases -----
__global__ __launch_bounds__(256) void prep_kernel(
    const void* wg, const void* lin_w, const void* inp_w, const void* out_w,
    const void* lin_b, const void* inp_b, const void* out_b,
    const void* a1, const void* a2, float* ws, const int* flagp) {
  const int bf = *flagp;
  unsigned short* wbf = (unsigned short*)ws;
  int t = threadIdx.x;        // o (output feature)
  int f = blockIdx.x;         // e (input feature)
  int m = blockIdx.y;
  if (m == 0) {
    int h = t >> 5, d = t & 31;
    wbf[t*256 + f] = rdbf(wg, h*8192 + f*32 + d, bf);   // Wcat[o=h*32+d][e]
  } else if (m <= 5) {
    int dst = m*65536 + t*256 + f;          // W[o=t][e=f]
    if (m == 1)      wbf[dst] = rdbf(lin_w, t*256 + f, bf);
    else if (m == 2) wbf[dst] = rdbf(inp_w, t*256 + f, bf);
    else if (m == 3) wbf[dst] = rdbf(inp_w, (256 + t)*256 + f, bf);
    else if (m == 4) wbf[dst] = rdbf(inp_w, (512 + t)*256 + f, bf);
    else             wbf[dst] = rdbf(out_w, t*256 + f, bf);
  } else {
    // m == 6: ca1[h][e] = sum_d Wg[h][e][d]*a1[h][d]; ca2 likewise
    int h = t >> 5, d = t & 31;
    float wv = ldin(wg, h*8192 + f*32 + d, bf);
    float p1 = wv * ldin(a1, t, bf);
    float p2 = wv * ldin(a2, t, bf);
    #pragma unroll
    for (int off = 16; off > 0; off >>= 1) {
      p1 += __shfl_xor(p1, off, 32);
      p2 += __shfl_xor(p2, off, 32);
    }
    if (d == 0) {
      ws[CS_OFF + h*256 + f]        = p1;
      ws[CS_OFF + 2048 + h*256 + f] = p2;
    }
    if (f == 0) {
      ws[BIAS_OFF + t]        = ldin(lin_b, t, bf);
      ws[BIAS_OFF + 256 + t]  = ldin(inp_b, t, bf);
      ws[BIAS_OFF + 512 + t]  = ldin(inp_b, 256 + t, bf);
      ws[BIAS_OFF + 768 + t]  = ldin(inp_b, 512 + t, bf);
      ws[BIAS_OFF + 1024 + t] = ldin(out_b, t, bf);
      ws[CS_OFF + 4096 + t]   = 0.0f;        // zero bias for Wcat GEMM
    }
  }
}

// ---- s1/s2 = x @ ca  (4096x256 @ 256x16 GEMV); grid 256, 16 rows/block ----
__global__ __launch_bounds__(256) void s1s2_kernel(const void* x, float* ws,
                                                   const int* flagp) {
  const int bf = *flagp;
  int t = threadIdx.x;
  int r0 = blockIdx.x * 16;
  __shared__ float X[16][260];
  __shared__ float CA[16][260];
  #pragma unroll
  for (int r = 0; r < 16; ++r)
    X[r][t] = ldin(x, (long)(r0 + r)*256 + t, bf);
  #pragma unroll
  for (int i = 0; i < 16; ++i)
    CA[i][t] = ws[CS_OFF + ((i < 8) ? i*256 : 2048 + (i - 8)*256) + t];
  __syncthreads();
  int r = t >> 4, c = t & 15;
  float acc = 0.0f;
  for (int e = 0; e < 256; ++e) acc += X[r][e] * CA[c][e];
  int row = r0 + r;
  if (c < 8) ws[S1_OFF + c*4096 + row] = acc;
  else       ws[S2_OFF + (c - 8)*4096 + row] = acc;
}

// ------- graph attention, head-split, 32 REAL rows/block -------------------
// GRID 1024, BLOCK 512 (8 waves): 4b x 32 groups x 8h; h in low 3 bits
// (XCD-L2 locality on WhT). adj from packed bitmask (scalar loads).
// Softmax register-resident: wave w owns rows 4w..4w+3. P bf16 in Pb[32]
// (two 16-row A-frag groups; PV shares each bw load across both groups).
// PV: wave w -> d-tile (w&1), key-chunks (w>>1)*8..+7; opart OVERLAYS the
// dead Pb/s2s arena after a barrier (all Pb reads complete). LDS 68.5 KB ->
// 2 blocks/CU. WhT now [b][h][d][n] (from gemm2whs). Writes:
//   C region: raw xa slice  xa[b,n,h*32+d] = x + leaky(PV)
//   MX/RS: per-(h,row) softmax max and 1/sum (consumed by eout_kernel)
#define PB_S 1032    // Pb row stride (ushorts); 2064 B -> m*4 banks, conflict-free
__global__ __launch_bounds__(512) void attn1a_kernel(const void* x, float* ws,
                                                     const int* flagp) {
  const int bf = *flagp;
  int t = threadIdx.x;
  int gid = blockIdx.x;
  int h = gid & 7;
  int b = (gid >> 3) & 3;
  int n0 = (gid >> 5) * 32;               // gid>>5 in 0..31
  __shared__ __align__(16) unsigned char arena[4096 + 32*PB_S*2];  // 68.5 KB
  float* s2s = (float*)arena;
  unsigned short (*Pb)[PB_S] = (unsigned short (*)[PB_S])(arena + 4096);
  float (*opart)[32][17] = (float (*)[32][17])arena;   // overlay (after Pb dead)
  int w = t >> 6, lane = t & 63;          // w 0..7
  int m = lane & 15, quad = lane >> 4;
  const unsigned long long* pk = (const unsigned long long*)(ws + PK_OFF);
  const float* s2p = ws + S2_OFF + h*4096 + b*1024;
  #pragma unroll
  for (int j = 0; j < 2; ++j) s2s[t + 512*j] = s2p[t + 512*j];
  __syncthreads();
  // ---- softmax rows n0+4w .. n0+4w+3, head h: register resident -----------
  #pragma unroll
  for (int rr = 0; rr < 4; ++rr) {
    int r = 4*w + rr;
    int rowi = __builtin_amdgcn_readfirstlane(b*1024 + n0 + r);
    const unsigned long long* prow = pk + (long)rowi * 16;   // wave-uniform
    float s1v = ws[S1_OFF + h*4096 + rowi];
    float p[16];
    float mx = -3.4e38f;
    #pragma unroll
    for (int j = 0; j < 16; ++j) {
      int mm = lane + 64*j;
      float ev = s1v + s2s[mm];
      ev = (ev >= 0.0f) ? ev : 0.1f*ev;
      ev = ((prow[j] >> lane) & 1ull) ? ev : NEGC;
      p[j] = ev;
      mx = fmaxf(mx, ev);
    }
    #pragma unroll
    for (int off = 32; off > 0; off >>= 1) mx = fmaxf(mx, __shfl_xor(mx, off));
    float s = 0.0f;
    #pragma unroll
    for (int j = 0; j < 16; ++j) { p[j] = __expf(p[j] - mx); s += p[j]; }
    #pragma unroll
    for (int off = 32; off > 0; off >>= 1) s += __shfl_xor(s, off);
    float rs = 1.0f / s;
    #pragma unroll
    for (int j = 0; j < 16; ++j)
      Pb[r][lane + 64*j] = f2bf(p[j] * rs);
    if (lane == 0) {
      ws[MX_OFF + h*4096 + rowi] = mx;
      ws[RS_OFF + h*4096 + rowi] = rs;
    }
  }
  __syncthreads();
  // ---- PV via MFMA: wave w -> d-tile (w&1), key-chunks (w>>1)*8 .. +7 -----
  f32x4 g0, g1;
  {
    const unsigned short* wht = (const unsigned short*)(ws + A_OFF);
    int ntile = w & 1;
    int ktbase = (w >> 1) * 8;
    int vd = ntile*16 + m;
    const unsigned short* wrow = wht + ((long)((b*8 + h)*32 + vd))*1024;
    f32x4 a0g0 = {0,0,0,0}, a1g0 = {0,0,0,0};
    f32x4 a0g1 = {0,0,0,0}, a1g1 = {0,0,0,0};
    #pragma unroll
    for (int kt2 = 0; kt2 < 4; ++kt2) {
      int kt = ktbase + 2*kt2;
      bf16x8s bw0 = *(const bf16x8s*)(wrow + kt*32 + quad*8);
      bf16x8s bw1 = *(const bf16x8s*)(wrow + (kt+1)*32 + quad*8);
      bf16x8s p00 = *(const bf16x8s*)&Pb[m][kt*32 + quad*8];
      bf16x8s p01 = *(const bf16x8s*)&Pb[16 + m][kt*32 + quad*8];
      a0g0 = __builtin_amdgcn_mfma_f32_16x16x32_bf16(p00, bw0, a0g0, 0, 0, 0);
      a0g1 = __builtin_amdgcn_mfma_f32_16x16x32_bf16(p01, bw0, a0g1, 0, 0, 0);
      bf16x8s p10 = *(const bf16x8s*)&Pb[m][(kt+1)*32 + quad*8];
      bf16x8s p11 = *(const bf16x8s*)&Pb[16 + m][(kt+1)*32 + quad*8];
      a1g0 = __builtin_amdgcn_mfma_f32_16x16x32_bf16(p10, bw1, a1g0, 0, 0, 0);
      a1g1 = __builtin_amdgcn_mfma_f32_16x16x32_bf16(p11, bw1, a1g1, 0, 0, 0);
    }
    g0 = a0g0 + a1g0;
    g1 = a0g1 + a1g1;
  }
  __syncthreads();          // all Pb reads complete -> arena reusable
  #pragma unroll
  for (int i = 0; i < 4; ++i) {
    opart[w][quad*4 + i][m]      = g0[i];
    opart[w][16 + quad*4 + i][m] = g1[i];
  }
  __syncthreads();
  #pragma unroll
  for (int half = 0; half < 2; ++half) {
    int r = (t >> 5) + half*16;         // 16 rows per half
    int dd = t & 31;
    int nt = dd >> 4, c = dd & 15;
    float sum = opart[nt][r][c] + opart[nt + 2][r][c]
              + opart[nt + 4][r][c] + opart[nt + 6][r][c];
    float hv = (sum >= 0.0f) ? sum : 0.01f*sum;
    long idx = (long)(b*1024 + n0 + r)*256 + h*32 + dd;
    ws[C_OFF + idx] = ldin(x, idx, bf) + hv;   // raw residual row slice
  }
}

// ------- e_out = mean_h attn (from stored mx/rs) + fused rownorm(xa) -------
__global__ __launch_bounds__(256) void eout_kernel(float* ws, void* dout,
                                                   const int* flagp) {
  const int bf = *flagp;
  int t = threadIdx.x;
  int gid = blockIdx.x;
  int b = gid & 3;
  int n = gid >> 2;
  int row = b*1024 + n;
  int w = t >> 6, lane = t & 63;
  __shared__ float part[8];
  const unsigned long long* pk = (const unsigned long long*)(ws + PK_OFF);
  const unsigned long long* prow = pk + (long)row * 16;
  // ---- rownorm (ddof=1, two-pass) of raw xa row ---------------------------
  float v = ws[C_OFF + (long)row*256 + t];
  float s = v;
  #pragma unroll
  for (int off = 32; off > 0; off >>= 1) s += __shfl_xor(s, off);
  if (lane == 0) part[w] = s;
  __syncthreads();
  float mean = (part[0] + part[1] + part[2] + part[3]) * (1.0f/256.0f);
  float d = v - mean;
  float ss = d*d;
  #pragma unroll
  for (int off = 32; off > 0; off >>= 1) ss += __shfl_xor(ss, off);
  if (lane == 0) part[4 + w] = ss;
  __syncthreads();
  float inv = 1.0f / (sqrtf((part[4]+part[5]+part[6]+part[7]) * (1.0f/255.0f)) + 1e-6f);
  ws[B_OFF + (long)row*256 + t] = d * inv;
  // ---- e_out --------------------------------------------------------------
  float s1v[8], mxv[8], rsv[8];
  #pragma unroll
  for (int h = 0; h < 8; ++h) {
    s1v[h] = ws[S1_OFF + h*4096 + row];
    mxv[h] = ws[MX_OFF + h*4096 + row];
    rsv[h] = ws[RS_OFF + h*4096 + row];
  }
  const float* s2b = ws + S2_OFF + b*1024;
  #pragma unroll
  for (int j = 0; j < 4; ++j) {
    int m = t + 256*j;
    bool a = (prow[w + 4*j] >> lane) & 1ull;
    float acc = 0.0f;
    #pragma unroll
    for (int h = 0; h < 8; ++h) {
      float ev = s1v[h] + s2b[h*4096 + m];
      ev = (ev >= 0.0f) ? ev : 0.1f*ev;
      ev = a ? ev : NEGC;
      acc += rsv[h] * __expf(ev - mxv[h]);
    }
    stout(dout, 1048576L + (long)row*1024 + m, 0.125f*acc, bf);
  }
}

// -------- column (axis=1) stats, ddof=1; scratch in MX region (dead) -------
__global__ __launch_bounds__(256) void colstatsA_kernel(const float* in, float* cs) {
  int t = threadIdx.x;
  int j = blockIdx.x & 63;
  int b = blockIdx.x >> 6;
  float s = 0, ss = 0;
  for (int n = j*16; n < j*16 + 16; ++n) {
    float v = in[(b*1024 + n)*256 + t];
    s += v; ss += v*v;
  }
  cs[(b*64 + j)*256 + t] = s;
  cs[65536 + (b*64 + j)*256 + t] = ss;
}

__global__ __launch_bounds__(256) void colstatsB_kernel(const float* cs, float* st) {
  int t = threadIdx.x;
  int b = blockIdx.x;
  float s = 0, ss = 0;
  for (int j = 0; j < 64; ++j) {
    s  += cs[(b*64 + j)*256 + t];
    ss += cs[65536 + (b*64 + j)*256 + t];
  }
  float mean = s * (1.0f/1024.0f);
  float var = fmaxf((ss - s*mean) * (1.0f/1023.0f), 0.0f);
  st[b*256 + t] = mean;
  st[1024 + b*256 + t] = 1.0f / (sqrtf(var) + 1e-6f);
}

// ---------------- MFMA row-GEMM, fp32-accurate via bf16 hi/lo split --------
// out[row][o] = sum_e in[row][e] * W[o][e] + bias[o];  in = hi + lo (bf16).
// Block 512 thr (8 waves), 16 rows staged in LDS (bf16 hi/lo, pad 264).
// CS=2: grid 512 = 256 rowgroups x 2 colhalves. CS=1: grid 256 (RN-able).
// IN_MODE 0: d_in flat (dtype flag); 1: fp32 + colnorm(st); 2: src permuted
//   (n,b,e)->(b,n,e); 3: fp32 head-major.
// OUTM 0: fp32 flat (RN=1: fused rownorm + column partials -> csout);
//   1: d_out; 4: bf16 T hm [b][h][d][n]; 5: DUAL Q/K (Q fp32 hm A, K bf16 B).
template<int IN_MODE, int RN, int OUTM, int CS>
__global__ __launch_bounds__(512) void gemm2_kernel(const void* inp,
    const unsigned short* wmat, const unsigned short* wmat2,
    const float* bias, const float* bias2, const float* st,
    void* outp, float* csout, const int* flagp) {
  const int bf = *flagp;
  int t = threadIdx.x;
  int gid = blockIdx.x;
  int rowg = (CS == 2) ? (gid >> 1) : gid;
  int colbase = (CS == 2) ? ((gid & 1) * 128) : 0;
  int r0 = rowg * 16;
  __shared__ __align__(16) unsigned short Usm[2*16*264];    // 16.9 KB
  unsigned short (*Uh)[264] = (unsigned short (*)[264])Usm;
  unsigned short (*Ul)[264] = (unsigned short (*)[264])(Usm + 16*264);
  // ---- stage 16 rows as bf16 hi/lo ----------------------------------------
  {
    int srow = t >> 5;
    int e0 = (t & 31) * 8;
    long grow = r0 + srow;
    float v[8];
    if (IN_MODE == 0) {
      #pragma unroll
      for (int j = 0; j < 8; ++j) v[j] = ldin(inp, grow*256 + e0 + j, bf);
    } else if (IN_MODE == 1) {
      int b = (int)(grow >> 10);
      const float* ip = (const float*)inp + grow*256 + e0;
      const float* mp = st + b*256 + e0;
      const float* vp = st + 1024 + b*256 + e0;
      #pragma unroll
      for (int j = 0; j < 8; ++j) v[j] = (ip[j] - mp[j]) * vp[j];
    } else if (IN_MODE == 2) {
      int b = (int)(grow >> 10), n = (int)(grow & 1023);
      #pragma unroll
      for (int j = 0; j < 8; ++j)
        v[j] = ldin(inp, (long)(n*4 + b)*256 + e0 + j, bf);
    } else {
      int b = (int)(grow >> 10), n = (int)(grow & 1023);
      const float* ip = (const float*)inp
          + ((long)(b*8 + (e0 >> 5))*1024 + n)*32 + (e0 & 31);
      #pragma unroll
      for (int j = 0; j < 8; ++j) v[j] = ip[j];
    }
    unsigned short hv[8], lv[8];
    #pragma unroll
    for (int j = 0; j < 8; ++j) {
      hv[j] = f2bf(v[j]);
      lv[j] = f2bf(v[j] - bf2f(hv[j]));
    }
    *(bf16x8s*)&Uh[srow][e0] = *(bf16x8s*)hv;
    *(bf16x8s*)&Ul[srow][e0] = *(bf16x8s*)lv;
  }
  __syncthreads();
  int w = t >> 6, lane = t & 63, m = lane & 15, quad = lane >> 4;
  const int NT = (CS == 1) ? 2 : 1;
  f32x4 accs[2];
  f32x4 acck;
  #pragma unroll
  for (int nt = 0; nt < NT; ++nt) {
    int o = colbase + w*16 + nt*128 + m;
    const unsigned short* wp = wmat + o*256 + quad*8;
    f32x4 ah_acc = {0,0,0,0}, al_acc = {0,0,0,0};
    f32x4 kh_acc = {0,0,0,0}, kl_acc = {0,0,0,0};
    const unsigned short* wp2 = (OUTM == 5) ? (wmat2 + o*256 + quad*8) : wp;
    #pragma unroll
    for (int kt = 0; kt < 8; ++kt) {
      bf16x8s ah = *(const bf16x8s*)&Uh[m][kt*32 + quad*8];
      bf16x8s al = *(const bf16x8s*)&Ul[m][kt*32 + quad*8];
      bf16x8s bw = *(const bf16x8s*)(wp + kt*32);
      ah_acc = __builtin_amdgcn_mfma_f32_16x16x32_bf16(ah, bw, ah_acc, 0, 0, 0);
      al_acc = __builtin_amdgcn_mfma_f32_16x16x32_bf16(al, bw, al_acc, 0, 0, 0);
      if (OUTM == 5) {
        bf16x8s bw2 = *(const bf16x8s*)(wp2 + kt*32);
        kh_acc = __builtin_amdgcn_mfma_f32_16x16x32_bf16(ah, bw2, kh_acc, 0, 0, 0);
        kl_acc = __builtin_amdgcn_mfma_f32_16x16x32_bf16(al, bw2, kl_acc, 0, 0, 0);
      }
    }
    accs[nt] = ah_acc + al_acc;
    if (OUTM == 5) acck = kh_acc + kl_acc;
    if (RN == 0) {
      float bv = bias[o];
      if constexpr (OUTM == 0) {
        #pragma unroll
        for (int i = 0; i < 4; ++i) {
          long row = r0 + quad*4 + i;
          ((float*)outp)[row*256 + o] = accs[nt][i] + bv;
        }
      } else if constexpr (OUTM == 1) {
        #pragma unroll
        for (int i = 0; i < 4; ++i) {
          long row = r0 + quad*4 + i;
          stout(outp, row*256 + o, accs[nt][i] + bv, bf);
        }
      } else if constexpr (OUTM == 4) {
        int h = o >> 5, d = o & 31;
        #pragma unroll
        for (int i = 0; i < 4; ++i) {
          long row = r0 + quad*4 + i;
          int b = (int)(row >> 10), n = (int)(row & 1023);
          ((unsigned short*)outp)[((long)((b*8 + h)*32 + d))*1024 + n]
              = f2bf(accs[nt][i] + bv);
        }
      } else if constexpr (OUTM == 5) {
        float* wsf = (float*)outp;                 // outp = ws base
        float* qhm = wsf + A_OFF;
        unsigned short* khm = (unsigned short*)(wsf + B_OFF);
        float bq = bias[o], bk = bias2[o];
        int h = o >> 5, d = o & 31;
        #pragma unroll
        for (int i = 0; i < 4; ++i) {
          long row = r0 + quad*4 + i;
          int b = (int)(row >> 10), n = (int)(row & 1023);
          long idx = ((long)((b*8 + h)*1024 + n))*32 + d;
          qhm[idx] = accs[nt][i] + bq;
          khm[idx] = f2bf(acck[i] + bk);
        }
      }
    }
  }
  if constexpr (RN == 1) {
    // overlay O (fp32 16x264) on Usm; all U reads are done
    __syncthreads();
    float (*O)[264] = (float (*)[264])Usm;
    #pragma unroll
    for (int nt = 0; nt < NT; ++nt) {
      int oc = colbase + w*16 + nt*128 + m;
      float bv = bias[oc];
      #pragma unroll
      for (int i = 0; i < 4; ++i)
        O[quad*4 + i][oc] = accs[nt][i] + bv;
    }
    __syncthreads();
    #pragma unroll
    for (int rr = 0; rr < 2; ++rr) {
      int r = 2*w + rr;
      float vals[4]; float s = 0.0f;
      #pragma unroll
      for (int j = 0; j < 4; ++j) { vals[j] = O[r][lane + 64*j]; s += vals[j]; }
      #pragma unroll
      for (int off = 32; off > 0; off >>= 1) s += __shfl_xor(s, off);
      float mean = s * (1.0f/256.0f);
      float ss = 0.0f;
      #pragma unroll
      for (int j = 0; j < 4; ++j) { float d = vals[j] - mean; ss += d*d; }
      #pragma unroll
      for (int off = 32; off > 0; off >>= 1) ss += __shfl_xor(ss, off);
      float inv = 1.0f / (sqrtf(ss * (1.0f/255.0f)) + 1e-6f);
      #pragma unroll
      for (int j = 0; j < 4; ++j) {
        float nv = (vals[j] - mean) * inv;
        ((float*)outp)[(long)(r0 + r)*256 + lane + 64*j] = nv;
        O[r][lane + 64*j] = nv;      // write back for column partials
      }
    }
    __syncthreads();
    if (csout != nullptr && t < 256) {
      float s = 0, ss = 0;
      #pragma unroll
      for (int r = 0; r < 16; ++r) { float v = O[r][t]; s += v; ss += v*v; }
      csout[gid*256 + t] = s;              // gid in 0..255 == (b*64 + j)
      csout[65536 + gid*256 + t] = ss;
    }
  }
}

// ---------------- MHA via MFMA, bf16 K/V, 16 q-rows per block --------------
#define SPS 1036
__global__ __launch_bounds__(512) void attn2_kernel(float* ws) {
  int t = threadIdx.x;
  int gid = blockIdx.x;
  int h = gid & 7;
  int b = (gid >> 3) & 3;
  int n0 = (gid >> 5) << 4;   // 16 q-rows per block; gid>>5 in 0..63
  __shared__ __align__(16) float Sp[16*SPS];        // 66.3 KB
  __shared__ __align__(16) float opart[8][16][17];  // 8.7 KB
  float* qq = ws + A_OFF;
  const unsigned short* kk = (const unsigned short*)(ws + B_OFF);
  const unsigned short* vt = (const unsigned short*)(ws + C_OFF);
  int base_bh = (b*8 + h)*1024;
  int w = t >> 6, lane = t & 63;   // w 0..7
  int m = lane & 15, quad = lane >> 4;
  const float scl = 0.17677669529663687f; // 1/sqrt(32)
  // ---- QK via MFMA: wave w covers keys w*128 .. +127 ----------------------
  {
    const float* qp = qq + (base_bh + n0 + m)*32 + quad*8;   // 16 real rows
    bf16x8s aq;
    #pragma unroll
    for (int j = 0; j < 8; ++j) ((unsigned short*)&aq)[j] = f2bf(qp[j]);
    f32x4 zero = {0.0f, 0.0f, 0.0f, 0.0f};
    #pragma unroll
    for (int kt = 0; kt < 8; ++kt) {
      int kbase = w*128 + kt*16;
      bf16x8s bk = *(const bf16x8s*)(kk + (base_bh + kbase + m)*32 + quad*8);
      f32x4 d = __builtin_amdgcn_mfma_f32_16x16x32_bf16(aq, bk, zero, 0, 0, 0);
      int key = kbase + m;
      #pragma unroll
      for (int i = 0; i < 4; ++i)
        Sp[(quad*4 + i)*SPS + key] = d[i] * scl;
    }
  }
  __syncthreads();
  // ---- softmax: wave w owns rows 2w, 2w+1; single pass, bf16 overlay ------
  #pragma unroll
  for (int rr = 0; rr < 2; ++rr) {
    int r = 2*w + rr;
    float* Sr = Sp + r*SPS;
    float p[16];
    #pragma unroll
    for (int j = 0; j < 16; ++j) p[j] = Sr[lane + 64*j];
    float mx = -3.4e38f;
    #pragma unroll
    for (int j = 0; j < 16; ++j) mx = fmaxf(mx, p[j]);
    #pragma unroll
    for (int off = 32; off > 0; off >>= 1) mx = fmaxf(mx, __shfl_xor(mx, off));
    float s = 0.0f;
    #pragma unroll
    for (int j = 0; j < 16; ++j) { p[j] = __expf(p[j] - mx); s += p[j]; }
    #pragma unroll
    for (int off = 32; off > 0; off >>= 1) s += __shfl_xor(s, off);
    float rs = 1.0f / s;
    unsigned short* Pr = (unsigned short*)Sr;     // bf16 overlay, same row
    #pragma unroll
    for (int j = 0; j < 16; ++j)
      Pr[lane + 64*j] = f2bf(p[j] * rs);
  }
  __syncthreads();
  // ---- PV via MFMA: wave w -> d-tile (w&1), key-chunks (w>>1)*8 .. +7 -----
  {
    int ntile = w & 1;
    int ktbase = (w >> 1) * 8;
    int vd = ntile*16 + m;
    const unsigned short* vrow = vt + base_bh*32 + vd*1024;
    const unsigned short* P0 = (const unsigned short*)Sp + m*(SPS*2);  // row m
    f32x4 acc0 = {0.0f, 0.0f, 0.0f, 0.0f};
    f32x4 acc1 = {0.0f, 0.0f, 0.0f, 0.0f};
    #pragma unroll
    for (int kt2 = 0; kt2 < 4; ++kt2) {
      int kt = ktbase + 2*kt2;
      bf16x8s ap0 = *(const bf16x8s*)(P0 + kt*32 + quad*8);
      bf16x8s bv0 = *(const bf16x8s*)(vrow + kt*32 + quad*8);
      acc0 = __builtin_amdgcn_mfma_f32_16x16x32_bf16(ap0, bv0, acc0, 0, 0, 0);
      bf16x8s ap1 = *(const bf16x8s*)(P0 + (kt+1)*32 + quad*8);
      bf16x8s bv1 = *(const bf16x8s*)(vrow + (kt+1)*32 + quad*8);
      acc1 = __builtin_amdgcn_mfma_f32_16x16x32_bf16(ap1, bv1, acc1, 0, 0, 0);
    }
    f32x4 acc = acc0 + acc1;
    #pragma unroll
    for (int i = 0; i < 4; ++i)
      opart[w][quad*4 + i][m] = acc[i];
  }
  __syncthreads();
  {
    int r = t >> 5, d = t & 31;         // 512 threads: 16 rows x 32 d
    int nt = d >> 4, c = d & 15;
    float sum = opart[nt][r][c] + opart[nt + 2][r][c]
              + opart[nt + 4][r][c] + opart[nt + 6][r][c];
    qq[(base_bh + n0 + r)*32 + d] = sum;   // o over q (own slots)
  }
}

extern "C" void kernel_launch(void* const* d_in, const int* in_sizes, int n_in,
                              void* d_out, int out_size, void* d_ws, size_t ws_size,
                              hipStream_t stream) {
  const void* x   = d_in[0];
  const void* src = d_in[1];
  const int* adj  = (const int*)d_in[2];
  const void* wg  = d_in[3];
  const void* a1  = d_in[4];
  const void* a2  = d_in[5];
  const void* lw  = d_in[6];
  const void* lb  = d_in[7];
  const void* ipw = d_in[8];
  const void* ipb = d_in[9];
  const void* opw = d_in[10];
  const void* opb = d_in[11];
  float* ws = (float*)d_ws;
  const unsigned short* wbf = (const unsigned short*)d_ws;
  int* flagp = (int*)(ws + FLAG_F);

  detect_kernel<<<1, 64, 0, stream>>>((const unsigned short*)x, flagp);
  prep_kernel<<<dim3(256, 7), 256, 0, stream>>>(wg, lw, ipw, opw, lb, ipb, opb,
                                                a1, a2, ws, flagp);
  packadj_kernel<<<4096, 256, 0, stream>>>(adj,
      (unsigned long long*)(ws + PK_OFF));
  gemm2_kernel<0,0,4,2><<<512, 512, 0, stream>>>(x, wbf + 0*65536,
      nullptr, ws + CS_OFF + 4096, nullptr, nullptr, ws + A_OFF, nullptr,
      flagp);                                                  // WhT -> A
  s1s2_kernel<<<256, 256, 0, stream>>>(x, ws, flagp);          // s1/s2
  attn1a_kernel<<<1024, 512, 0, stream>>>(x, ws, flagp);       // xa -> C, mx/rs
  eout_kernel<<<4096, 256, 0, stream>>>(ws, d_out, flagp);     // e_out; rownorm -> B
  colstatsA_kernel<<<256, 256, 0, stream>>>(ws + B_OFF, ws + MX_OFF);
  colstatsB_kernel<<<4, 256, 0, stream>>>(ws + MX_OFF, ws + ST1_OFF);
  gemm2_kernel<1,1,0,1><<<256, 512, 0, stream>>>(ws + B_OFF, wbf + 1*65536,
      nullptr, ws + BIAS_OFF, nullptr, ws + ST1_OFF, ws + C_OFF, ws + MX_OFF,
      flagp);                                                  // lin+RN -> C (+col partials)
  colstatsB_kernel<<<4, 256, 0, stream>>>(ws + MX_OFF, ws + ST2_OFF);
  gemm2_kernel<1,0,5,2><<<512, 512, 0, stream>>>(ws + C_OFF, wbf + 2*65536,
      wbf + 3*65536, ws + BIAS_OFF + 256, ws + BIAS_OFF + 512, ws + ST2_OFF,
      ws, nullptr, flagp);                                     // Q -> A, K -> B
  gemm2_kernel<2,0,4,2><<<512, 512, 0, stream>>>(src, wbf + 4*65536,
      nullptr, ws + BIAS_OFF + 768, nullptr, nullptr, ws + C_OFF, nullptr,
      flagp);                                                  // V^T -> C
  attn2_kernel<<<2048, 512, 0, stream>>>(ws);                  // o -> A_OFF
  gemm2_kernel<3,0,1,2><<<512, 512, 0, stream>>>(ws + A_OFF, wbf + 5*65536,
      nullptr, ws + BIAS_OFF + 1024, nullptr, nullptr, d_out, nullptr,
      flagp);                                                  // out-proj
}

// Round 9
// 243.173 us; speedup vs baseline: 1.4316x; 1.0102x over previous
//
#include <hip/hip_runtime.h>
#include <hip/hip_bf16.h>

// B=4, N=1024, E=256, H=8, D=32. Float tensors may be bf16 OR fp32 in d_in /
// d_out (detected at runtime on-device); adj is int32.
// Output: x_out [4,1024,256] then e_out [4,1024,1024] (element offsets).
//
// ws float offsets:
//   [0 .. 196608)   : weight matrices, bf16, ushort offset m*65536, ALL o-major
//       W[o][e] at m*65536 + o*256 + e.  m: 0=Wcat 1=LIN 2=WQ 3=WK 4=WV 5=WO
#define BIAS_OFF 196608   // lin_b, bq, bk, bv, bo, a1, a2  (7*256 fp32)
#define S1_OFF   198400   // [h][4096]
#define S2_OFF   231168
#define CS_OFF   263936   // +4096: zero-bias[256] (prep-filled)
#define ST1_OFF  296704   // mean[1024] + inv[1024]
#define ST2_OFF  298752
#define A_OFF    300800   // WhT bf16 [b][h][d][n] (2 MB) -> later Q,o fp32 head-major
#define MX_OFF   825088   // softmax row max [h][4096]; later colstats scratch (131072 f)
#define RS_OFF   857856   // softmax row 1/sum [h][4096]
#define PK_OFF   890624   // packed adj bitmask: [4096 rows][16 u64] = 512 KB (dead after eout)
#define B_OFF    1349376  // 4 MB: rownorm(xa)     -> later K bf16 head-major [b][h][n][32]
#define C_OFF    2397952  // 4 MB: raw xa, then rownorm(lin) -> later V^T bf16 hm [b][h][d][n]
#define FLAG_F   3446528  // int: 1 = bf16 tensors, 0 = fp32 tensors
// end 3446529 floats = 13.8 MB

#define NEGC (-9.0e15f)

typedef __attribute__((ext_vector_type(8))) short bf16x8s;
typedef __attribute__((ext_vector_type(4))) float f32x4;

static __device__ __forceinline__ float bf2f(unsigned short u) {
  union { unsigned int i; float f; } v; v.i = ((unsigned int)u) << 16; return v.f;
}
static __device__ __forceinline__ unsigned short f2bf(float f) {
  union { float f; unsigned int u; } v; v.f = f;
  unsigned int r = (v.u + 0x7FFFu + ((v.u >> 16) & 1u)) >> 16;   // RNE
  return (unsigned short)r;
}
static __device__ __forceinline__ float ldin(const void* p, long i, int bf) {
  return bf ? bf2f(((const unsigned short*)p)[i]) : ((const float*)p)[i];
}
static __device__ __forceinline__ unsigned short rdbf(const void* p, long i, int bf) {
  if (bf) return ((const unsigned short*)p)[i];
  return f2bf(((const float*)p)[i]);
}
static __device__ __forceinline__ void stout(void* p, long i, float v, int bf) {
  if (bf) ((unsigned short*)p)[i] = f2bf(v);
  else    ((float*)p)[i] = v;
}

// ---------------- dtype detector -------------------------------------------
__global__ __launch_bounds__(64) void detect_kernel(const unsigned short* x, int* flag) {
  int lane = threadIdx.x;
  unsigned short u = x[2 * lane];
  int e = (u >> 7) & 0xFF;
  bool good = (e >= 100 && e <= 140);
  unsigned long long m = __ballot(good);
  if (lane == 0) *flag = (__popcll(m) >= 48) ? 1 : 0;
}

// ---------------- adj -> bitmask: [row][16 u64], bit m%64 of word m/64 -----
__global__ __launch_bounds__(256) void packadj_kernel(const int* adj,
                                                      unsigned long long* pk) {
  int t = threadIdx.x, w = t >> 6, lane = t & 63;
  long row = blockIdx.x;            // 4096 rows
  #pragma unroll
  for (int j = 0; j < 4; ++j) {
    int m = t + 256*j;              // wave covers bits [w*64+256j .. +63]
    bool bit = adj[row*1024 + m] > 0;
    unsigned long long mask = __ballot(bit);
    if (lane == 0) pk[row*16 + w + 4*j] = mask;
  }
}

// ------- prep: all weights -> o-major bf16; biases + a1/a2 fp32 ------------
__global__ __launch_bounds__(256) void prep_kernel(
    const void* wg, const void* lin_w, const void* inp_w, const void* out_w,
    const void* lin_b, const void* inp_b, const void* out_b,
    const void* a1, const void* a2, float* ws, const int* flagp) {
  const int bf = *flagp;
  unsigned short* wbf = (unsigned short*)ws;
  int t = threadIdx.x;        // o (output feature)
  int f = blockIdx.x;         // e (input feature)
  int m = blockIdx.y;
  if (m == 0) {
    int h = t >> 5, d = t & 31;
    wbf[t*256 + f] = rdbf(wg, h*8192 + f*32 + d, bf);   // Wcat[o=h*32+d][e]
  } else if (m <= 5) {
    int dst = m*65536 + t*256 + f;          // W[o=t][e=f]
    if (m == 1)      wbf[dst] = rdbf(lin_w, t*256 + f, bf);
    else if (m == 2) wbf[dst] = rdbf(inp_w, t*256 + f, bf);
    else if (m == 3) wbf[dst] = rdbf(inp_w, (256 + t)*256 + f, bf);
    else if (m == 4) wbf[dst] = rdbf(inp_w, (512 + t)*256 + f, bf);
    else             wbf[dst] = rdbf(out_w, t*256 + f, bf);
  } else if (f == 0) {
    ws[BIAS_OFF + t]        = ldin(lin_b, t, bf);
    ws[BIAS_OFF + 256 + t]  = ldin(inp_b, t, bf);
    ws[BIAS_OFF + 512 + t]  = ldin(inp_b, 256 + t, bf);
    ws[BIAS_OFF + 768 + t]  = ldin(inp_b, 512 + t, bf);
    ws[BIAS_OFF + 1024 + t] = ldin(out_b, t, bf);
    ws[BIAS_OFF + 1280 + t] = ldin(a1, t, bf);
    ws[BIAS_OFF + 1536 + t] = ldin(a2, t, bf);
    ws[CS_OFF + 4096 + t]   = 0.0f;        // zero bias for Wcat GEMM
  }
}

// ------- graph attention, head-split, 32 REAL rows/block -------------------
// GRID 1024, BLOCK 512 (8 waves): 4b x 32 groups x 8h; h in low 3 bits
// (XCD-L2 locality on WhT). adj from packed bitmask (scalar loads).
// Softmax register-resident: wave w owns rows 4w..4w+3. P bf16 in Pb[32]
// (two 16-row A-frag groups; PV shares each bw load across both groups).
// PV: wave w -> d-tile (w&1), key-chunks (w>>1)*8..+7; opart OVERLAYS the
// dead Pb/s2s arena after a barrier (all Pb reads complete). LDS 68.5 KB ->
// 2 blocks/CU. WhT [b][h][d][n] (from gemm2 WhT). Writes:
//   C region: raw xa slice  xa[b,n,h*32+d] = x + leaky(PV)
//   MX/RS: per-(h,row) softmax max and 1/sum (consumed by eout_kernel)
#define PB_S 1032    // Pb row stride (ushorts); 2064 B -> m*4 banks, conflict-free
__global__ __launch_bounds__(512) void attn1a_kernel(const void* x, float* ws,
                                                     const int* flagp) {
  const int bf = *flagp;
  int t = threadIdx.x;
  int gid = blockIdx.x;
  int h = gid & 7;
  int b = (gid >> 3) & 3;
  int n0 = (gid >> 5) * 32;               // gid>>5 in 0..31
  __shared__ __align__(16) unsigned char arena[4096 + 32*PB_S*2];  // 68.5 KB
  float* s2s = (float*)arena;
  unsigned short (*Pb)[PB_S] = (unsigned short (*)[PB_S])(arena + 4096);
  float (*opart)[32][17] = (float (*)[32][17])arena;   // overlay (after Pb dead)
  int w = t >> 6, lane = t & 63;          // w 0..7
  int m = lane & 15, quad = lane >> 4;
  const unsigned long long* pk = (const unsigned long long*)(ws + PK_OFF);
  const float* s2p = ws + S2_OFF + h*4096 + b*1024;
  #pragma unroll
  for (int j = 0; j < 2; ++j) s2s[t + 512*j] = s2p[t + 512*j];
  __syncthreads();
  // ---- softmax rows n0+4w .. n0+4w+3, head h: register resident -----------
  #pragma unroll
  for (int rr = 0; rr < 4; ++rr) {
    int r = 4*w + rr;
    int rowi = __builtin_amdgcn_readfirstlane(b*1024 + n0 + r);
    const unsigned long long* prow = pk + (long)rowi * 16;   // wave-uniform
    float s1v = ws[S1_OFF + h*4096 + rowi];
    float p[16];
    float mx = -3.4e38f;
    #pragma unroll
    for (int j = 0; j < 16; ++j) {
      int mm = lane + 64*j;
      float ev = s1v + s2s[mm];
      ev = (ev >= 0.0f) ? ev : 0.1f*ev;
      ev = ((prow[j] >> lane) & 1ull) ? ev : NEGC;
      p[j] = ev;
      mx = fmaxf(mx, ev);
    }
    #pragma unroll
    for (int off = 32; off > 0; off >>= 1) mx = fmaxf(mx, __shfl_xor(mx, off));
    float s = 0.0f;
    #pragma unroll
    for (int j = 0; j < 16; ++j) { p[j] = __expf(p[j] - mx); s += p[j]; }
    #pragma unroll
    for (int off = 32; off > 0; off >>= 1) s += __shfl_xor(s, off);
    float rs = 1.0f / s;
    #pragma unroll
    for (int j = 0; j < 16; ++j)
      Pb[r][lane + 64*j] = f2bf(p[j] * rs);
    if (lane == 0) {
      ws[MX_OFF + h*4096 + rowi] = mx;
      ws[RS_OFF + h*4096 + rowi] = rs;
    }
  }
  __syncthreads();
  // ---- PV via MFMA: wave w -> d-tile (w&1), key-chunks (w>>1)*8 .. +7 -----
  f32x4 g0, g1;
  {
    const unsigned short* wht = (const unsigned short*)(ws + A_OFF);
    int ntile = w & 1;
    int ktbase = (w >> 1) * 8;
    int vd = ntile*16 + m;
    const unsigned short* wrow = wht + ((long)((b*8 + h)*32 + vd))*1024;
    f32x4 a0g0 = {0,0,0,0}, a1g0 = {0,0,0,0};
    f32x4 a0g1 = {0,0,0,0}, a1g1 = {0,0,0,0};
    #pragma unroll
    for (int kt2 = 0; kt2 < 4; ++kt2) {
      int kt = ktbase + 2*kt2;
      bf16x8s bw0 = *(const bf16x8s*)(wrow + kt*32 + quad*8);
      bf16x8s bw1 = *(const bf16x8s*)(wrow + (kt+1)*32 + quad*8);
      bf16x8s p00 = *(const bf16x8s*)&Pb[m][kt*32 + quad*8];
      bf16x8s p01 = *(const bf16x8s*)&Pb[16 + m][kt*32 + quad*8];
      a0g0 = __builtin_amdgcn_mfma_f32_16x16x32_bf16(p00, bw0, a0g0, 0, 0, 0);
      a0g1 = __builtin_amdgcn_mfma_f32_16x16x32_bf16(p01, bw0, a0g1, 0, 0, 0);
      bf16x8s p10 = *(const bf16x8s*)&Pb[m][(kt+1)*32 + quad*8];
      bf16x8s p11 = *(const bf16x8s*)&Pb[16 + m][(kt+1)*32 + quad*8];
      a1g0 = __builtin_amdgcn_mfma_f32_16x16x32_bf16(p10, bw1, a1g0, 0, 0, 0);
      a1g1 = __builtin_amdgcn_mfma_f32_16x16x32_bf16(p11, bw1, a1g1, 0, 0, 0);
    }
    g0 = a0g0 + a1g0;
    g1 = a0g1 + a1g1;
  }
  __syncthreads();          // all Pb reads complete -> arena reusable
  #pragma unroll
  for (int i = 0; i < 4; ++i) {
    opart[w][quad*4 + i][m]      = g0[i];
    opart[w][16 + quad*4 + i][m] = g1[i];
  }
  __syncthreads();
  #pragma unroll
  for (int half = 0; half < 2; ++half) {
    int r = (t >> 5) + half*16;         // 16 rows per half
    int dd = t & 31;
    int nt = dd >> 4, c = dd & 15;
    float sum = opart[nt][r][c] + opart[nt + 2][r][c]
              + opart[nt + 4][r][c] + opart[nt + 6][r][c];
    float hv = (sum >= 0.0f) ? sum : 0.01f*sum;
    long idx = (long)(b*1024 + n0 + r)*256 + h*32 + dd;
    ws[C_OFF + idx] = ldin(x, idx, bf) + hv;   // raw residual row slice
  }
}

// ------- e_out = mean_h attn (from stored mx/rs) + fused rownorm(xa) -------
__global__ __launch_bounds__(256) void eout_kernel(float* ws, void* dout,
                                                   const int* flagp) {
  const int bf = *flagp;
  int t = threadIdx.x;
  int gid = blockIdx.x;
  int b = gid & 3;
  int n = gid >> 2;
  int row = b*1024 + n;
  int w = t >> 6, lane = t & 63;
  __shared__ float part[8];
  const unsigned long long* pk = (const unsigned long long*)(ws + PK_OFF);
  const unsigned long long* prow = pk + (long)row * 16;
  // ---- rownorm (ddof=1, two-pass) of raw xa row ---------------------------
  float v = ws[C_OFF + (long)row*256 + t];
  float s = v;
  #pragma unroll
  for (int off = 32; off > 0; off >>= 1) s += __shfl_xor(s, off);
  if (lane == 0) part[w] = s;
  __syncthreads();
  float mean = (part[0] + part[1] + part[2] + part[3]) * (1.0f/256.0f);
  float d = v - mean;
  float ss = d*d;
  #pragma unroll
  for (int off = 32; off > 0; off >>= 1) ss += __shfl_xor(ss, off);
  if (lane == 0) part[4 + w] = ss;
  __syncthreads();
  float inv = 1.0f / (sqrtf((part[4]+part[5]+part[6]+part[7]) * (1.0f/255.0f)) + 1e-6f);
  ws[B_OFF + (long)row*256 + t] = d * inv;
  // ---- e_out --------------------------------------------------------------
  float s1v[8], mxv[8], rsv[8];
  #pragma unroll
  for (int h = 0; h < 8; ++h) {
    s1v[h] = ws[S1_OFF + h*4096 + row];
    mxv[h] = ws[MX_OFF + h*4096 + row];
    rsv[h] = ws[RS_OFF + h*4096 + row];
  }
  const float* s2b = ws + S2_OFF + b*1024;
  #pragma unroll
  for (int j = 0; j < 4; ++j) {
    int m = t + 256*j;
    bool a = (prow[w + 4*j] >> lane) & 1ull;
    float acc = 0.0f;
    #pragma unroll
    for (int h = 0; h < 8; ++h) {
      float ev = s1v[h] + s2b[h*4096 + m];
      ev = (ev >= 0.0f) ? ev : 0.1f*ev;
      ev = a ? ev : NEGC;
      acc += rsv[h] * __expf(ev - mxv[h]);
    }
    stout(dout, 1048576L + (long)row*1024 + m, 0.125f*acc, bf);
  }
}

// -------- column (axis=1) stats, ddof=1; scratch in MX region (dead) -------
__global__ __launch_bounds__(256) void colstatsA_kernel(const float* in, float* cs) {
  int t = threadIdx.x;
  int j = blockIdx.x & 63;
  int b = blockIdx.x >> 6;
  float s = 0, ss = 0;
  for (int n = j*16; n < j*16 + 16; ++n) {
    float v = in[(b*1024 + n)*256 + t];
    s += v; ss += v*v;
  }
  cs[(b*64 + j)*256 + t] = s;
  cs[65536 + (b*64 + j)*256 + t] = ss;
}

__global__ __launch_bounds__(256) void colstatsB_kernel(const float* cs, float* st) {
  int t = threadIdx.x;
  int b = blockIdx.x;
  float s = 0, ss = 0;
  for (int j = 0; j < 64; ++j) {
    s  += cs[(b*64 + j)*256 + t];
    ss += cs[65536 + (b*64 + j)*256 + t];
  }
  float mean = s * (1.0f/1024.0f);
  float var = fmaxf((ss - s*mean) * (1.0f/1023.0f), 0.0f);
  st[b*256 + t] = mean;
  st[1024 + b*256 + t] = 1.0f / (sqrtf(var) + 1e-6f);
}

// ---------------- MFMA row-GEMM, fp32-accurate via bf16 hi/lo split --------
// out[row][o] = sum_e in[row][e] * W[o][e] + bias[o];  in = hi + lo (bf16).
// Block 512 thr (8 waves), 16 rows staged in LDS (bf16 hi/lo, pad 264).
// CS=2: grid 512 = 256 rowgroups x 2 colhalves. CS=1: grid 256 (RN-able).
// IN_MODE 0: d_in flat (dtype flag); 1: fp32 + colnorm(st); 2: src permuted
//   (n,b,e)->(b,n,e); 3: fp32 head-major.
// OUTM 0: fp32 flat (RN=1: fused rownorm + column partials -> csout);
//   1: d_out; 4: bf16 T hm [b][h][d][n]; 5: DUAL Q/K (Q fp32 hm A, K bf16 B).
// SOP=1 (with OUTM 4): also emit s1/s2 = Wh·a1/a2 head reductions
//   (a1 = bias2, a2 = st, ws base = csout) -- replaces the s1s2 kernel.
template<int IN_MODE, int RN, int OUTM, int CS, int SOP>
__global__ __launch_bounds__(512) void gemm2_kernel(const void* inp,
    const unsigned short* wmat, const unsigned short* wmat2,
    const float* bias, const float* bias2, const float* st,
    void* outp, float* csout, const int* flagp) {
  const int bf = *flagp;
  int t = threadIdx.x;
  int gid = blockIdx.x;
  int rowg = (CS == 2) ? (gid >> 1) : gid;
  int colbase = (CS == 2) ? ((gid & 1) * 128) : 0;
  int r0 = rowg * 16;
  __shared__ __align__(16) unsigned short Usm[2*16*264];    // 16.9 KB
  unsigned short (*Uh)[264] = (unsigned short (*)[264])Usm;
  unsigned short (*Ul)[264] = (unsigned short (*)[264])(Usm + 16*264);
  // ---- stage 16 rows as bf16 hi/lo ----------------------------------------
  {
    int srow = t >> 5;
    int e0 = (t & 31) * 8;
    long grow = r0 + srow;
    float v[8];
    if (IN_MODE == 0) {
      #pragma unroll
      for (int j = 0; j < 8; ++j) v[j] = ldin(inp, grow*256 + e0 + j, bf);
    } else if (IN_MODE == 1) {
      int b = (int)(grow >> 10);
      const float* ip = (const float*)inp + grow*256 + e0;
      const float* mp = st + b*256 + e0;
      const float* vp = st + 1024 + b*256 + e0;
      #pragma unroll
      for (int j = 0; j < 8; ++j) v[j] = (ip[j] - mp[j]) * vp[j];
    } else if (IN_MODE == 2) {
      int b = (int)(grow >> 10), n = (int)(grow & 1023);
      #pragma unroll
      for (int j = 0; j < 8; ++j)
        v[j] = ldin(inp, (long)(n*4 + b)*256 + e0 + j, bf);
    } else {
      int b = (int)(grow >> 10), n = (int)(grow & 1023);
      const float* ip = (const float*)inp
          + ((long)(b*8 + (e0 >> 5))*1024 + n)*32 + (e0 & 31);
      #pragma unroll
      for (int j = 0; j < 8; ++j) v[j] = ip[j];
    }
    unsigned short hv[8], lv[8];
    #pragma unroll
    for (int j = 0; j < 8; ++j) {
      hv[j] = f2bf(v[j]);
      lv[j] = f2bf(v[j] - bf2f(hv[j]));
    }
    *(bf16x8s*)&Uh[srow][e0] = *(bf16x8s*)hv;
    *(bf16x8s*)&Ul[srow][e0] = *(bf16x8s*)lv;
  }
  __syncthreads();
  int w = t >> 6, lane = t & 63, m = lane & 15, quad = lane >> 4;
  const int NT = (CS == 1) ? 2 : 1;
  f32x4 accs[2];
  f32x4 acck;
  #pragma unroll
  for (int nt = 0; nt < NT; ++nt) {
    int o = colbase + w*16 + nt*128 + m;
    const unsigned short* wp = wmat + o*256 + quad*8;
    f32x4 ah_acc = {0,0,0,0}, al_acc = {0,0,0,0};
    f32x4 kh_acc = {0,0,0,0}, kl_acc = {0,0,0,0};
    const unsigned short* wp2 = (OUTM == 5) ? (wmat2 + o*256 + quad*8) : wp;
    #pragma unroll
    for (int kt = 0; kt < 8; ++kt) {
      bf16x8s ah = *(const bf16x8s*)&Uh[m][kt*32 + quad*8];
      bf16x8s al = *(const bf16x8s*)&Ul[m][kt*32 + quad*8];
      bf16x8s bw = *(const bf16x8s*)(wp + kt*32);
      ah_acc = __builtin_amdgcn_mfma_f32_16x16x32_bf16(ah, bw, ah_acc, 0, 0, 0);
      al_acc = __builtin_amdgcn_mfma_f32_16x16x32_bf16(al, bw, al_acc, 0, 0, 0);
      if (OUTM == 5) {
        bf16x8s bw2 = *(const bf16x8s*)(wp2 + kt*32);
        kh_acc = __builtin_amdgcn_mfma_f32_16x16x32_bf16(ah, bw2, kh_acc, 0, 0, 0);
        kl_acc = __builtin_amdgcn_mfma_f32_16x16x32_bf16(al, bw2, kl_acc, 0, 0, 0);
      }
    }
    accs[nt] = ah_acc + al_acc;
    if (OUTM == 5) acck = kh_acc + kl_acc;
    if (RN == 0) {
      float bv = bias[o];
      if constexpr (OUTM == 0) {
        #pragma unroll
        for (int i = 0; i < 4; ++i) {
          long row = r0 + quad*4 + i;
          ((float*)outp)[row*256 + o] = accs[nt][i] + bv;
        }
      } else if constexpr (OUTM == 1) {
        #pragma unroll
        for (int i = 0; i < 4; ++i) {
          long row = r0 + quad*4 + i;
          stout(outp, row*256 + o, accs[nt][i] + bv, bf);
        }
      } else if constexpr (OUTM == 4) {
        int h = o >> 5, d = o & 31;
        #pragma unroll
        for (int i = 0; i < 4; ++i) {
          long row = r0 + quad*4 + i;
          int b = (int)(row >> 10), n = (int)(row & 1023);
          ((unsigned short*)outp)[((long)((b*8 + h)*32 + d))*1024 + n]
              = f2bf(accs[nt][i] + bv);
        }
      } else if constexpr (OUTM == 5) {
        float* wsf = (float*)outp;                 // outp = ws base
        float* qhm = wsf + A_OFF;
        unsigned short* khm = (unsigned short*)(wsf + B_OFF);
        float bq = bias[o], bk = bias2[o];
        int h = o >> 5, d = o & 31;
        #pragma unroll
        for (int i = 0; i < 4; ++i) {
          long row = r0 + quad*4 + i;
          int b = (int)(row >> 10), n = (int)(row & 1023);
          long idx = ((long)((b*8 + h)*1024 + n))*32 + d;
          qhm[idx] = accs[nt][i] + bq;
          khm[idx] = f2bf(acck[i] + bk);
        }
      }
    }
  }
  if constexpr (SOP == 1) {
    // s1/s2 head reductions from the Wh accumulators (CS=2 -> NT=1):
    // s1[h][row] = sum_d Wh[row][h*32+d]*a1[h*32+d]. Wave w covers o =
    // colbase + w*16 + m (half a head); pair waves (2h2, 2h2+1) = one head.
    __shared__ float sp[2][8][16];
    int o = colbase + w*16 + m;
    float a1v = bias2[o];
    float a2v = st[o];
    #pragma unroll
    for (int i = 0; i < 4; ++i) {
      float v1 = accs[0][i] * a1v;
      float v2 = accs[0][i] * a2v;
      #pragma unroll
      for (int off = 8; off > 0; off >>= 1) {
        v1 += __shfl_xor(v1, off);
        v2 += __shfl_xor(v2, off);
      }
      if (m == 0) {
        sp[0][w][quad*4 + i] = v1;
        sp[1][w][quad*4 + i] = v2;
      }
    }
    __syncthreads();
    if (t < 128) {
      int which = t >> 6, h2 = (t >> 4) & 3, r = t & 15;
      float v = sp[which][2*h2][r] + sp[which][2*h2 + 1][r];
      long dst = (which ? S2_OFF : S1_OFF)
               + (long)((colbase >> 5) + h2)*4096 + (r0 + r);
      csout[dst] = v;
    }
  }
  if constexpr (RN == 1) {
    // overlay O (fp32 16x264) on Usm; all U reads are done
    __syncthreads();
    float (*O)[264] = (float (*)[264])Usm;
    #pragma unroll
    for (int nt = 0; nt < NT; ++nt) {
      int oc = colbase + w*16 + nt*128 + m;
      float bv = bias[oc];
      #pragma unroll
      for (int i = 0; i < 4; ++i)
        O[quad*4 + i][oc] = accs[nt][i] + bv;
    }
    __syncthreads();
    #pragma unroll
    for (int rr = 0; rr < 2; ++rr) {
      int r = 2*w + rr;
      float vals[4]; float s = 0.0f;
      #pragma unroll
      for (int j = 0; j < 4; ++j) { vals[j] = O[r][lane + 64*j]; s += vals[j]; }
      #pragma unroll
      for (int off = 32; off > 0; off >>= 1) s += __shfl_xor(s, off);
      float mean = s * (1.0f/256.0f);
      float ss = 0.0f;
      #pragma unroll
      for (int j = 0; j < 4; ++j) { float d = vals[j] - mean; ss += d*d; }
      #pragma unroll
      for (int off = 32; off > 0; off >>= 1) ss += __shfl_xor(ss, off);
      float inv = 1.0f / (sqrtf(ss * (1.0f/255.0f)) + 1e-6f);
      #pragma unroll
      for (int j = 0; j < 4; ++j) {
        float nv = (vals[j] - mean) * inv;
        ((float*)outp)[(long)(r0 + r)*256 + lane + 64*j] = nv;
        O[r][lane + 64*j] = nv;      // write back for column partials
      }
    }
    __syncthreads();
    if (csout != nullptr && t < 256) {
      float s = 0, ss = 0;
      #pragma unroll
      for (int r = 0; r < 16; ++r) { float v = O[r][t]; s += v; ss += v*v; }
      csout[gid*256 + t] = s;              // gid in 0..255 == (b*64 + j)
      csout[65536 + gid*256 + t] = ss;
    }
  }
}

// -------- MHA via MFMA, flash-register softmax, 16 q-rows per block --------
// GRID 2048, BLOCK 512 (8 waves): 64 row-groups x 4 b x 8 h (h low 3 bits).
// Q fp32 hm [b][h][n][32] at A_OFF (o overwrites q, exclusive slots);
// K bf16 [b][h][n][32] at B_OFF; V^T bf16 [b][h][d][n] at C_OFF.
// QK: wave w covers keys w*128..+127, S stays in REGISTERS (s[8][4]).
// Per-wave partial max/sum over 128 keys (shfl over the 16-lane m group);
// 16-thread LDS combine -> global max + 1/denominator; each wave writes its
// NORMALIZED P tile bf16 directly (no fp32 S in LDS). P stride 1036 ushorts
// (2072 B: quad rows hit distinct bank groups; PV b128 reads ~2-way).
// LDS ~44 KB -> 3 blocks/CU (was 75 KB / 2). PV unchanged.
#define P2S 1036
__global__ __launch_bounds__(512) void attn2_kernel(float* ws) {
  int t = threadIdx.x;
  int gid = blockIdx.x;
  int h = gid & 7;
  int b = (gid >> 3) & 3;
  int n0 = (gid >> 5) << 4;   // 16 q-rows per block; gid>>5 in 0..63
  __shared__ __align__(16) unsigned short P[16][P2S];   // 33.2 KB
  __shared__ float pmx[8][16];
  __shared__ float psm[8][16];
  __shared__ float gmx[16];
  __shared__ float grs[16];
  __shared__ __align__(16) float opart[8][16][17];      // 8.7 KB
  float* qq = ws + A_OFF;
  const unsigned short* kk = (const unsigned short*)(ws + B_OFF);
  const unsigned short* vt = (const unsigned short*)(ws + C_OFF);
  int base_bh = (b*8 + h)*1024;
  int w = t >> 6, lane = t & 63;   // w 0..7
  int m = lane & 15, quad = lane >> 4;
  const float scl = 0.17677669529663687f; // 1/sqrt(32)
  float s[8][4];
  // ---- QK via MFMA into registers: wave w covers keys w*128 .. +127 -------
  {
    const float* qp = qq + (base_bh + n0 + m)*32 + quad*8;   // 16 real rows
    bf16x8s aq;
    #pragma unroll
    for (int j = 0; j < 8; ++j) ((unsigned short*)&aq)[j] = f2bf(qp[j]);
    f32x4 zero = {0.0f, 0.0f, 0.0f, 0.0f};
    #pragma unroll
    for (int kt = 0; kt < 8; ++kt) {
      int kbase = w*128 + kt*16;
      bf16x8s bk = *(const bf16x8s*)(kk + (base_bh + kbase + m)*32 + quad*8);
      f32x4 d = __builtin_amdgcn_mfma_f32_16x16x32_bf16(aq, bk, zero, 0, 0, 0);
      #pragma unroll
      for (int i = 0; i < 4; ++i) s[kt][i] = d[i] * scl;   // row=quad*4+i, key=kbase+m
    }
  }
  // ---- per-wave partial max/sum over its 128 keys -------------------------
  #pragma unroll
  for (int i = 0; i < 4; ++i) {
    float mx = s[0][i];
    #pragma unroll
    for (int kt = 1; kt < 8; ++kt) mx = fmaxf(mx, s[kt][i]);
    #pragma unroll
    for (int off = 8; off > 0; off >>= 1) mx = fmaxf(mx, __shfl_xor(mx, off));
    float sm = 0.0f;
    #pragma unroll
    for (int kt = 0; kt < 8; ++kt) sm += __expf(s[kt][i] - mx);
    #pragma unroll
    for (int off = 8; off > 0; off >>= 1) sm += __shfl_xor(sm, off);
    if (m == 0) { pmx[w][quad*4 + i] = mx; psm[w][quad*4 + i] = sm; }
  }
  __syncthreads();
  if (t < 16) {
    float mx = pmx[0][t];
    #pragma unroll
    for (int w2 = 1; w2 < 8; ++w2) mx = fmaxf(mx, pmx[w2][t]);
    float den = 0.0f;
    #pragma unroll
    for (int w2 = 0; w2 < 8; ++w2) den += psm[w2][t] * __expf(pmx[w2][t] - mx);
    gmx[t] = mx;
    grs[t] = 1.0f / den;
  }
  __syncthreads();
  // ---- write normalized P bf16 --------------------------------------------
  #pragma unroll
  for (int i = 0; i < 4; ++i) {
    int row = quad*4 + i;
    float mx = gmx[row], rs = grs[row];
    #pragma unroll
    for (int kt = 0; kt < 8; ++kt)
      P[row][w*128 + kt*16 + m] = f2bf(__expf(s[kt][i] - mx) * rs);
  }
  __syncthreads();
  // ---- PV via MFMA: wave w -> d-tile (w&1), key-chunks (w>>1)*8 .. +7 -----
  {
    int ntile = w & 1;
    int ktbase = (w >> 1) * 8;
    int vd = ntile*16 + m;
    const unsigned short* vrow = vt + base_bh*32 + vd*1024;
    const unsigned short* P0 = &P[m][0];                 // A-frag row m
    f32x4 acc0 = {0.0f, 0.0f, 0.0f, 0.0f};
    f32x4 acc1 = {0.0f, 0.0f, 0.0f, 0.0f};
    #pragma unroll
    for (int kt2 = 0; kt2 < 4; ++kt2) {
      int kt = ktbase + 2*kt2;
      bf16x8s ap0 = *(const bf16x8s*)(P0 + kt*32 + quad*8);
      bf16x8s bv0 = *(const bf16x8s*)(vrow + kt*32 + quad*8);
      acc0 = __builtin_amdgcn_mfma_f32_16x16x32_bf16(ap0, bv0, acc0, 0, 0, 0);
      bf16x8s ap1 = *(const bf16x8s*)(P0 + (kt+1)*32 + quad*8);
      bf16x8s bv1 = *(const bf16x8s*)(vrow + (kt+1)*32 + quad*8);
      acc1 = __builtin_amdgcn_mfma_f32_16x16x32_bf16(ap1, bv1, acc1, 0, 0, 0);
    }
    f32x4 acc = acc0 + acc1;
    #pragma unroll
    for (int i = 0; i < 4; ++i)
      opart[w][quad*4 + i][m] = acc[i];
  }
  __syncthreads();
  {
    int r = t >> 5, d = t & 31;         // 512 threads: 16 rows x 32 d
    int nt = d >> 4, c = d & 15;
    float sum = opart[nt][r][c] + opart[nt + 2][r][c]
              + opart[nt + 4][r][c] + opart[nt + 6][r][c];
    qq[(base_bh + n0 + r)*32 + d] = sum;   // o over q (own slots)
  }
}

extern "C" void kernel_launch(void* const* d_in, const int* in_sizes, int n_in,
                              void* d_out, int out_size, void* d_ws, size_t ws_size,
                              hipStream_t stream) {
  const void* x   = d_in[0];
  const void* src = d_in[1];
  const int* adj  = (const int*)d_in[2];
  const void* wg  = d_in[3];
  const void* a1  = d_in[4];
  const void* a2  = d_in[5];
  const void* lw  = d_in[6];
  const void* lb  = d_in[7];
  const void* ipw = d_in[8];
  const void* ipb = d_in[9];
  const void* opw = d_in[10];
  const void* opb = d_in[11];
  float* ws = (float*)d_ws;
  const unsigned short* wbf = (const unsigned short*)d_ws;
  int* flagp = (int*)(ws + FLAG_F);

  detect_kernel<<<1, 64, 0, stream>>>((const unsigned short*)x, flagp);
  prep_kernel<<<dim3(256, 7), 256, 0, stream>>>(wg, lw, ipw, opw, lb, ipb, opb,
                                                a1, a2, ws, flagp);
  packadj_kernel<<<4096, 256, 0, stream>>>(adj,
      (unsigned long long*)(ws + PK_OFF));
  gemm2_kernel<0,0,4,2,1><<<512, 512, 0, stream>>>(x, wbf + 0*65536,
      nullptr, ws + CS_OFF + 4096, ws + BIAS_OFF + 1280, ws + BIAS_OFF + 1536,
      ws + A_OFF, ws, flagp);                              // WhT -> A; s1/s2
  attn1a_kernel<<<1024, 512, 0, stream>>>(x, ws, flagp);       // xa -> C, mx/rs
  eout_kernel<<<4096, 256, 0, stream>>>(ws, d_out, flagp);     // e_out; rownorm -> B
  colstatsA_kernel<<<256, 256, 0, stream>>>(ws + B_OFF, ws + MX_OFF);
  colstatsB_kernel<<<4, 256, 0, stream>>>(ws + MX_OFF, ws + ST1_OFF);
  gemm2_kernel<1,1,0,1,0><<<256, 512, 0, stream>>>(ws + B_OFF, wbf + 1*65536,
      nullptr, ws + BIAS_OFF, nullptr, ws + ST1_OFF, ws + C_OFF, ws + MX_OFF,
      flagp);                                                  // lin+RN -> C (+col partials)
  colstatsB_kernel<<<4, 256, 0, stream>>>(ws + MX_OFF, ws + ST2_OFF);
  gemm2_kernel<1,0,5,2,0><<<512, 512, 0, stream>>>(ws + C_OFF, wbf + 2*65536,
      wbf + 3*65536, ws + BIAS_OFF + 256, ws + BIAS_OFF + 512, ws + ST2_OFF,
      ws, nullptr, flagp);                                     // Q -> A, K -> B
  gemm2_kernel<2,0,4,2,0><<<512, 512, 0, stream>>>(src, wbf + 4*65536,
      nullptr, ws + BIAS_OFF + 768, nullptr, nullptr, ws + C_OFF, nullptr,
      flagp);                                                  // V^T -> C
  attn2_kernel<<<2048, 512, 0, stream>>>(ws);                  // o -> A_OFF
  gemm2_kernel<3,0,1,2,0><<<512, 512, 0, stream>>>(ws + A_OFF, wbf + 5*65536,
      nullptr, ws + BIAS_OFF + 1024, nullptr, nullptr, d_out, nullptr,
      flagp);                                                  // out-proj
}